// Round 5
// baseline (64321.997 us; speedup 1.0000x reference)
//
#include <hip/hip_runtime.h>

#define B_  8
#define N_  16384
#define D_  64
#define S_  2048
#define K_  32
#define SPLIT_  4
#define NSPL_   (N_/SPLIT_)       // 4096 candidates per block
#define CH32_   (NSPL_/32)        // 128 chunks of 32
#define PLANE_  ((size_t)B_*N_*64) // shorts per plane (8.39M = 16.78 MB)

using short8_ = __attribute__((ext_vector_type(8))) short;
using f32x4_  = __attribute__((ext_vector_type(4))) float;

// =====================================================================
// exact bf16 triple-split of fp32 (truncation-based): f = h0 + h1 + h2
// (every op is exact in IEEE fp32 -> bit-deterministic across kernels)
// =====================================================================
__device__ __forceinline__ void bf3split(float f, short& h0, short& h1, short& h2)
{
  unsigned u0 = __float_as_uint(f);
  float f0 = __uint_as_float(u0 & 0xFFFF0000u);
  h0 = (short)(u0 >> 16);
  float r1 = f - f0;
  unsigned u1 = __float_as_uint(r1);
  float f1 = __uint_as_float(u1 & 0xFFFF0000u);
  h1 = (short)(u1 >> 16);
  float r2 = r1 - f1;                 // <= 8 significant bits: bf16-exact
  h2 = (short)(__float_as_uint(r2) >> 16);
}

// sorted-DESCENDING 32-entry list (Lv[0] = largest kept)
__device__ __forceinline__ void insert32(float (&Lv)[32], int (&Li)[32], float x, int n)
{
  bool ci = x < Lv[0];
  #pragma unroll
  for (int i = 0; i < 31; ++i) {
    bool c1 = x < Lv[i+1];
    float nv = c1 ? Lv[i+1] : (ci ? x : Lv[i]);
    int   ni = c1 ? Li[i+1] : (ci ? n : Li[i]);
    Lv[i] = nv; Li[i] = ni;
    ci = c1;
  }
  Lv[31] = ci ? x : Lv[31];
  Li[31] = ci ? n : Li[31];
}

// =====================================================================
// K1 (fast path): sqn + new_xyz gather + fragment-major bf16x3 planes
// sqn uses the EXACT round-3 expression/order (bit-identical keys ->
// bit-identical selection vs the passing round-3 run).
// plane layout: off(b,n,k) = ((((b*256 + n>>6)*4 + (n>>4)&3)*2 + k>>5)*64
//                             + ((k>>3)&3)*16 + (n&15))*8 + (k&7)
// =====================================================================
__global__ __launch_bounds__(256) void k_prep(
    const float* __restrict__ xyz, const float* __restrict__ points,
    const int* __restrict__ sidx, float* __restrict__ out, float* __restrict__ sqn,
    short* __restrict__ P0, short* __restrict__ P1, short* __restrict__ P2)
{
  int tid = blockIdx.x * 256 + threadIdx.x;      // 0 .. B*N-1
  const float4* p = (const float4*)(points + (size_t)tid * 64);

  // ---- sqnorm: verbatim round-3 loop (bit-identical contraction) ----
  float s = 0.f;
  #pragma unroll
  for (int i = 0; i < 16; ++i) {
    float4 v = p[i];
    s += v.x*v.x + v.y*v.y + v.z*v.z + v.w*v.w;
  }
  sqn[tid] = s;

  // ---- fragment-major bf16x3 planes ----
  int n = tid & (N_-1);
  int c = n >> 6, ct = (n >> 4) & 3, mc = n & 15;
  size_t segbase = (((size_t)(tid >> 14) * 256 + c) * 4 + ct) * 2;  // *512 shorts

  #pragma unroll
  for (int g = 0; g < 8; ++g) {                  // (kt=g>>2, qd=g&3), dims 8g..8g+7
    float4 a = p[2*g], b4 = p[2*g+1];
    float f[8] = {a.x,a.y,a.z,a.w, b4.x,b4.y,b4.z,b4.w};
    short8_ h0v, h1v, h2v;
    #pragma unroll
    for (int j = 0; j < 8; ++j) {
      short h0, h1, h2;
      bf3split(f[j], h0, h1, h2);
      h0v[j] = h0; h1v[j] = h1; h2v[j] = h2;
    }
    size_t off = ((segbase + (g>>2))*64 + (size_t)(g&3)*16 + mc)*8;
    *(short8_*)(P0 + off) = h0v;
    *(short8_*)(P1 + off) = h1v;
    *(short8_*)(P2 + off) = h2v;
  }
  if (tid < B_*S_) {
    int b = tid >> 11, ss = tid & (S_-1);
    int nn = sidx[ss];
    const float* src = xyz + ((size_t)b * N_ + nn) * 3;
    out[(size_t)tid*3+0] = src[0];
    out[(size_t)tid*3+1] = src[1];
    out[(size_t)tid*3+2] = src[2];
  }
}

// =====================================================================
// K2 (fast path): MFMA over pre-split planes + mask-then-insert top-32
// =====================================================================
__global__ __launch_bounds__(256, 4) void k_knn(
    const short* __restrict__ P0, const short* __restrict__ P1,
    const short* __restrict__ P2, const int* __restrict__ sidx,
    const float* __restrict__ sqn, uint2* __restrict__ pw)
{
  // LDS: Bp [12 segs][64 lanes][8 shorts] = 12288 B | Dt [32c][68r] f32 = 8704 B
  //      | sqc [32] f32. merge phase aliases all as uint2 mbuf[32][130] = 33280 B
  __shared__ __align__(16) char smraw[33280];
  short* Bp  = (short*)smraw;
  float* Dt  = (float*)(smraw + 12288);
  float* sqc = (float*)(smraw + 20992);

  const int t = threadIdx.x;
  const int b     = blockIdx.x & 7;          // XCD swizzle
  const int y     = blockIdx.x >> 3;
  const int tile  = y & 31;
  const int split = y >> 5;
  const int s0 = tile * 64;
  const float* Qb = sqn + (size_t)b * N_;

  const int lane = t & 63, wv = t >> 6;
  const int quad = lane >> 4, mcol = lane & 15;

  // ---- A fragments (wave wv owns sampled rows 16*wv..+15), from planes ----
  short8_ A0[2], A1[2], A2[2];
  {
    int srow = sidx[s0 + 16*wv + mcol];
    int cs = srow >> 6, cts = (srow >> 4) & 3, ms = srow & 15;
    size_t ab = (((size_t)(b*256 + cs))*4 + cts)*2*512 + ((size_t)quad*16 + ms)*8;
    #pragma unroll
    for (int kt = 0; kt < 2; ++kt) {
      A0[kt] = *(const short8_*)(P0 + ab + kt*512);
      A1[kt] = *(const short8_*)(P1 + ab + kt*512);
      A2[kt] = *(const short8_*)(P2 + ab + kt*512);
    }
  }

  float Lv[32]; int Li[32];
  #pragma unroll
  for (int i = 0; i < 32; ++i) { Lv[i] = 3.0e38f; Li[i] = 0; }

  const int r = t >> 2;        // selection row 0..63
  const int q = t & 3;         // stream within row
  const int n0base = split * NSPL_;
  const size_t bc8base = (size_t)b * 256;

  for (int ch = 0; ch < CH32_; ++ch) {
    const int n0 = n0base + ch * 32;
    const int c64 = n0 >> 6, half = (n0 >> 5) & 1;
    // ---- stage 12 segments (3 planes x 2 ct x 2 kt), 1 KB each ----
    {
      const size_t bc8 = (bc8base + c64) * 8;
      #pragma unroll
      for (int rep = 0; rep < 3; ++rep) {
        int task = rep*256 + t;
        int seg = task >> 6, ln = task & 63;
        int pl = seg >> 2, rem = seg & 3;        // rem = ctl*2 + kt
        int st = (half*2 + (rem>>1))*2 + (rem&1);
        const short* Pp = (pl == 0) ? P0 : (pl == 1) ? P1 : P2;
        short8_ v = *(const short8_*)(Pp + (bc8 + st)*512 + (size_t)ln*8);
        *(short8_*)(Bp + seg*512 + ln*8) = v;
      }
      if (t < 8) *(float4*)(sqc + 4*t) = *(const float4*)(Qb + n0 + 4*t);
    }
    __syncthreads();

    // ---- 16 MFMA per 16-cand tile (8 combos x 2 kt), 2 tiles ----
    #pragma unroll
    for (int ct = 0; ct < 2; ++ct) {
      short8_ b0[2], b1[2], b2[2];
      #pragma unroll
      for (int kt = 0; kt < 2; ++kt) {
        int lo = lane*8;
        b0[kt] = *(const short8_*)(Bp + (0*4 + ct*2 + kt)*512 + lo);
        b1[kt] = *(const short8_*)(Bp + (1*4 + ct*2 + kt)*512 + lo);
        b2[kt] = *(const short8_*)(Bp + (2*4 + ct*2 + kt)*512 + lo);
      }
      f32x4_ a = {0.f, 0.f, 0.f, 0.f};
      #pragma unroll
      for (int kt = 0; kt < 2; ++kt) {
        a = __builtin_amdgcn_mfma_f32_16x16x32_bf16(A0[kt], b0[kt], a, 0,0,0);
        a = __builtin_amdgcn_mfma_f32_16x16x32_bf16(A0[kt], b1[kt], a, 0,0,0);
        a = __builtin_amdgcn_mfma_f32_16x16x32_bf16(A1[kt], b0[kt], a, 0,0,0);
        a = __builtin_amdgcn_mfma_f32_16x16x32_bf16(A1[kt], b1[kt], a, 0,0,0);
        a = __builtin_amdgcn_mfma_f32_16x16x32_bf16(A0[kt], b2[kt], a, 0,0,0);
        a = __builtin_amdgcn_mfma_f32_16x16x32_bf16(A2[kt], b0[kt], a, 0,0,0);
        a = __builtin_amdgcn_mfma_f32_16x16x32_bf16(A1[kt], b2[kt], a, 0,0,0);
        a = __builtin_amdgcn_mfma_f32_16x16x32_bf16(A2[kt], b1[kt], a, 0,0,0);
      }
      // keys -> Dt col-major. C/D: col=lane&15, row=quad*4+reg
      int cc = 16*ct + mcol;
      float sq = sqc[cc];
      float4 kv;
      kv.x = sq - 2.f*a[0];
      kv.y = sq - 2.f*a[1];
      kv.z = sq - 2.f*a[2];
      kv.w = sq - 2.f*a[3];
      *(float4*)(Dt + cc*68 + 16*wv + 4*quad) = kv;
    }
    __syncthreads();

    // ---- selection: mask survivors, then lane-parallel insert ----
    float L0 = Lv[0];
    L0 = fminf(L0, __shfl_xor(L0, 1));
    L0 = fminf(L0, __shfl_xor(L0, 2));
    const float tau = L0;
    const float thr = fminf(tau, Lv[0]);

    unsigned m = 0;
    #pragma unroll
    for (int i = 0; i < 8; ++i) {
      float x = Dt[(q*8 + i)*68 + r];
      m |= (x < thr) ? (1u << i) : 0u;
    }
    while (__any(m != 0)) {
      if (m) {
        int i = __ffs(m) - 1;
        m &= m - 1;
        float x = Dt[(q*8 + i)*68 + r];
        if (x < Lv[0])
          insert32(Lv, Li, x, n0 + q*8 + i);
      }
    }
  }

  // ---- in-block 4-pointer merge (streams stored reversed -> ascending) ----
  uint2* mbuf = (uint2*)smraw;                 // [32][130]
  const int rowg = b * S_ + s0;
  for (int pass = 0; pass < 2; ++pass) {
    __syncthreads();
    const int rb = pass * 32;
    if (r >= rb && r < rb + 32) {
      #pragma unroll
      for (int i = 0; i < 32; ++i)
        mbuf[(r - rb)*130 + q*32 + (31 - i)] =
            make_uint2(__float_as_uint(Lv[i]), (unsigned)Li[i]);
    }
    __syncthreads();
    if (t < 32) {
      const uint2* Lrow = mbuf + t*130;
      uint2* dst = pw + ((size_t)(rowg + rb + t) * SPLIT_ + split) * 32;
      int p0 = 0, p1 = 0, p2 = 0, p3 = 0;
      for (int k = 0; k < 32; ++k) {
        float bv = 3.0e38f; unsigned bi = 0xFFFFFFFFu; int bq = 0;
        int pa[4] = {p0, p1, p2, p3};
        #pragma unroll
        for (int q4 = 0; q4 < 4; ++q4) {
          if (pa[q4] < 32) {
            uint2 e = Lrow[q4*32 + pa[q4]];
            float v = __uint_as_float(e.x);
            if (v < bv || (v == bv && e.y < bi)) { bv = v; bi = e.y; bq = q4; }
          }
        }
        dst[k] = make_uint2(__float_as_uint(bv), bi);
        if (bq == 0) p0++; else if (bq == 1) p1++; else if (bq == 2) p2++; else p3++;
      }
    }
  }
}

// =====================================================================
// FALLBACK path (ws too small): round-3 kernels, proven correct
// =====================================================================
__global__ __launch_bounds__(256) void k_prep_fb(
    const float* __restrict__ xyz, const float* __restrict__ points,
    const int* __restrict__ sidx, float* __restrict__ out, float* __restrict__ sqn)
{
  int tid = blockIdx.x * 256 + threadIdx.x;
  const float4* p = (const float4*)(points + (size_t)tid * 64);
  float s = 0.f;
  #pragma unroll
  for (int i = 0; i < 16; ++i) {
    float4 v = p[i];
    s += v.x*v.x + v.y*v.y + v.z*v.z + v.w*v.w;
  }
  sqn[tid] = s;
  if (tid < B_*S_) {
    int b = tid >> 11, ss = tid & (S_-1);
    int n = sidx[ss];
    const float* src = xyz + ((size_t)b * N_ + n) * 3;
    out[(size_t)tid*3+0] = src[0];
    out[(size_t)tid*3+1] = src[1];
    out[(size_t)tid*3+2] = src[2];
  }
}

__global__ __launch_bounds__(256) void k_knn_fb(
    const float* __restrict__ points, const int* __restrict__ sidx,
    const float* __restrict__ sqn, uint2* __restrict__ pw)
{
  __shared__ __align__(16) char smraw[45312];
  short* Bp0 = (short*)smraw;
  short* Bp1 = (short*)(smraw + 9216);
  short* Bp2 = (short*)(smraw + 18432);
  float* Dt  = (float*)(smraw + 27648);
  float* sqc = (float*)(smraw + 45056);

  const int t = threadIdx.x;
  const int b     = blockIdx.x & 7;
  const int y     = blockIdx.x >> 3;
  const int tile  = y & 31;
  const int split = y >> 5;
  const int s0 = tile * 64;
  const float* Pb = points + (size_t)b * N_ * 64;
  const float* Qb = sqn    + (size_t)b * N_;

  const int lane = t & 63, wv = t >> 6;
  const int quad = lane >> 4, mcol = lane & 15;

  short8_ A0[2], A1[2], A2[2];
  {
    int srow = sidx[s0 + 16*wv + mcol];
    const float* ar = Pb + (size_t)srow * 64;
    #pragma unroll
    for (int kt = 0; kt < 2; ++kt) {
      float4 v0 = *(const float4*)(ar + 32*kt + 8*quad);
      float4 v1 = *(const float4*)(ar + 32*kt + 8*quad + 4);
      float f[8] = {v0.x,v0.y,v0.z,v0.w,v1.x,v1.y,v1.z,v1.w};
      #pragma unroll
      for (int j = 0; j < 8; ++j) {
        short h0, h1, h2;
        bf3split(f[j], h0, h1, h2);
        A0[kt][j] = h0; A1[kt][j] = h1; A2[kt][j] = h2;
      }
    }
  }

  float Lv[32]; int Li[32];
  #pragma unroll
  for (int i = 0; i < 32; ++i) { Lv[i] = 3.0e38f; Li[i] = 0; }

  const int r = t >> 2;
  const int q = t & 3;
  const int n0base = split * NSPL_;

  for (int ch = 0; ch < NSPL_/64; ++ch) {
    const int n0 = n0base + ch * 64;
    {
      const int n = t & 63, jg = t >> 6;
      const float* src = Pb + (size_t)(n0 + n) * 64 + 16*jg;
      float4 u0 = *(const float4*)(src);
      float4 u1 = *(const float4*)(src + 4);
      float4 u2 = *(const float4*)(src + 8);
      float4 u3 = *(const float4*)(src + 12);
      float f[16] = {u0.x,u0.y,u0.z,u0.w, u1.x,u1.y,u1.z,u1.w,
                     u2.x,u2.y,u2.z,u2.w, u3.x,u3.y,u3.z,u3.w};
      short8_ p0[2], p1[2], p2[2];
      #pragma unroll
      for (int j = 0; j < 16; ++j) {
        short h0, h1, h2;
        bf3split(f[j], h0, h1, h2);
        p0[j>>3][j&7] = h0; p1[j>>3][j&7] = h1; p2[j>>3][j&7] = h2;
      }
      *(short8_*)(Bp0 + n*72 + 16*jg)     = p0[0];
      *(short8_*)(Bp0 + n*72 + 16*jg + 8) = p0[1];
      *(short8_*)(Bp1 + n*72 + 16*jg)     = p1[0];
      *(short8_*)(Bp1 + n*72 + 16*jg + 8) = p1[1];
      *(short8_*)(Bp2 + n*72 + 16*jg)     = p2[0];
      *(short8_*)(Bp2 + n*72 + 16*jg + 8) = p2[1];
      if (t < 16) *(float4*)(sqc + 4*t) = *(const float4*)(Qb + n0 + 4*t);
    }
    __syncthreads();

    f32x4_ acc[4];
    #pragma unroll
    for (int ct = 0; ct < 4; ++ct) {
      const int boff = (16*ct + mcol)*72 + 8*quad;
      short8_ b0[2], b1[2], b2[2];
      b0[0] = *(const short8_*)(Bp0 + boff); b0[1] = *(const short8_*)(Bp0 + boff + 32);
      b1[0] = *(const short8_*)(Bp1 + boff); b1[1] = *(const short8_*)(Bp1 + boff + 32);
      b2[0] = *(const short8_*)(Bp2 + boff); b2[1] = *(const short8_*)(Bp2 + boff + 32);
      f32x4_ a = {0.f, 0.f, 0.f, 0.f};
      #pragma unroll
      for (int kt = 0; kt < 2; ++kt) {
        a = __builtin_amdgcn_mfma_f32_16x16x32_bf16(A0[kt], b0[kt], a, 0,0,0);
        a = __builtin_amdgcn_mfma_f32_16x16x32_bf16(A0[kt], b1[kt], a, 0,0,0);
        a = __builtin_amdgcn_mfma_f32_16x16x32_bf16(A1[kt], b0[kt], a, 0,0,0);
        a = __builtin_amdgcn_mfma_f32_16x16x32_bf16(A1[kt], b1[kt], a, 0,0,0);
        a = __builtin_amdgcn_mfma_f32_16x16x32_bf16(A0[kt], b2[kt], a, 0,0,0);
        a = __builtin_amdgcn_mfma_f32_16x16x32_bf16(A2[kt], b0[kt], a, 0,0,0);
        a = __builtin_amdgcn_mfma_f32_16x16x32_bf16(A1[kt], b2[kt], a, 0,0,0);
        a = __builtin_amdgcn_mfma_f32_16x16x32_bf16(A2[kt], b1[kt], a, 0,0,0);
      }
      acc[ct] = a;
    }
    #pragma unroll
    for (int ct = 0; ct < 4; ++ct) {
      int c = 16*ct + mcol;
      float sq = sqc[c];
      float4 kv;
      kv.x = sq - 2.f*acc[ct][0];
      kv.y = sq - 2.f*acc[ct][1];
      kv.z = sq - 2.f*acc[ct][2];
      kv.w = sq - 2.f*acc[ct][3];
      *(float4*)(Dt + c*68 + 16*wv + 4*quad) = kv;
    }
    __syncthreads();

    float L0 = Lv[0];
    L0 = fminf(L0, __shfl_xor(L0, 1));
    L0 = fminf(L0, __shfl_xor(L0, 2));
    const float tau = L0;
    #pragma unroll
    for (int g = 0; g < 4; ++g) {
      #pragma unroll
      for (int u = 0; u < 4; ++u) {
        int c = q*16 + g*4 + u;
        float x = Dt[c*68 + r];
        if (x < fminf(tau, Lv[0]))
          insert32(Lv, Li, x, n0 + c);
      }
    }
  }

  uint2* mbuf = (uint2*)smraw;
  const int rowg = b * S_ + s0;
  for (int pass = 0; pass < 2; ++pass) {
    __syncthreads();
    const int rb = pass * 32;
    if (r >= rb && r < rb + 32) {
      #pragma unroll
      for (int i = 0; i < 32; ++i)
        mbuf[(r - rb)*130 + q*32 + (31 - i)] =
            make_uint2(__float_as_uint(Lv[i]), (unsigned)Li[i]);
    }
    __syncthreads();
    if (t < 32) {
      const uint2* Lrow = mbuf + t*130;
      uint2* dst = pw + ((size_t)(rowg + rb + t) * SPLIT_ + split) * 32;
      int p0 = 0, p1 = 0, p2 = 0, p3 = 0;
      for (int k = 0; k < 32; ++k) {
        float bv = 3.0e38f; unsigned bi = 0xFFFFFFFFu; int bq = 0;
        int pa[4] = {p0, p1, p2, p3};
        #pragma unroll
        for (int q4 = 0; q4 < 4; ++q4) {
          if (pa[q4] < 32) {
            uint2 e = Lrow[q4*32 + pa[q4]];
            float v = __uint_as_float(e.x);
            if (v < bv || (v == bv && e.y < bi)) { bv = v; bi = e.y; bq = q4; }
          }
        }
        dst[k] = make_uint2(__float_as_uint(bv), bi);
        if (bq == 0) p0++; else if (bq == 1) p1++; else if (bq == 2) p2++; else p3++;
      }
    }
  }
}

// =====================================================================
// K2b: merge the 4 split-partials (ascending) per row -> 32 indices
// =====================================================================
__global__ __launch_bounds__(256) void k_sel(const uint2* __restrict__ pw,
                                             int* __restrict__ nbr)
{
  int row = blockIdx.x * 256 + threadIdx.x;       // 0 .. B*S-1
  const uint2* L = pw + (size_t)row * (SPLIT_*32);
  int* dst = nbr + (size_t)row * K_;
  int p[4] = {0,0,0,0};
  for (int k = 0; k < K_; ++k) {
    float bv = 3.0e38f; unsigned bi = 0xFFFFFFFFu; int bq = 0;
    #pragma unroll
    for (int q4 = 0; q4 < 4; ++q4) {
      if (p[q4] < 32) {
        uint2 e = L[q4*32 + p[q4]];
        float v = __uint_as_float(e.x);
        if (v < bv || (v == bv && e.y < bi)) { bv = v; bi = e.y; bq = q4; }
      }
    }
    dst[k] = (int)bi;
    p[bq]++;
  }
}

// =====================================================================
// K3: gather + 3-layer MLP (BN folded) + maxpool over 32 neighbors
// =====================================================================
__device__ __forceinline__ void layer64(
    const int t, const float* __restrict__ w, const float* __restrict__ bb,
    const float* __restrict__ gg, const float* __restrict__ be,
    const float* __restrict__ mm, const float* __restrict__ vv,
    const float* Xin, float* Hout, float* W, float* scl, float* bia)
{
  if (t < 64) {
    float sc = gg[t] * rsqrtf(vv[t] + 1e-5f);
    scl[t] = sc;
    bia[t] = (bb[t] - mm[t]) * sc + be[t];
  }
  __syncthreads();
  #pragma unroll
  for (int k = 0; k < 4; ++k) {
    int flat = k*256 + t;
    int o = flat >> 4, j = flat & 15;
    float4 v = *(const float4*)(w + o*64 + j*4);
    float sc = scl[o];
    v.x *= sc; v.y *= sc; v.z *= sc; v.w *= sc;
    *(float4*)(W + o*68 + j*4) = v;
  }
  __syncthreads();
  const int o0 = (t & 15) * 4;
  const int rp = t >> 4;
  float acc[2][4] = {};
  #pragma unroll 4
  for (int c4 = 0; c4 < 16; ++c4) {
    float4 xa = *(const float4*)(Xin + (2*rp)*68   + c4*4);
    float4 xb = *(const float4*)(Xin + (2*rp+1)*68 + c4*4);
    #pragma unroll
    for (int j = 0; j < 4; ++j) {
      float4 wv = *(const float4*)(W + (o0+j)*68 + c4*4);
      acc[0][j] = fmaf(xa.x,wv.x, fmaf(xa.y,wv.y, fmaf(xa.z,wv.z, fmaf(xa.w,wv.w, acc[0][j]))));
      acc[1][j] = fmaf(xb.x,wv.x, fmaf(xb.y,wv.y, fmaf(xb.z,wv.z, fmaf(xb.w,wv.w, acc[1][j]))));
    }
  }
  #pragma unroll
  for (int j = 0; j < 4; ++j) {
    Hout[(2*rp)*68   + o0+j] = fmaxf(acc[0][j] + bia[o0+j], 0.f);
    Hout[(2*rp+1)*68 + o0+j] = fmaxf(acc[1][j] + bia[o0+j], 0.f);
  }
  __syncthreads();
}

__global__ __launch_bounds__(256) void k_mlp(
    const float* __restrict__ points, const int* __restrict__ nbr,
    const float* __restrict__ w0, const float* __restrict__ b0,
    const float* __restrict__ g0, const float* __restrict__ be0,
    const float* __restrict__ m0, const float* __restrict__ v0,
    const float* __restrict__ w1, const float* __restrict__ b1,
    const float* __restrict__ g1, const float* __restrict__ be1,
    const float* __restrict__ m1, const float* __restrict__ v1,
    const float* __restrict__ w2, const float* __restrict__ b2,
    const float* __restrict__ g2, const float* __restrict__ be2,
    const float* __restrict__ m2, const float* __restrict__ v2,
    float* __restrict__ out)
{
  __shared__ float X[32*68];
  __shared__ float H[32*68];
  __shared__ float W[128*68];
  __shared__ float scl[128];
  __shared__ float bia[128];
  __shared__ int   nIx[32];

  const int t  = threadIdx.x;
  const int bs = blockIdx.x;
  const int b  = bs >> 11;

  if (t < 32) nIx[t] = nbr[(size_t)bs * K_ + t];
  __syncthreads();
  #pragma unroll
  for (int k = 0; k < 2; ++k) {
    int flat = k*256 + t;
    int row = flat >> 4, j = flat & 15;
    float4 v = *(const float4*)(points + ((size_t)b*N_ + nIx[row])*64 + j*4);
    *(float4*)(X + row*68 + j*4) = v;
  }
  __syncthreads();

  layer64(t, w0, b0, g0, be0, m0, v0, X, H, W, scl, bia);
  layer64(t, w1, b1, g1, be1, m1, v1, H, X, W, scl, bia);

  if (t < 128) {
    float sc = g2[t] * rsqrtf(v2[t] + 1e-5f);
    scl[t] = sc;
    bia[t] = (b2[t] - m2[t]) * sc + be2[t];
  }
  __syncthreads();
  #pragma unroll
  for (int k = 0; k < 8; ++k) {
    int flat = k*256 + t;
    int o = flat >> 4, j = flat & 15;
    float4 v = *(const float4*)(w2 + o*64 + j*4);
    float sc = scl[o];
    v.x *= sc; v.y *= sc; v.z *= sc; v.w *= sc;
    *(float4*)(W + o*68 + j*4) = v;
  }
  __syncthreads();
  {
    const int o0 = (t & 31) * 4;
    const int rq = t >> 5;
    float acc[4][4] = {};
    #pragma unroll 4
    for (int c4 = 0; c4 < 16; ++c4) {
      float4 xr[4];
      #pragma unroll
      for (int i = 0; i < 4; ++i) xr[i] = *(const float4*)(X + (4*rq+i)*68 + c4*4);
      #pragma unroll
      for (int j = 0; j < 4; ++j) {
        float4 wv = *(const float4*)(W + (o0+j)*68 + c4*4);
        #pragma unroll
        for (int i = 0; i < 4; ++i)
          acc[i][j] = fmaf(xr[i].x,wv.x, fmaf(xr[i].y,wv.y, fmaf(xr[i].z,wv.z, fmaf(xr[i].w,wv.w, acc[i][j]))));
      }
    }
    float pm[4];
    #pragma unroll
    for (int j = 0; j < 4; ++j) {
      float m = -3.0e38f;
      #pragma unroll
      for (int i = 0; i < 4; ++i)
        m = fmaxf(m, fmaxf(acc[i][j] + bia[o0+j], 0.f));
      pm[j] = m;
    }
    __syncthreads();
    *(float4*)(H + rq*132 + o0) = make_float4(pm[0], pm[1], pm[2], pm[3]);
  }
  __syncthreads();
  if (t < 128) {
    float m = -3.0e38f;
    #pragma unroll
    for (int rq = 0; rq < 8; ++rq) m = fmaxf(m, H[rq*132 + t]);
    out[(size_t)(B_*S_*3) + (size_t)bs*128 + t] = m;
  }
}

// =====================================================================
extern "C" void kernel_launch(void* const* d_in, const int* in_sizes, int n_in,
                              void* d_out, int out_size, void* d_ws, size_t ws_size,
                              hipStream_t stream)
{
  const float* xyz  = (const float*)d_in[0];
  const float* pts  = (const float*)d_in[1];
  const int*   sidx = (const int*)  d_in[2];
  const float* w0 = (const float*)d_in[3];
  const float* b0 = (const float*)d_in[4];
  const float* g0 = (const float*)d_in[5];
  const float* be0= (const float*)d_in[6];
  const float* m0 = (const float*)d_in[7];
  const float* v0 = (const float*)d_in[8];
  const float* w1 = (const float*)d_in[9];
  const float* b1 = (const float*)d_in[10];
  const float* g1 = (const float*)d_in[11];
  const float* be1= (const float*)d_in[12];
  const float* m1 = (const float*)d_in[13];
  const float* v1 = (const float*)d_in[14];
  const float* w2 = (const float*)d_in[15];
  const float* b2 = (const float*)d_in[16];
  const float* g2 = (const float*)d_in[17];
  const float* be2= (const float*)d_in[18];
  const float* m2 = (const float*)d_in[19];
  const float* v2 = (const float*)d_in[20];

  float* out = (float*)d_out;
  // ws: sqn (512KB) | nbr (2MB) | pw (16.8MB) | planes (3 x 16.78MB)
  float* sqn = (float*)d_ws;
  int*   nbr = (int*)  ((char*)d_ws + (size_t)B_*N_*4);
  uint2* pw  = (uint2*)((char*)d_ws + (size_t)B_*N_*4 + (size_t)B_*S_*K_*4);
  char*  pl  = (char*)d_ws + (size_t)B_*N_*4 + (size_t)B_*S_*K_*4
             + (size_t)B_*S_*SPLIT_*32*8;
  short* P0 = (short*)pl;
  short* P1 = P0 + PLANE_;
  short* P2 = P1 + PLANE_;
  const size_t need = (size_t)B_*N_*4 + (size_t)B_*S_*K_*4
                    + (size_t)B_*S_*SPLIT_*32*8 + 3*PLANE_*2;

  if (ws_size >= need) {
    k_prep<<<(B_*N_)/256, 256, 0, stream>>>(xyz, pts, sidx, out, sqn, P0, P1, P2);
    k_knn <<<B_*32*SPLIT_, 256, 0, stream>>>(P0, P1, P2, sidx, sqn, pw);
  } else {
    k_prep_fb<<<(B_*N_)/256, 256, 0, stream>>>(xyz, pts, sidx, out, sqn);
    k_knn_fb <<<B_*32*SPLIT_, 256, 0, stream>>>(pts, sidx, sqn, pw);
  }
  k_sel <<<(B_*S_)/256, 256, 0, stream>>>(pw, nbr);
  k_mlp <<<B_*S_, 256, 0, stream>>>(pts, nbr,
            w0,b0,g0,be0,m0,v0, w1,b1,g1,be1,m1,v1, w2,b2,g2,be2,m2,v2, out);
}

// Round 6
// 2411.381 us; speedup vs baseline: 26.6743x; 26.6743x over previous
//
#include <hip/hip_runtime.h>

#define B_  8
#define N_  16384
#define D_  64
#define S_  2048
#define K_  32
#define SPLIT_  4
#define NSPL_   (N_/SPLIT_)       // 4096 candidates per block
#define CH32_   (NSPL_/32)        // 128 chunks of 32
#define PLANE_  ((size_t)B_*N_*64) // shorts per plane (8.39M = 16.78 MB)

using short8_ = __attribute__((ext_vector_type(8))) short;
using f32x4_  = __attribute__((ext_vector_type(4))) float;

// =====================================================================
// exact bf16 triple-split of fp32 (truncation-based): f = h0 + h1 + h2
// (every op is exact in IEEE fp32 -> bit-deterministic across kernels)
// =====================================================================
__device__ __forceinline__ void bf3split(float f, short& h0, short& h1, short& h2)
{
  unsigned u0 = __float_as_uint(f);
  float f0 = __uint_as_float(u0 & 0xFFFF0000u);
  h0 = (short)(u0 >> 16);
  float r1 = f - f0;
  unsigned u1 = __float_as_uint(r1);
  float f1 = __uint_as_float(u1 & 0xFFFF0000u);
  h1 = (short)(u1 >> 16);
  float r2 = r1 - f1;                 // <= 8 significant bits: bf16-exact
  h2 = (short)(__float_as_uint(r2) >> 16);
}

// sorted-DESCENDING 32-entry list (Lv[0] = largest kept)
__device__ __forceinline__ void insert32(float (&Lv)[32], int (&Li)[32], float x, int n)
{
  bool ci = x < Lv[0];
  #pragma unroll
  for (int i = 0; i < 31; ++i) {
    bool c1 = x < Lv[i+1];
    float nv = c1 ? Lv[i+1] : (ci ? x : Lv[i]);
    int   ni = c1 ? Li[i+1] : (ci ? n : Li[i]);
    Lv[i] = nv; Li[i] = ni;
    ci = c1;
  }
  Lv[31] = ci ? x : Lv[31];
  Li[31] = ci ? n : Li[31];
}

// =====================================================================
// K1 (fast path): sqn + new_xyz gather + fragment-major bf16x3 planes
// sqn uses the EXACT round-3 expression/order (bit-identical keys ->
// bit-identical selection vs the passing round-3 run).
// plane layout: off(b,n,k) = ((((b*256 + n>>6)*4 + (n>>4)&3)*2 + k>>5)*64
//                             + ((k>>3)&3)*16 + (n&15))*8 + (k&7)
// =====================================================================
__global__ __launch_bounds__(256) void k_prep(
    const float* __restrict__ xyz, const float* __restrict__ points,
    const int* __restrict__ sidx, float* __restrict__ out, float* __restrict__ sqn,
    short* __restrict__ P0, short* __restrict__ P1, short* __restrict__ P2)
{
  int tid = blockIdx.x * 256 + threadIdx.x;      // 0 .. B*N-1
  const float4* p = (const float4*)(points + (size_t)tid * 64);

  // ---- sqnorm: verbatim round-3 loop (bit-identical contraction) ----
  float s = 0.f;
  #pragma unroll
  for (int i = 0; i < 16; ++i) {
    float4 v = p[i];
    s += v.x*v.x + v.y*v.y + v.z*v.z + v.w*v.w;
  }
  sqn[tid] = s;

  // ---- fragment-major bf16x3 planes ----
  int n = tid & (N_-1);
  int c = n >> 6, ct = (n >> 4) & 3, mc = n & 15;
  size_t segbase = (((size_t)(tid >> 14) * 256 + c) * 4 + ct) * 2;  // *512 shorts

  #pragma unroll
  for (int g = 0; g < 8; ++g) {                  // (kt=g>>2, qd=g&3), dims 8g..8g+7
    float4 a = p[2*g], b4 = p[2*g+1];
    float f[8] = {a.x,a.y,a.z,a.w, b4.x,b4.y,b4.z,b4.w};
    short8_ h0v, h1v, h2v;
    #pragma unroll
    for (int j = 0; j < 8; ++j) {
      short h0, h1, h2;
      bf3split(f[j], h0, h1, h2);
      h0v[j] = h0; h1v[j] = h1; h2v[j] = h2;
    }
    size_t off = ((segbase + (g>>2))*64 + (size_t)(g&3)*16 + mc)*8;
    *(short8_*)(P0 + off) = h0v;
    *(short8_*)(P1 + off) = h1v;
    *(short8_*)(P2 + off) = h2v;
  }
  if (tid < B_*S_) {
    int b = tid >> 11, ss = tid & (S_-1);
    int nn = sidx[ss];
    const float* src = xyz + ((size_t)b * N_ + nn) * 3;
    out[(size_t)tid*3+0] = src[0];
    out[(size_t)tid*3+1] = src[1];
    out[(size_t)tid*3+2] = src[2];
  }
}

// =====================================================================
// K2 (fast path): MFMA over pre-split planes + mask-then-insert top-32
// NOTE: plain __launch_bounds__(256) — a min-waves/EU of 4 caps VGPR at
// 128 and spills Lv/Li to scratch (r5: 100 GB HBM spill traffic, 30x
// regression). ~104 VGPR still gives 4 waves/SIMD with zero spill.
// =====================================================================
__global__ __launch_bounds__(256) void k_knn(
    const short* __restrict__ P0, const short* __restrict__ P1,
    const short* __restrict__ P2, const int* __restrict__ sidx,
    const float* __restrict__ sqn, uint2* __restrict__ pw)
{
  // LDS: Bp [12 segs][64 lanes][8 shorts] = 12288 B | Dt [32c][68r] f32 = 8704 B
  //      | sqc [32] f32. merge phase aliases all as uint2 mbuf[32][130] = 33280 B
  __shared__ __align__(16) char smraw[33280];
  short* Bp  = (short*)smraw;
  float* Dt  = (float*)(smraw + 12288);
  float* sqc = (float*)(smraw + 20992);

  const int t = threadIdx.x;
  const int b     = blockIdx.x & 7;          // XCD swizzle
  const int y     = blockIdx.x >> 3;
  const int tile  = y & 31;
  const int split = y >> 5;
  const int s0 = tile * 64;
  const float* Qb = sqn + (size_t)b * N_;

  const int lane = t & 63, wv = t >> 6;
  const int quad = lane >> 4, mcol = lane & 15;

  // ---- A fragments (wave wv owns sampled rows 16*wv..+15), from planes ----
  short8_ A0[2], A1[2], A2[2];
  {
    int srow = sidx[s0 + 16*wv + mcol];
    int cs = srow >> 6, cts = (srow >> 4) & 3, ms = srow & 15;
    size_t ab = (((size_t)(b*256 + cs))*4 + cts)*2*512 + ((size_t)quad*16 + ms)*8;
    #pragma unroll
    for (int kt = 0; kt < 2; ++kt) {
      A0[kt] = *(const short8_*)(P0 + ab + kt*512);
      A1[kt] = *(const short8_*)(P1 + ab + kt*512);
      A2[kt] = *(const short8_*)(P2 + ab + kt*512);
    }
  }

  float Lv[32]; int Li[32];
  #pragma unroll
  for (int i = 0; i < 32; ++i) { Lv[i] = 3.0e38f; Li[i] = 0; }

  const int r = t >> 2;        // selection row 0..63
  const int q = t & 3;         // stream within row
  const int n0base = split * NSPL_;
  const size_t bc8base = (size_t)b * 256;

  for (int ch = 0; ch < CH32_; ++ch) {
    const int n0 = n0base + ch * 32;
    const int c64 = n0 >> 6, half = (n0 >> 5) & 1;
    // ---- stage 12 segments (3 planes x 2 ct x 2 kt), 1 KB each ----
    {
      const size_t bc8 = (bc8base + c64) * 8;
      #pragma unroll
      for (int rep = 0; rep < 3; ++rep) {
        int task = rep*256 + t;
        int seg = task >> 6, ln = task & 63;
        int pl = seg >> 2, rem = seg & 3;        // rem = ctl*2 + kt
        int st = (half*2 + (rem>>1))*2 + (rem&1);
        const short* Pp = (pl == 0) ? P0 : (pl == 1) ? P1 : P2;
        short8_ v = *(const short8_*)(Pp + (bc8 + st)*512 + (size_t)ln*8);
        *(short8_*)(Bp + seg*512 + ln*8) = v;
      }
      if (t < 8) *(float4*)(sqc + 4*t) = *(const float4*)(Qb + n0 + 4*t);
    }
    __syncthreads();

    // ---- 16 MFMA per 16-cand tile (8 combos x 2 kt), 2 tiles ----
    #pragma unroll
    for (int ct = 0; ct < 2; ++ct) {
      short8_ b0[2], b1[2], b2[2];
      #pragma unroll
      for (int kt = 0; kt < 2; ++kt) {
        int lo = lane*8;
        b0[kt] = *(const short8_*)(Bp + (0*4 + ct*2 + kt)*512 + lo);
        b1[kt] = *(const short8_*)(Bp + (1*4 + ct*2 + kt)*512 + lo);
        b2[kt] = *(const short8_*)(Bp + (2*4 + ct*2 + kt)*512 + lo);
      }
      f32x4_ a = {0.f, 0.f, 0.f, 0.f};
      #pragma unroll
      for (int kt = 0; kt < 2; ++kt) {
        a = __builtin_amdgcn_mfma_f32_16x16x32_bf16(A0[kt], b0[kt], a, 0,0,0);
        a = __builtin_amdgcn_mfma_f32_16x16x32_bf16(A0[kt], b1[kt], a, 0,0,0);
        a = __builtin_amdgcn_mfma_f32_16x16x32_bf16(A1[kt], b0[kt], a, 0,0,0);
        a = __builtin_amdgcn_mfma_f32_16x16x32_bf16(A1[kt], b1[kt], a, 0,0,0);
        a = __builtin_amdgcn_mfma_f32_16x16x32_bf16(A0[kt], b2[kt], a, 0,0,0);
        a = __builtin_amdgcn_mfma_f32_16x16x32_bf16(A2[kt], b0[kt], a, 0,0,0);
        a = __builtin_amdgcn_mfma_f32_16x16x32_bf16(A1[kt], b2[kt], a, 0,0,0);
        a = __builtin_amdgcn_mfma_f32_16x16x32_bf16(A2[kt], b1[kt], a, 0,0,0);
      }
      // keys -> Dt col-major. C/D: col=lane&15, row=quad*4+reg
      int cc = 16*ct + mcol;
      float sq = sqc[cc];
      float4 kv;
      kv.x = sq - 2.f*a[0];
      kv.y = sq - 2.f*a[1];
      kv.z = sq - 2.f*a[2];
      kv.w = sq - 2.f*a[3];
      *(float4*)(Dt + cc*68 + 16*wv + 4*quad) = kv;
    }
    __syncthreads();

    // ---- selection: mask survivors, then lane-parallel insert ----
    float L0 = Lv[0];
    L0 = fminf(L0, __shfl_xor(L0, 1));
    L0 = fminf(L0, __shfl_xor(L0, 2));
    const float tau = L0;
    const float thr = fminf(tau, Lv[0]);

    unsigned m = 0;
    #pragma unroll
    for (int i = 0; i < 8; ++i) {
      float x = Dt[(q*8 + i)*68 + r];
      m |= (x < thr) ? (1u << i) : 0u;
    }
    while (__any(m != 0)) {
      if (m) {
        int i = __ffs(m) - 1;
        m &= m - 1;
        float x = Dt[(q*8 + i)*68 + r];
        if (x < Lv[0])
          insert32(Lv, Li, x, n0 + q*8 + i);
      }
    }
  }

  // ---- in-block 4-pointer merge (streams stored reversed -> ascending) ----
  uint2* mbuf = (uint2*)smraw;                 // [32][130]
  const int rowg = b * S_ + s0;
  for (int pass = 0; pass < 2; ++pass) {
    __syncthreads();
    const int rb = pass * 32;
    if (r >= rb && r < rb + 32) {
      #pragma unroll
      for (int i = 0; i < 32; ++i)
        mbuf[(r - rb)*130 + q*32 + (31 - i)] =
            make_uint2(__float_as_uint(Lv[i]), (unsigned)Li[i]);
    }
    __syncthreads();
    if (t < 32) {
      const uint2* Lrow = mbuf + t*130;
      uint2* dst = pw + ((size_t)(rowg + rb + t) * SPLIT_ + split) * 32;
      int p0 = 0, p1 = 0, p2 = 0, p3 = 0;
      for (int k = 0; k < 32; ++k) {
        float bv = 3.0e38f; unsigned bi = 0xFFFFFFFFu; int bq = 0;
        int pa[4] = {p0, p1, p2, p3};
        #pragma unroll
        for (int q4 = 0; q4 < 4; ++q4) {
          if (pa[q4] < 32) {
            uint2 e = Lrow[q4*32 + pa[q4]];
            float v = __uint_as_float(e.x);
            if (v < bv || (v == bv && e.y < bi)) { bv = v; bi = e.y; bq = q4; }
          }
        }
        dst[k] = make_uint2(__float_as_uint(bv), bi);
        if (bq == 0) p0++; else if (bq == 1) p1++; else if (bq == 2) p2++; else p3++;
      }
    }
  }
}

// =====================================================================
// FALLBACK path (ws too small): round-3 kernels, proven correct
// =====================================================================
__global__ __launch_bounds__(256) void k_prep_fb(
    const float* __restrict__ xyz, const float* __restrict__ points,
    const int* __restrict__ sidx, float* __restrict__ out, float* __restrict__ sqn)
{
  int tid = blockIdx.x * 256 + threadIdx.x;
  const float4* p = (const float4*)(points + (size_t)tid * 64);
  float s = 0.f;
  #pragma unroll
  for (int i = 0; i < 16; ++i) {
    float4 v = p[i];
    s += v.x*v.x + v.y*v.y + v.z*v.z + v.w*v.w;
  }
  sqn[tid] = s;
  if (tid < B_*S_) {
    int b = tid >> 11, ss = tid & (S_-1);
    int n = sidx[ss];
    const float* src = xyz + ((size_t)b * N_ + n) * 3;
    out[(size_t)tid*3+0] = src[0];
    out[(size_t)tid*3+1] = src[1];
    out[(size_t)tid*3+2] = src[2];
  }
}

__global__ __launch_bounds__(256) void k_knn_fb(
    const float* __restrict__ points, const int* __restrict__ sidx,
    const float* __restrict__ sqn, uint2* __restrict__ pw)
{
  __shared__ __align__(16) char smraw[45312];
  short* Bp0 = (short*)smraw;
  short* Bp1 = (short*)(smraw + 9216);
  short* Bp2 = (short*)(smraw + 18432);
  float* Dt  = (float*)(smraw + 27648);
  float* sqc = (float*)(smraw + 45056);

  const int t = threadIdx.x;
  const int b     = blockIdx.x & 7;
  const int y     = blockIdx.x >> 3;
  const int tile  = y & 31;
  const int split = y >> 5;
  const int s0 = tile * 64;
  const float* Pb = points + (size_t)b * N_ * 64;
  const float* Qb = sqn    + (size_t)b * N_;

  const int lane = t & 63, wv = t >> 6;
  const int quad = lane >> 4, mcol = lane & 15;

  short8_ A0[2], A1[2], A2[2];
  {
    int srow = sidx[s0 + 16*wv + mcol];
    const float* ar = Pb + (size_t)srow * 64;
    #pragma unroll
    for (int kt = 0; kt < 2; ++kt) {
      float4 v0 = *(const float4*)(ar + 32*kt + 8*quad);
      float4 v1 = *(const float4*)(ar + 32*kt + 8*quad + 4);
      float f[8] = {v0.x,v0.y,v0.z,v0.w,v1.x,v1.y,v1.z,v1.w};
      #pragma unroll
      for (int j = 0; j < 8; ++j) {
        short h0, h1, h2;
        bf3split(f[j], h0, h1, h2);
        A0[kt][j] = h0; A1[kt][j] = h1; A2[kt][j] = h2;
      }
    }
  }

  float Lv[32]; int Li[32];
  #pragma unroll
  for (int i = 0; i < 32; ++i) { Lv[i] = 3.0e38f; Li[i] = 0; }

  const int r = t >> 2;
  const int q = t & 3;
  const int n0base = split * NSPL_;

  for (int ch = 0; ch < NSPL_/64; ++ch) {
    const int n0 = n0base + ch * 64;
    {
      const int n = t & 63, jg = t >> 6;
      const float* src = Pb + (size_t)(n0 + n) * 64 + 16*jg;
      float4 u0 = *(const float4*)(src);
      float4 u1 = *(const float4*)(src + 4);
      float4 u2 = *(const float4*)(src + 8);
      float4 u3 = *(const float4*)(src + 12);
      float f[16] = {u0.x,u0.y,u0.z,u0.w, u1.x,u1.y,u1.z,u1.w,
                     u2.x,u2.y,u2.z,u2.w, u3.x,u3.y,u3.z,u3.w};
      short8_ p0[2], p1[2], p2[2];
      #pragma unroll
      for (int j = 0; j < 16; ++j) {
        short h0, h1, h2;
        bf3split(f[j], h0, h1, h2);
        p0[j>>3][j&7] = h0; p1[j>>3][j&7] = h1; p2[j>>3][j&7] = h2;
      }
      *(short8_*)(Bp0 + n*72 + 16*jg)     = p0[0];
      *(short8_*)(Bp0 + n*72 + 16*jg + 8) = p0[1];
      *(short8_*)(Bp1 + n*72 + 16*jg)     = p1[0];
      *(short8_*)(Bp1 + n*72 + 16*jg + 8) = p1[1];
      *(short8_*)(Bp2 + n*72 + 16*jg)     = p2[0];
      *(short8_*)(Bp2 + n*72 + 16*jg + 8) = p2[1];
      if (t < 16) *(float4*)(sqc + 4*t) = *(const float4*)(Qb + n0 + 4*t);
    }
    __syncthreads();

    f32x4_ acc[4];
    #pragma unroll
    for (int ct = 0; ct < 4; ++ct) {
      const int boff = (16*ct + mcol)*72 + 8*quad;
      short8_ b0[2], b1[2], b2[2];
      b0[0] = *(const short8_*)(Bp0 + boff); b0[1] = *(const short8_*)(Bp0 + boff + 32);
      b1[0] = *(const short8_*)(Bp1 + boff); b1[1] = *(const short8_*)(Bp1 + boff + 32);
      b2[0] = *(const short8_*)(Bp2 + boff); b2[1] = *(const short8_*)(Bp2 + boff + 32);
      f32x4_ a = {0.f, 0.f, 0.f, 0.f};
      #pragma unroll
      for (int kt = 0; kt < 2; ++kt) {
        a = __builtin_amdgcn_mfma_f32_16x16x32_bf16(A0[kt], b0[kt], a, 0,0,0);
        a = __builtin_amdgcn_mfma_f32_16x16x32_bf16(A0[kt], b1[kt], a, 0,0,0);
        a = __builtin_amdgcn_mfma_f32_16x16x32_bf16(A1[kt], b0[kt], a, 0,0,0);
        a = __builtin_amdgcn_mfma_f32_16x16x32_bf16(A1[kt], b1[kt], a, 0,0,0);
        a = __builtin_amdgcn_mfma_f32_16x16x32_bf16(A0[kt], b2[kt], a, 0,0,0);
        a = __builtin_amdgcn_mfma_f32_16x16x32_bf16(A2[kt], b0[kt], a, 0,0,0);
        a = __builtin_amdgcn_mfma_f32_16x16x32_bf16(A1[kt], b2[kt], a, 0,0,0);
        a = __builtin_amdgcn_mfma_f32_16x16x32_bf16(A2[kt], b1[kt], a, 0,0,0);
      }
      acc[ct] = a;
    }
    #pragma unroll
    for (int ct = 0; ct < 4; ++ct) {
      int c = 16*ct + mcol;
      float sq = sqc[c];
      float4 kv;
      kv.x = sq - 2.f*acc[ct][0];
      kv.y = sq - 2.f*acc[ct][1];
      kv.z = sq - 2.f*acc[ct][2];
      kv.w = sq - 2.f*acc[ct][3];
      *(float4*)(Dt + c*68 + 16*wv + 4*quad) = kv;
    }
    __syncthreads();

    float L0 = Lv[0];
    L0 = fminf(L0, __shfl_xor(L0, 1));
    L0 = fminf(L0, __shfl_xor(L0, 2));
    const float tau = L0;
    #pragma unroll
    for (int g = 0; g < 4; ++g) {
      #pragma unroll
      for (int u = 0; u < 4; ++u) {
        int c = q*16 + g*4 + u;
        float x = Dt[c*68 + r];
        if (x < fminf(tau, Lv[0]))
          insert32(Lv, Li, x, n0 + c);
      }
    }
  }

  uint2* mbuf = (uint2*)smraw;
  const int rowg = b * S_ + s0;
  for (int pass = 0; pass < 2; ++pass) {
    __syncthreads();
    const int rb = pass * 32;
    if (r >= rb && r < rb + 32) {
      #pragma unroll
      for (int i = 0; i < 32; ++i)
        mbuf[(r - rb)*130 + q*32 + (31 - i)] =
            make_uint2(__float_as_uint(Lv[i]), (unsigned)Li[i]);
    }
    __syncthreads();
    if (t < 32) {
      const uint2* Lrow = mbuf + t*130;
      uint2* dst = pw + ((size_t)(rowg + rb + t) * SPLIT_ + split) * 32;
      int p0 = 0, p1 = 0, p2 = 0, p3 = 0;
      for (int k = 0; k < 32; ++k) {
        float bv = 3.0e38f; unsigned bi = 0xFFFFFFFFu; int bq = 0;
        int pa[4] = {p0, p1, p2, p3};
        #pragma unroll
        for (int q4 = 0; q4 < 4; ++q4) {
          if (pa[q4] < 32) {
            uint2 e = Lrow[q4*32 + pa[q4]];
            float v = __uint_as_float(e.x);
            if (v < bv || (v == bv && e.y < bi)) { bv = v; bi = e.y; bq = q4; }
          }
        }
        dst[k] = make_uint2(__float_as_uint(bv), bi);
        if (bq == 0) p0++; else if (bq == 1) p1++; else if (bq == 2) p2++; else p3++;
      }
    }
  }
}

// =====================================================================
// K2b: merge the 4 split-partials (ascending) per row -> 32 indices
// =====================================================================
__global__ __launch_bounds__(256) void k_sel(const uint2* __restrict__ pw,
                                             int* __restrict__ nbr)
{
  int row = blockIdx.x * 256 + threadIdx.x;       // 0 .. B*S-1
  const uint2* L = pw + (size_t)row * (SPLIT_*32);
  int* dst = nbr + (size_t)row * K_;
  int p[4] = {0,0,0,0};
  for (int k = 0; k < K_; ++k) {
    float bv = 3.0e38f; unsigned bi = 0xFFFFFFFFu; int bq = 0;
    #pragma unroll
    for (int q4 = 0; q4 < 4; ++q4) {
      if (p[q4] < 32) {
        uint2 e = L[q4*32 + p[q4]];
        float v = __uint_as_float(e.x);
        if (v < bv || (v == bv && e.y < bi)) { bv = v; bi = e.y; bq = q4; }
      }
    }
    dst[k] = (int)bi;
    p[bq]++;
  }
}

// =====================================================================
// K3: gather + 3-layer MLP (BN folded) + maxpool over 32 neighbors
// =====================================================================
__device__ __forceinline__ void layer64(
    const int t, const float* __restrict__ w, const float* __restrict__ bb,
    const float* __restrict__ gg, const float* __restrict__ be,
    const float* __restrict__ mm, const float* __restrict__ vv,
    const float* Xin, float* Hout, float* W, float* scl, float* bia)
{
  if (t < 64) {
    float sc = gg[t] * rsqrtf(vv[t] + 1e-5f);
    scl[t] = sc;
    bia[t] = (bb[t] - mm[t]) * sc + be[t];
  }
  __syncthreads();
  #pragma unroll
  for (int k = 0; k < 4; ++k) {
    int flat = k*256 + t;
    int o = flat >> 4, j = flat & 15;
    float4 v = *(const float4*)(w + o*64 + j*4);
    float sc = scl[o];
    v.x *= sc; v.y *= sc; v.z *= sc; v.w *= sc;
    *(float4*)(W + o*68 + j*4) = v;
  }
  __syncthreads();
  const int o0 = (t & 15) * 4;
  const int rp = t >> 4;
  float acc[2][4] = {};
  #pragma unroll 4
  for (int c4 = 0; c4 < 16; ++c4) {
    float4 xa = *(const float4*)(Xin + (2*rp)*68   + c4*4);
    float4 xb = *(const float4*)(Xin + (2*rp+1)*68 + c4*4);
    #pragma unroll
    for (int j = 0; j < 4; ++j) {
      float4 wv = *(const float4*)(W + (o0+j)*68 + c4*4);
      acc[0][j] = fmaf(xa.x,wv.x, fmaf(xa.y,wv.y, fmaf(xa.z,wv.z, fmaf(xa.w,wv.w, acc[0][j]))));
      acc[1][j] = fmaf(xb.x,wv.x, fmaf(xb.y,wv.y, fmaf(xb.z,wv.z, fmaf(xb.w,wv.w, acc[1][j]))));
    }
  }
  #pragma unroll
  for (int j = 0; j < 4; ++j) {
    Hout[(2*rp)*68   + o0+j] = fmaxf(acc[0][j] + bia[o0+j], 0.f);
    Hout[(2*rp+1)*68 + o0+j] = fmaxf(acc[1][j] + bia[o0+j], 0.f);
  }
  __syncthreads();
}

__global__ __launch_bounds__(256) void k_mlp(
    const float* __restrict__ points, const int* __restrict__ nbr,
    const float* __restrict__ w0, const float* __restrict__ b0,
    const float* __restrict__ g0, const float* __restrict__ be0,
    const float* __restrict__ m0, const float* __restrict__ v0,
    const float* __restrict__ w1, const float* __restrict__ b1,
    const float* __restrict__ g1, const float* __restrict__ be1,
    const float* __restrict__ m1, const float* __restrict__ v1,
    const float* __restrict__ w2, const float* __restrict__ b2,
    const float* __restrict__ g2, const float* __restrict__ be2,
    const float* __restrict__ m2, const float* __restrict__ v2,
    float* __restrict__ out)
{
  __shared__ float X[32*68];
  __shared__ float H[32*68];
  __shared__ float W[128*68];
  __shared__ float scl[128];
  __shared__ float bia[128];
  __shared__ int   nIx[32];

  const int t  = threadIdx.x;
  const int bs = blockIdx.x;
  const int b  = bs >> 11;

  if (t < 32) nIx[t] = nbr[(size_t)bs * K_ + t];
  __syncthreads();
  #pragma unroll
  for (int k = 0; k < 2; ++k) {
    int flat = k*256 + t;
    int row = flat >> 4, j = flat & 15;
    float4 v = *(const float4*)(points + ((size_t)b*N_ + nIx[row])*64 + j*4);
    *(float4*)(X + row*68 + j*4) = v;
  }
  __syncthreads();

  layer64(t, w0, b0, g0, be0, m0, v0, X, H, W, scl, bia);
  layer64(t, w1, b1, g1, be1, m1, v1, H, X, W, scl, bia);

  if (t < 128) {
    float sc = g2[t] * rsqrtf(v2[t] + 1e-5f);
    scl[t] = sc;
    bia[t] = (b2[t] - m2[t]) * sc + be2[t];
  }
  __syncthreads();
  #pragma unroll
  for (int k = 0; k < 8; ++k) {
    int flat = k*256 + t;
    int o = flat >> 4, j = flat & 15;
    float4 v = *(const float4*)(w2 + o*64 + j*4);
    float sc = scl[o];
    v.x *= sc; v.y *= sc; v.z *= sc; v.w *= sc;
    *(float4*)(W + o*68 + j*4) = v;
  }
  __syncthreads();
  {
    const int o0 = (t & 31) * 4;
    const int rq = t >> 5;
    float acc[4][4] = {};
    #pragma unroll 4
    for (int c4 = 0; c4 < 16; ++c4) {
      float4 xr[4];
      #pragma unroll
      for (int i = 0; i < 4; ++i) xr[i] = *(const float4*)(X + (4*rq+i)*68 + c4*4);
      #pragma unroll
      for (int j = 0; j < 4; ++j) {
        float4 wv = *(const float4*)(W + (o0+j)*68 + c4*4);
        #pragma unroll
        for (int i = 0; i < 4; ++i)
          acc[i][j] = fmaf(xr[i].x,wv.x, fmaf(xr[i].y,wv.y, fmaf(xr[i].z,wv.z, fmaf(xr[i].w,wv.w, acc[i][j]))));
      }
    }
    float pm[4];
    #pragma unroll
    for (int j = 0; j < 4; ++j) {
      float m = -3.0e38f;
      #pragma unroll
      for (int i = 0; i < 4; ++i)
        m = fmaxf(m, fmaxf(acc[i][j] + bia[o0+j], 0.f));
      pm[j] = m;
    }
    __syncthreads();
    *(float4*)(H + rq*132 + o0) = make_float4(pm[0], pm[1], pm[2], pm[3]);
  }
  __syncthreads();
  if (t < 128) {
    float m = -3.0e38f;
    #pragma unroll
    for (int rq = 0; rq < 8; ++rq) m = fmaxf(m, H[rq*132 + t]);
    out[(size_t)(B_*S_*3) + (size_t)bs*128 + t] = m;
  }
}

// =====================================================================
extern "C" void kernel_launch(void* const* d_in, const int* in_sizes, int n_in,
                              void* d_out, int out_size, void* d_ws, size_t ws_size,
                              hipStream_t stream)
{
  const float* xyz  = (const float*)d_in[0];
  const float* pts  = (const float*)d_in[1];
  const int*   sidx = (const int*)  d_in[2];
  const float* w0 = (const float*)d_in[3];
  const float* b0 = (const float*)d_in[4];
  const float* g0 = (const float*)d_in[5];
  const float* be0= (const float*)d_in[6];
  const float* m0 = (const float*)d_in[7];
  const float* v0 = (const float*)d_in[8];
  const float* w1 = (const float*)d_in[9];
  const float* b1 = (const float*)d_in[10];
  const float* g1 = (const float*)d_in[11];
  const float* be1= (const float*)d_in[12];
  const float* m1 = (const float*)d_in[13];
  const float* v1 = (const float*)d_in[14];
  const float* w2 = (const float*)d_in[15];
  const float* b2 = (const float*)d_in[16];
  const float* g2 = (const float*)d_in[17];
  const float* be2= (const float*)d_in[18];
  const float* m2 = (const float*)d_in[19];
  const float* v2 = (const float*)d_in[20];

  float* out = (float*)d_out;
  // ws: sqn (512KB) | nbr (2MB) | pw (16.8MB) | planes (3 x 16.78MB)
  float* sqn = (float*)d_ws;
  int*   nbr = (int*)  ((char*)d_ws + (size_t)B_*N_*4);
  uint2* pw  = (uint2*)((char*)d_ws + (size_t)B_*N_*4 + (size_t)B_*S_*K_*4);
  char*  pl  = (char*)d_ws + (size_t)B_*N_*4 + (size_t)B_*S_*K_*4
             + (size_t)B_*S_*SPLIT_*32*8;
  short* P0 = (short*)pl;
  short* P1 = P0 + PLANE_;
  short* P2 = P1 + PLANE_;
  const size_t need = (size_t)B_*N_*4 + (size_t)B_*S_*K_*4
                    + (size_t)B_*S_*SPLIT_*32*8 + 3*PLANE_*2;

  if (ws_size >= need) {
    k_prep<<<(B_*N_)/256, 256, 0, stream>>>(xyz, pts, sidx, out, sqn, P0, P1, P2);
    k_knn <<<B_*32*SPLIT_, 256, 0, stream>>>(P0, P1, P2, sidx, sqn, pw);
  } else {
    k_prep_fb<<<(B_*N_)/256, 256, 0, stream>>>(xyz, pts, sidx, out, sqn);
    k_knn_fb <<<B_*32*SPLIT_, 256, 0, stream>>>(pts, sidx, sqn, pw);
  }
  k_sel <<<(B_*S_)/256, 256, 0, stream>>>(pw, nbr);
  k_mlp <<<B_*S_, 256, 0, stream>>>(pts, nbr,
            w0,b0,g0,be0,m0,v0, w1,b1,g1,be1,m1,v1, w2,b2,g2,be2,m2,v2, out);
}

// Round 7
// 2063.677 us; speedup vs baseline: 31.1686x; 1.1685x over previous
//
#include <hip/hip_runtime.h>

#define B_  8
#define N_  16384
#define D_  64
#define S_  2048
#define K_  32
#define SPLIT_  4
#define NSPL_   (N_/SPLIT_)       // 4096 candidates per block
#define CH32_   (NSPL_/32)        // 128 chunks of 32
#define PLANE_  ((size_t)B_*N_*64) // shorts per plane (8.39M = 16.78 MB)

using short8_ = __attribute__((ext_vector_type(8))) short;
using f32x4_  = __attribute__((ext_vector_type(4))) float;

// =====================================================================
// exact bf16 triple-split of fp32 (truncation-based): f = h0 + h1 + h2
// =====================================================================
__device__ __forceinline__ void bf3split(float f, short& h0, short& h1, short& h2)
{
  unsigned u0 = __float_as_uint(f);
  float f0 = __uint_as_float(u0 & 0xFFFF0000u);
  h0 = (short)(u0 >> 16);
  float r1 = f - f0;
  unsigned u1 = __float_as_uint(r1);
  float f1 = __uint_as_float(u1 & 0xFFFF0000u);
  h1 = (short)(u1 >> 16);
  float r2 = r1 - f1;                 // <= 8 significant bits: bf16-exact
  h2 = (short)(__float_as_uint(r2) >> 16);
}

// bf16 2-split of 8 floats (for the MLP; residual ~2^-16 rel)
__device__ __forceinline__ void bf2split8(const float* f, short8_& h0, short8_& h1)
{
  #pragma unroll
  for (int j = 0; j < 8; ++j) {
    unsigned u = __float_as_uint(f[j]);
    h0[j] = (short)(u >> 16);
    float r = f[j] - __uint_as_float(u & 0xFFFF0000u);
    h1[j] = (short)(__float_as_uint(r) >> 16);
  }
}

// sorted-DESCENDING 32-entry list (Lv[0] = largest kept)
__device__ __forceinline__ void insert32(float (&Lv)[32], int (&Li)[32], float x, int n)
{
  bool ci = x < Lv[0];
  #pragma unroll
  for (int i = 0; i < 31; ++i) {
    bool c1 = x < Lv[i+1];
    float nv = c1 ? Lv[i+1] : (ci ? x : Lv[i]);
    int   ni = c1 ? Li[i+1] : (ci ? n : Li[i]);
    Lv[i] = nv; Li[i] = ni;
    ci = c1;
  }
  Lv[31] = ci ? x : Lv[31];
  Li[31] = ci ? n : Li[31];
}

// =====================================================================
// K1 (fast path): sqn + new_xyz gather + fragment-major bf16x3 planes
// sqn: EXACT round-3 expression (bit-identical keys -> selection).
// =====================================================================
__global__ __launch_bounds__(256) void k_prep(
    const float* __restrict__ xyz, const float* __restrict__ points,
    const int* __restrict__ sidx, float* __restrict__ out, float* __restrict__ sqn,
    short* __restrict__ P0, short* __restrict__ P1, short* __restrict__ P2)
{
  int tid = blockIdx.x * 256 + threadIdx.x;      // 0 .. B*N-1
  const float4* p = (const float4*)(points + (size_t)tid * 64);

  float s = 0.f;
  #pragma unroll
  for (int i = 0; i < 16; ++i) {
    float4 v = p[i];
    s += v.x*v.x + v.y*v.y + v.z*v.z + v.w*v.w;
  }
  sqn[tid] = s;

  int n = tid & (N_-1);
  int c = n >> 6, ct = (n >> 4) & 3, mc = n & 15;
  size_t segbase = (((size_t)(tid >> 14) * 256 + c) * 4 + ct) * 2;  // *512 shorts

  #pragma unroll
  for (int g = 0; g < 8; ++g) {                  // (kt=g>>2, qd=g&3), dims 8g..8g+7
    float4 a = p[2*g], b4 = p[2*g+1];
    float f[8] = {a.x,a.y,a.z,a.w, b4.x,b4.y,b4.z,b4.w};
    short8_ h0v, h1v, h2v;
    #pragma unroll
    for (int j = 0; j < 8; ++j) {
      short h0, h1, h2;
      bf3split(f[j], h0, h1, h2);
      h0v[j] = h0; h1v[j] = h1; h2v[j] = h2;
    }
    size_t off = ((segbase + (g>>2))*64 + (size_t)(g&3)*16 + mc)*8;
    *(short8_*)(P0 + off) = h0v;
    *(short8_*)(P1 + off) = h1v;
    *(short8_*)(P2 + off) = h2v;
  }
  if (tid < B_*S_) {
    int b = tid >> 11, ss = tid & (S_-1);
    int nn = sidx[ss];
    const float* src = xyz + ((size_t)b * N_ + nn) * 3;
    out[(size_t)tid*3+0] = src[0];
    out[(size_t)tid*3+1] = src[1];
    out[(size_t)tid*3+2] = src[2];
  }
}

// =====================================================================
// K2 (fast path): MFMA over pre-split planes + mask-then-insert top-32
// Keys bit-identical to r3/r6.  Dtr is TRANSPOSED [row][cand] pitch 36:
// write-side conflict-free, selection reads 2x ds_read_b128 (2-way=free).
// =====================================================================
__global__ __launch_bounds__(256) void k_knn(
    const short* __restrict__ P0, const short* __restrict__ P1,
    const short* __restrict__ P2, const int* __restrict__ sidx,
    const float* __restrict__ sqn, uint2* __restrict__ pw)
{
  // LDS: Bp [12 segs][64 lanes][8 shorts] = 12288 | Dtr [64r][36c] f32 = 9216
  //      | sqc [32] f32.  merge aliases all as uint2 mbuf[32][130] = 33280
  __shared__ __align__(16) char smraw[33280];
  short* Bp  = (short*)smraw;
  float* Dtr = (float*)(smraw + 12288);
  float* sqc = (float*)(smraw + 21504);

  const int t = threadIdx.x;
  const int b     = blockIdx.x & 7;          // XCD swizzle
  const int y     = blockIdx.x >> 3;
  const int tile  = y & 31;
  const int split = y >> 5;
  const int s0 = tile * 64;
  const float* Qb = sqn + (size_t)b * N_;

  const int lane = t & 63, wv = t >> 6;
  const int quad = lane >> 4, mcol = lane & 15;

  // ---- A fragments (wave wv owns sampled rows 16*wv..+15), from planes ----
  short8_ A0[2], A1[2], A2[2];
  {
    int srow = sidx[s0 + 16*wv + mcol];
    int cs = srow >> 6, cts = (srow >> 4) & 3, ms = srow & 15;
    size_t ab = (((size_t)(b*256 + cs))*4 + cts)*2*512 + ((size_t)quad*16 + ms)*8;
    #pragma unroll
    for (int kt = 0; kt < 2; ++kt) {
      A0[kt] = *(const short8_*)(P0 + ab + kt*512);
      A1[kt] = *(const short8_*)(P1 + ab + kt*512);
      A2[kt] = *(const short8_*)(P2 + ab + kt*512);
    }
  }

  float Lv[32]; int Li[32];
  #pragma unroll
  for (int i = 0; i < 32; ++i) { Lv[i] = 3.0e38f; Li[i] = 0; }

  const int r = t >> 2;        // selection row 0..63
  const int q = t & 3;         // stream within row
  const int n0base = split * NSPL_;
  const size_t bc8base = (size_t)b * 256;
  const int segl = t >> 6, ln = t & 63;   // staging: seg-local 0..3, lane

  for (int ch = 0; ch < CH32_; ++ch) {
    const int n0 = n0base + ch * 32;
    const int c64 = n0 >> 6, half = (n0 >> 5) & 1;
    // ---- stage 12 segments (plane-per-rep hardcoded), 1 KB each ----
    {
      const size_t gsrc = (bc8base + c64) * 8 + (size_t)(half*4 + segl);
      const size_t goff = gsrc*512 + (size_t)ln*8;
      short8_ v0 = *(const short8_*)(P0 + goff);
      short8_ v1 = *(const short8_*)(P1 + goff);
      short8_ v2 = *(const short8_*)(P2 + goff);
      *(short8_*)(Bp + (0*4 + segl)*512 + ln*8) = v0;
      *(short8_*)(Bp + (1*4 + segl)*512 + ln*8) = v1;
      *(short8_*)(Bp + (2*4 + segl)*512 + ln*8) = v2;
      if (t < 8) *(float4*)(sqc + 4*t) = *(const float4*)(Qb + n0 + 4*t);
    }
    __syncthreads();

    // ---- 16 MFMA per 16-cand tile (8 combos x 2 kt), 2 tiles ----
    #pragma unroll
    for (int ct = 0; ct < 2; ++ct) {
      short8_ b0[2], b1[2], b2[2];
      #pragma unroll
      for (int kt = 0; kt < 2; ++kt) {
        int lo = lane*8;
        b0[kt] = *(const short8_*)(Bp + (0*4 + ct*2 + kt)*512 + lo);
        b1[kt] = *(const short8_*)(Bp + (1*4 + ct*2 + kt)*512 + lo);
        b2[kt] = *(const short8_*)(Bp + (2*4 + ct*2 + kt)*512 + lo);
      }
      f32x4_ a = {0.f, 0.f, 0.f, 0.f};
      #pragma unroll
      for (int kt = 0; kt < 2; ++kt) {
        a = __builtin_amdgcn_mfma_f32_16x16x32_bf16(A0[kt], b0[kt], a, 0,0,0);
        a = __builtin_amdgcn_mfma_f32_16x16x32_bf16(A0[kt], b1[kt], a, 0,0,0);
        a = __builtin_amdgcn_mfma_f32_16x16x32_bf16(A1[kt], b0[kt], a, 0,0,0);
        a = __builtin_amdgcn_mfma_f32_16x16x32_bf16(A1[kt], b1[kt], a, 0,0,0);
        a = __builtin_amdgcn_mfma_f32_16x16x32_bf16(A0[kt], b2[kt], a, 0,0,0);
        a = __builtin_amdgcn_mfma_f32_16x16x32_bf16(A2[kt], b0[kt], a, 0,0,0);
        a = __builtin_amdgcn_mfma_f32_16x16x32_bf16(A1[kt], b2[kt], a, 0,0,0);
        a = __builtin_amdgcn_mfma_f32_16x16x32_bf16(A2[kt], b1[kt], a, 0,0,0);
      }
      // keys -> Dtr transposed. C/D: col=lane&15, row=quad*4+reg
      int cc = 16*ct + mcol;
      float sq = sqc[cc];
      int rb = 16*wv + 4*quad;
      Dtr[(rb+0)*36 + cc] = sq - 2.f*a[0];
      Dtr[(rb+1)*36 + cc] = sq - 2.f*a[1];
      Dtr[(rb+2)*36 + cc] = sq - 2.f*a[2];
      Dtr[(rb+3)*36 + cc] = sq - 2.f*a[3];
    }
    __syncthreads();

    // ---- selection: vector-load keys, mask survivors, lane-par insert ----
    float L0 = Lv[0];
    L0 = fminf(L0, __shfl_xor(L0, 1));
    L0 = fminf(L0, __shfl_xor(L0, 2));
    const float tau = L0;
    const float thr = fminf(tau, Lv[0]);

    float4 ka = *(const float4*)(Dtr + r*36 + q*8);
    float4 kb = *(const float4*)(Dtr + r*36 + q*8 + 4);
    float x8[8] = {ka.x,ka.y,ka.z,ka.w, kb.x,kb.y,kb.z,kb.w};
    unsigned m = 0;
    #pragma unroll
    for (int i = 0; i < 8; ++i)
      m |= (x8[i] < thr) ? (1u << i) : 0u;
    while (__any(m != 0)) {
      if (m) {
        int i = __ffs(m) - 1;
        m &= m - 1;
        float x = Dtr[r*36 + q*8 + i];
        if (x < Lv[0])
          insert32(Lv, Li, x, n0 + q*8 + i);
      }
    }
  }

  // ---- in-block 4-pointer merge (streams stored reversed -> ascending) ----
  uint2* mbuf = (uint2*)smraw;                 // [32][130]
  const int rowg = b * S_ + s0;
  for (int pass = 0; pass < 2; ++pass) {
    __syncthreads();
    const int rb = pass * 32;
    if (r >= rb && r < rb + 32) {
      #pragma unroll
      for (int i = 0; i < 32; ++i)
        mbuf[(r - rb)*130 + q*32 + (31 - i)] =
            make_uint2(__float_as_uint(Lv[i]), (unsigned)Li[i]);
    }
    __syncthreads();
    if (t < 32) {
      const uint2* Lrow = mbuf + t*130;
      uint2* dst = pw + ((size_t)(rowg + rb + t) * SPLIT_ + split) * 32;
      int p0 = 0, p1 = 0, p2 = 0, p3 = 0;
      for (int k = 0; k < 32; ++k) {
        float bv = 3.0e38f; unsigned bi = 0xFFFFFFFFu; int bq = 0;
        int pa[4] = {p0, p1, p2, p3};
        #pragma unroll
        for (int q4 = 0; q4 < 4; ++q4) {
          if (pa[q4] < 32) {
            uint2 e = Lrow[q4*32 + pa[q4]];
            float v = __uint_as_float(e.x);
            if (v < bv || (v == bv && e.y < bi)) { bv = v; bi = e.y; bq = q4; }
          }
        }
        dst[k] = make_uint2(__float_as_uint(bv), bi);
        if (bq == 0) p0++; else if (bq == 1) p1++; else if (bq == 2) p2++; else p3++;
      }
    }
  }
}

// =====================================================================
// FALLBACK path (ws too small): round-3 kernels, proven correct
// =====================================================================
__global__ __launch_bounds__(256) void k_prep_fb(
    const float* __restrict__ xyz, const float* __restrict__ points,
    const int* __restrict__ sidx, float* __restrict__ out, float* __restrict__ sqn)
{
  int tid = blockIdx.x * 256 + threadIdx.x;
  const float4* p = (const float4*)(points + (size_t)tid * 64);
  float s = 0.f;
  #pragma unroll
  for (int i = 0; i < 16; ++i) {
    float4 v = p[i];
    s += v.x*v.x + v.y*v.y + v.z*v.z + v.w*v.w;
  }
  sqn[tid] = s;
  if (tid < B_*S_) {
    int b = tid >> 11, ss = tid & (S_-1);
    int n = sidx[ss];
    const float* src = xyz + ((size_t)b * N_ + n) * 3;
    out[(size_t)tid*3+0] = src[0];
    out[(size_t)tid*3+1] = src[1];
    out[(size_t)tid*3+2] = src[2];
  }
}

__global__ __launch_bounds__(256) void k_knn_fb(
    const float* __restrict__ points, const int* __restrict__ sidx,
    const float* __restrict__ sqn, uint2* __restrict__ pw)
{
  __shared__ __align__(16) char smraw[45312];
  short* Bp0 = (short*)smraw;
  short* Bp1 = (short*)(smraw + 9216);
  short* Bp2 = (short*)(smraw + 18432);
  float* Dt  = (float*)(smraw + 27648);
  float* sqc = (float*)(smraw + 45056);

  const int t = threadIdx.x;
  const int b     = blockIdx.x & 7;
  const int y     = blockIdx.x >> 3;
  const int tile  = y & 31;
  const int split = y >> 5;
  const int s0 = tile * 64;
  const float* Pb = points + (size_t)b * N_ * 64;
  const float* Qb = sqn    + (size_t)b * N_;

  const int lane = t & 63, wv = t >> 6;
  const int quad = lane >> 4, mcol = lane & 15;

  short8_ A0[2], A1[2], A2[2];
  {
    int srow = sidx[s0 + 16*wv + mcol];
    const float* ar = Pb + (size_t)srow * 64;
    #pragma unroll
    for (int kt = 0; kt < 2; ++kt) {
      float4 v0 = *(const float4*)(ar + 32*kt + 8*quad);
      float4 v1 = *(const float4*)(ar + 32*kt + 8*quad + 4);
      float f[8] = {v0.x,v0.y,v0.z,v0.w,v1.x,v1.y,v1.z,v1.w};
      #pragma unroll
      for (int j = 0; j < 8; ++j) {
        short h0, h1, h2;
        bf3split(f[j], h0, h1, h2);
        A0[kt][j] = h0; A1[kt][j] = h1; A2[kt][j] = h2;
      }
    }
  }

  float Lv[32]; int Li[32];
  #pragma unroll
  for (int i = 0; i < 32; ++i) { Lv[i] = 3.0e38f; Li[i] = 0; }

  const int r = t >> 2;
  const int q = t & 3;
  const int n0base = split * NSPL_;

  for (int ch = 0; ch < NSPL_/64; ++ch) {
    const int n0 = n0base + ch * 64;
    {
      const int n = t & 63, jg = t >> 6;
      const float* src = Pb + (size_t)(n0 + n) * 64 + 16*jg;
      float4 u0 = *(const float4*)(src);
      float4 u1 = *(const float4*)(src + 4);
      float4 u2 = *(const float4*)(src + 8);
      float4 u3 = *(const float4*)(src + 12);
      float f[16] = {u0.x,u0.y,u0.z,u0.w, u1.x,u1.y,u1.z,u1.w,
                     u2.x,u2.y,u2.z,u2.w, u3.x,u3.y,u3.z,u3.w};
      short8_ p0[2], p1[2], p2[2];
      #pragma unroll
      for (int j = 0; j < 16; ++j) {
        short h0, h1, h2;
        bf3split(f[j], h0, h1, h2);
        p0[j>>3][j&7] = h0; p1[j>>3][j&7] = h1; p2[j>>3][j&7] = h2;
      }
      *(short8_*)(Bp0 + n*72 + 16*jg)     = p0[0];
      *(short8_*)(Bp0 + n*72 + 16*jg + 8) = p0[1];
      *(short8_*)(Bp1 + n*72 + 16*jg)     = p1[0];
      *(short8_*)(Bp1 + n*72 + 16*jg + 8) = p1[1];
      *(short8_*)(Bp2 + n*72 + 16*jg)     = p2[0];
      *(short8_*)(Bp2 + n*72 + 16*jg + 8) = p2[1];
      if (t < 16) *(float4*)(sqc + 4*t) = *(const float4*)(Qb + n0 + 4*t);
    }
    __syncthreads();

    f32x4_ acc[4];
    #pragma unroll
    for (int ct = 0; ct < 4; ++ct) {
      const int boff = (16*ct + mcol)*72 + 8*quad;
      short8_ b0[2], b1[2], b2[2];
      b0[0] = *(const short8_*)(Bp0 + boff); b0[1] = *(const short8_*)(Bp0 + boff + 32);
      b1[0] = *(const short8_*)(Bp1 + boff); b1[1] = *(const short8_*)(Bp1 + boff + 32);
      b2[0] = *(const short8_*)(Bp2 + boff); b2[1] = *(const short8_*)(Bp2 + boff + 32);
      f32x4_ a = {0.f, 0.f, 0.f, 0.f};
      #pragma unroll
      for (int kt = 0; kt < 2; ++kt) {
        a = __builtin_amdgcn_mfma_f32_16x16x32_bf16(A0[kt], b0[kt], a, 0,0,0);
        a = __builtin_amdgcn_mfma_f32_16x16x32_bf16(A0[kt], b1[kt], a, 0,0,0);
        a = __builtin_amdgcn_mfma_f32_16x16x32_bf16(A1[kt], b0[kt], a, 0,0,0);
        a = __builtin_amdgcn_mfma_f32_16x16x32_bf16(A1[kt], b1[kt], a, 0,0,0);
        a = __builtin_amdgcn_mfma_f32_16x16x32_bf16(A0[kt], b2[kt], a, 0,0,0);
        a = __builtin_amdgcn_mfma_f32_16x16x32_bf16(A2[kt], b0[kt], a, 0,0,0);
        a = __builtin_amdgcn_mfma_f32_16x16x32_bf16(A1[kt], b2[kt], a, 0,0,0);
        a = __builtin_amdgcn_mfma_f32_16x16x32_bf16(A2[kt], b1[kt], a, 0,0,0);
      }
      acc[ct] = a;
    }
    #pragma unroll
    for (int ct = 0; ct < 4; ++ct) {
      int c = 16*ct + mcol;
      float sq = sqc[c];
      float4 kv;
      kv.x = sq - 2.f*acc[ct][0];
      kv.y = sq - 2.f*acc[ct][1];
      kv.z = sq - 2.f*acc[ct][2];
      kv.w = sq - 2.f*acc[ct][3];
      *(float4*)(Dt + c*68 + 16*wv + 4*quad) = kv;
    }
    __syncthreads();

    float L0 = Lv[0];
    L0 = fminf(L0, __shfl_xor(L0, 1));
    L0 = fminf(L0, __shfl_xor(L0, 2));
    const float tau = L0;
    #pragma unroll
    for (int g = 0; g < 4; ++g) {
      #pragma unroll
      for (int u = 0; u < 4; ++u) {
        int c = q*16 + g*4 + u;
        float x = Dt[c*68 + r];
        if (x < fminf(tau, Lv[0]))
          insert32(Lv, Li, x, n0 + c);
      }
    }
  }

  uint2* mbuf = (uint2*)smraw;
  const int rowg = b * S_ + s0;
  for (int pass = 0; pass < 2; ++pass) {
    __syncthreads();
    const int rb = pass * 32;
    if (r >= rb && r < rb + 32) {
      #pragma unroll
      for (int i = 0; i < 32; ++i)
        mbuf[(r - rb)*130 + q*32 + (31 - i)] =
            make_uint2(__float_as_uint(Lv[i]), (unsigned)Li[i]);
    }
    __syncthreads();
    if (t < 32) {
      const uint2* Lrow = mbuf + t*130;
      uint2* dst = pw + ((size_t)(rowg + rb + t) * SPLIT_ + split) * 32;
      int p0 = 0, p1 = 0, p2 = 0, p3 = 0;
      for (int k = 0; k < 32; ++k) {
        float bv = 3.0e38f; unsigned bi = 0xFFFFFFFFu; int bq = 0;
        int pa[4] = {p0, p1, p2, p3};
        #pragma unroll
        for (int q4 = 0; q4 < 4; ++q4) {
          if (pa[q4] < 32) {
            uint2 e = Lrow[q4*32 + pa[q4]];
            float v = __uint_as_float(e.x);
            if (v < bv || (v == bv && e.y < bi)) { bv = v; bi = e.y; bq = q4; }
          }
        }
        dst[k] = make_uint2(__float_as_uint(bv), bi);
        if (bq == 0) p0++; else if (bq == 1) p1++; else if (bq == 2) p2++; else p3++;
      }
    }
  }
}

// =====================================================================
// K2b: merge the 4 split-partials (ascending) per row -> 32 indices
// =====================================================================
__global__ __launch_bounds__(256) void k_sel(const uint2* __restrict__ pw,
                                             int* __restrict__ nbr)
{
  int row = blockIdx.x * 256 + threadIdx.x;       // 0 .. B*S-1
  const uint2* L = pw + (size_t)row * (SPLIT_*32);
  int* dst = nbr + (size_t)row * K_;
  int p[4] = {0,0,0,0};
  for (int k = 0; k < K_; ++k) {
    float bv = 3.0e38f; unsigned bi = 0xFFFFFFFFu; int bq = 0;
    #pragma unroll
    for (int q4 = 0; q4 < 4; ++q4) {
      if (p[q4] < 32) {
        uint2 e = L[q4*32 + p[q4]];
        float v = __uint_as_float(e.x);
        if (v < bv || (v == bv && e.y < bi)) { bv = v; bi = e.y; bq = q4; }
      }
    }
    dst[k] = (int)bi;
    p[bq]++;
  }
}

// =====================================================================
// K3: MFMA MLP (bf16 2-split) + fused bias/relu/maxpool.
// Xf/Hf fragment-major fp32: seg(mt,kt,h) = ((mt*2+kt)*2+h)*1024B,
// slot = lane*16B holds X[m = qk*16... see index math in layer_mfma.
// =====================================================================
__device__ __forceinline__ void layer_mfma(
    int lane, int wv, const float* Xf, float* Hf,
    const float* __restrict__ wgt, const float* scl, const float* bia)
{
  const int quad = lane >> 4, mcol = lane & 15;
  const int o = wv*16 + mcol;                 // this wave's output column
  const float sc = scl[o];
  short8_ B0[2], B1[2];
  #pragma unroll
  for (int kt = 0; kt < 2; ++kt) {
    const float* wp = wgt + o*64 + kt*32 + quad*8;
    float4 u0 = *(const float4*)(wp);
    float4 u1 = *(const float4*)(wp + 4);
    float f[8] = {u0.x*sc,u0.y*sc,u0.z*sc,u0.w*sc,
                  u1.x*sc,u1.y*sc,u1.z*sc,u1.w*sc};
    bf2split8(f, B0[kt], B1[kt]);
  }
  const float bo = bia[o];
  const int kt2 = (o >> 5) & 1, qk2 = (o >> 3) & 3, h2 = (o >> 2) & 1, j2 = o & 3;
  #pragma unroll
  for (int mt = 0; mt < 2; ++mt) {
    short8_ A0[2], A1[2];
    #pragma unroll
    for (int kt = 0; kt < 2; ++kt) {
      float4 x0 = *(const float4*)(Xf + (((mt*2+kt)*2+0)*256) + lane*4);
      float4 x1 = *(const float4*)(Xf + (((mt*2+kt)*2+1)*256) + lane*4);
      float f[8] = {x0.x,x0.y,x0.z,x0.w, x1.x,x1.y,x1.z,x1.w};
      bf2split8(f, A0[kt], A1[kt]);
    }
    f32x4_ a = {0.f, 0.f, 0.f, 0.f};
    #pragma unroll
    for (int kt = 0; kt < 2; ++kt) {
      a = __builtin_amdgcn_mfma_f32_16x16x32_bf16(A0[kt], B0[kt], a, 0,0,0);
      a = __builtin_amdgcn_mfma_f32_16x16x32_bf16(A0[kt], B1[kt], a, 0,0,0);
      a = __builtin_amdgcn_mfma_f32_16x16x32_bf16(A1[kt], B0[kt], a, 0,0,0);
    }
    #pragma unroll
    for (int reg = 0; reg < 4; ++reg) {
      int ml = quad*4 + reg;                  // m within mtile
      float hval = fmaxf(a[reg] + bo, 0.f);
      Hf[((mt*2 + kt2)*2 + h2)*256 + (qk2*16 + ml)*4 + j2] = hval;
    }
  }
}

__global__ __launch_bounds__(256) void k_mlp(
    const float* __restrict__ points, const int* __restrict__ nbr,
    const float* __restrict__ w0, const float* __restrict__ b0,
    const float* __restrict__ g0, const float* __restrict__ be0,
    const float* __restrict__ m0, const float* __restrict__ v0,
    const float* __restrict__ w1, const float* __restrict__ b1,
    const float* __restrict__ g1, const float* __restrict__ be1,
    const float* __restrict__ m1, const float* __restrict__ v1,
    const float* __restrict__ w2, const float* __restrict__ b2,
    const float* __restrict__ g2, const float* __restrict__ be2,
    const float* __restrict__ m2, const float* __restrict__ v2,
    float* __restrict__ out)
{
  __shared__ __align__(16) float Xf[2048];   // 8 segs x 1KB
  __shared__ __align__(16) float Hf[2048];
  __shared__ float scl[128];
  __shared__ float bia[128];
  __shared__ int   nIx[32];

  const int t  = threadIdx.x;
  const int bs = blockIdx.x;
  const int b  = bs >> 11;
  const int lane = t & 63, wv = t >> 6;
  const int quad = lane >> 4, mcol = lane & 15;

  if (t < 32) nIx[t] = nbr[(size_t)bs * K_ + t];
  if (t >= 64 && t < 128) {                  // layer-0 BN fold in parallel
    int i = t - 64;
    float sc = g0[i] * rsqrtf(v0[i] + 1e-5f);
    scl[i] = sc;
    bia[i] = (b0[i] - m0[i]) * sc + be0[i];
  }
  __syncthreads();
  // stage X (32 rows x 64 ch fp32) into fragment-major segments
  #pragma unroll
  for (int rep = 0; rep < 2; ++rep) {
    int task = rep*256 + t;
    int row = task >> 4, j4 = task & 15;
    float4 v = *(const float4*)(points + ((size_t)b*N_ + nIx[row])*64 + j4*4);
    int kt = j4 >> 3, qk = (j4 >> 1) & 3, h = j4 & 1;
    *(float4*)(Xf + (((row>>4)*2 + kt)*2 + h)*256 + (qk*16 + (row&15))*4) = v;
  }
  __syncthreads();

  layer_mfma(lane, wv, Xf, Hf, w0, scl, bia);      // X -> H
  __syncthreads();
  if (t < 64) {
    float sc = g1[t] * rsqrtf(v1[t] + 1e-5f);
    scl[t] = sc;
    bia[t] = (b1[t] - m1[t]) * sc + be1[t];
  }
  __syncthreads();
  layer_mfma(lane, wv, Hf, Xf, w1, scl, bia);      // H -> X
  __syncthreads();
  if (t < 128) {
    float sc = g2[t] * rsqrtf(v2[t] + 1e-5f);
    scl[t] = sc;
    bia[t] = (b2[t] - m2[t]) * sc + be2[t];
  }
  __syncthreads();

  // ---- layer 2: 64 -> 128, fused maxpool.  A-frags hoisted (nt-indep) ----
  short8_ A0[2][2], A1[2][2];
  #pragma unroll
  for (int mt = 0; mt < 2; ++mt)
    #pragma unroll
    for (int kt = 0; kt < 2; ++kt) {
      float4 x0 = *(const float4*)(Xf + (((mt*2+kt)*2+0)*256) + lane*4);
      float4 x1 = *(const float4*)(Xf + (((mt*2+kt)*2+1)*256) + lane*4);
      float f[8] = {x0.x,x0.y,x0.z,x0.w, x1.x,x1.y,x1.z,x1.w};
      bf2split8(f, A0[mt][kt], A1[mt][kt]);
    }
  float* outp = out + (size_t)(B_*S_)*3 + (size_t)bs*128;
  #pragma unroll
  for (int sub = 0; sub < 2; ++sub) {
    const int o = (wv*2 + sub)*16 + mcol;
    const float sc = scl[o];
    short8_ B0[2], B1[2];
    #pragma unroll
    for (int kt = 0; kt < 2; ++kt) {
      const float* wp = w2 + o*64 + kt*32 + quad*8;
      float4 u0 = *(const float4*)(wp);
      float4 u1 = *(const float4*)(wp + 4);
      float f[8] = {u0.x*sc,u0.y*sc,u0.z*sc,u0.w*sc,
                    u1.x*sc,u1.y*sc,u1.z*sc,u1.w*sc};
      bf2split8(f, B0[kt], B1[kt]);
    }
    float vmax = -3.0e38f;
    #pragma unroll
    for (int mt = 0; mt < 2; ++mt) {
      f32x4_ a = {0.f, 0.f, 0.f, 0.f};
      #pragma unroll
      for (int kt = 0; kt < 2; ++kt) {
        a = __builtin_amdgcn_mfma_f32_16x16x32_bf16(A0[mt][kt], B0[kt], a, 0,0,0);
        a = __builtin_amdgcn_mfma_f32_16x16x32_bf16(A0[mt][kt], B1[kt], a, 0,0,0);
        a = __builtin_amdgcn_mfma_f32_16x16x32_bf16(A1[mt][kt], B0[kt], a, 0,0,0);
      }
      vmax = fmaxf(vmax, fmaxf(fmaxf(a[0], a[1]), fmaxf(a[2], a[3])));
    }
    vmax = fmaxf(vmax, __shfl_xor(vmax, 16));
    vmax = fmaxf(vmax, __shfl_xor(vmax, 32));
    if (quad == 0) outp[o] = fmaxf(vmax + bia[o], 0.f);
  }
}

// =====================================================================
extern "C" void kernel_launch(void* const* d_in, const int* in_sizes, int n_in,
                              void* d_out, int out_size, void* d_ws, size_t ws_size,
                              hipStream_t stream)
{
  const float* xyz  = (const float*)d_in[0];
  const float* pts  = (const float*)d_in[1];
  const int*   sidx = (const int*)  d_in[2];
  const float* w0 = (const float*)d_in[3];
  const float* b0 = (const float*)d_in[4];
  const float* g0 = (const float*)d_in[5];
  const float* be0= (const float*)d_in[6];
  const float* m0 = (const float*)d_in[7];
  const float* v0 = (const float*)d_in[8];
  const float* w1 = (const float*)d_in[9];
  const float* b1 = (const float*)d_in[10];
  const float* g1 = (const float*)d_in[11];
  const float* be1= (const float*)d_in[12];
  const float* m1 = (const float*)d_in[13];
  const float* v1 = (const float*)d_in[14];
  const float* w2 = (const float*)d_in[15];
  const float* b2 = (const float*)d_in[16];
  const float* g2 = (const float*)d_in[17];
  const float* be2= (const float*)d_in[18];
  const float* m2 = (const float*)d_in[19];
  const float* v2 = (const float*)d_in[20];

  float* out = (float*)d_out;
  // ws: sqn (512KB) | nbr (2MB) | pw (16.8MB) | planes (3 x 16.78MB)
  float* sqn = (float*)d_ws;
  int*   nbr = (int*)  ((char*)d_ws + (size_t)B_*N_*4);
  uint2* pw  = (uint2*)((char*)d_ws + (size_t)B_*N_*4 + (size_t)B_*S_*K_*4);
  char*  pl  = (char*)d_ws + (size_t)B_*N_*4 + (size_t)B_*S_*K_*4
             + (size_t)B_*S_*SPLIT_*32*8;
  short* P0 = (short*)pl;
  short* P1 = P0 + PLANE_;
  short* P2 = P1 + PLANE_;
  const size_t need = (size_t)B_*N_*4 + (size_t)B_*S_*K_*4
                    + (size_t)B_*S_*SPLIT_*32*8 + 3*PLANE_*2;

  if (ws_size >= need) {
    k_prep<<<(B_*N_)/256, 256, 0, stream>>>(xyz, pts, sidx, out, sqn, P0, P1, P2);
    k_knn <<<B_*32*SPLIT_, 256, 0, stream>>>(P0, P1, P2, sidx, sqn, pw);
  } else {
    k_prep_fb<<<(B_*N_)/256, 256, 0, stream>>>(xyz, pts, sidx, out, sqn);
    k_knn_fb <<<B_*32*SPLIT_, 256, 0, stream>>>(pts, sidx, sqn, pw);
  }
  k_sel <<<(B_*S_)/256, 256, 0, stream>>>(pw, nbr);
  k_mlp <<<B_*S_, 256, 0, stream>>>(pts, nbr,
            w0,b0,g0,be0,m0,v0, w1,b1,g1,be1,m1,v1, w2,b2,g2,be2,m2,v2, out);
}

// Round 8
// 1709.708 us; speedup vs baseline: 37.6216x; 1.2070x over previous
//
#include <hip/hip_runtime.h>

#define B_  8
#define N_  16384
#define D_  64
#define S_  2048
#define K_  32
#define SPLIT_  4
#define NSPL_   (N_/SPLIT_)       // 4096 candidates per block
#define CH32_   (NSPL_/32)        // 128 chunks of 32
#define PLANE_  ((size_t)B_*N_*64) // shorts per plane (8.39M = 16.78 MB)

using short8_ = __attribute__((ext_vector_type(8))) short;
using f32x4_  = __attribute__((ext_vector_type(4))) float;

// =====================================================================
// exact bf16 triple-split of fp32 (truncation-based): f = h0 + h1 + h2
// =====================================================================
__device__ __forceinline__ void bf3split(float f, short& h0, short& h1, short& h2)
{
  unsigned u0 = __float_as_uint(f);
  float f0 = __uint_as_float(u0 & 0xFFFF0000u);
  h0 = (short)(u0 >> 16);
  float r1 = f - f0;
  unsigned u1 = __float_as_uint(r1);
  float f1 = __uint_as_float(u1 & 0xFFFF0000u);
  h1 = (short)(u1 >> 16);
  float r2 = r1 - f1;                 // <= 8 significant bits: bf16-exact
  h2 = (short)(__float_as_uint(r2) >> 16);
}

// bf16 2-split of 8 floats (for the MLP; residual ~2^-16 rel)
__device__ __forceinline__ void bf2split8(const float* f, short8_& h0, short8_& h1)
{
  #pragma unroll
  for (int j = 0; j < 8; ++j) {
    unsigned u = __float_as_uint(f[j]);
    h0[j] = (short)(u >> 16);
    float r = f[j] - __uint_as_float(u & 0xFFFF0000u);
    h1[j] = (short)(__float_as_uint(r) >> 16);
  }
}

// sorted-DESCENDING 32-entry list (Lv[0] = largest kept)
__device__ __forceinline__ void insert32(float (&Lv)[32], int (&Li)[32], float x, int n)
{
  bool ci = x < Lv[0];
  #pragma unroll
  for (int i = 0; i < 31; ++i) {
    bool c1 = x < Lv[i+1];
    float nv = c1 ? Lv[i+1] : (ci ? x : Lv[i]);
    int   ni = c1 ? Li[i+1] : (ci ? n : Li[i]);
    Lv[i] = nv; Li[i] = ni;
    ci = c1;
  }
  Lv[31] = ci ? x : Lv[31];
  Li[31] = ci ? n : Li[31];
}

// =====================================================================
// K1 (fast path): sqn + new_xyz gather + fragment-major bf16x3 planes
// sqn: EXACT round-3 expression (bit-identical keys -> selection).
// =====================================================================
__global__ __launch_bounds__(256) void k_prep(
    const float* __restrict__ xyz, const float* __restrict__ points,
    const int* __restrict__ sidx, float* __restrict__ out, float* __restrict__ sqn,
    short* __restrict__ P0, short* __restrict__ P1, short* __restrict__ P2)
{
  int tid = blockIdx.x * 256 + threadIdx.x;      // 0 .. B*N-1
  const float4* p = (const float4*)(points + (size_t)tid * 64);

  float s = 0.f;
  #pragma unroll
  for (int i = 0; i < 16; ++i) {
    float4 v = p[i];
    s += v.x*v.x + v.y*v.y + v.z*v.z + v.w*v.w;
  }
  sqn[tid] = s;

  int n = tid & (N_-1);
  int c = n >> 6, ct = (n >> 4) & 3, mc = n & 15;
  size_t segbase = (((size_t)(tid >> 14) * 256 + c) * 4 + ct) * 2;  // *512 shorts

  #pragma unroll
  for (int g = 0; g < 8; ++g) {                  // (kt=g>>2, qd=g&3), dims 8g..8g+7
    float4 a = p[2*g], b4 = p[2*g+1];
    float f[8] = {a.x,a.y,a.z,a.w, b4.x,b4.y,b4.z,b4.w};
    short8_ h0v, h1v, h2v;
    #pragma unroll
    for (int j = 0; j < 8; ++j) {
      short h0, h1, h2;
      bf3split(f[j], h0, h1, h2);
      h0v[j] = h0; h1v[j] = h1; h2v[j] = h2;
    }
    size_t off = ((segbase + (g>>2))*64 + (size_t)(g&3)*16 + mc)*8;
    *(short8_*)(P0 + off) = h0v;
    *(short8_*)(P1 + off) = h1v;
    *(short8_*)(P2 + off) = h2v;
  }
  if (tid < B_*S_) {
    int b = tid >> 11, ss = tid & (S_-1);
    int nn = sidx[ss];
    const float* src = xyz + ((size_t)b * N_ + nn) * 3;
    out[(size_t)tid*3+0] = src[0];
    out[(size_t)tid*3+1] = src[1];
    out[(size_t)tid*3+2] = src[2];
  }
}

// =====================================================================
// K2 (fast path): MFMA over pre-split planes + filtered top-32.
// Keys bit-identical to r3/r6/r7.  New this round:
//  - thr = min(tau, tau2, own Lv[0]) with tau2 = max-over-streams(Lv[24])
//    (exact row-32nd upper bound: each stream has 8 values <= its Lv[24]
//     -> union has >=32 values <= tau2).  ~4x fewer inserts; merge output
//    provably unchanged.
//  - insert loop selects key from registers (3-level mux), no LDS re-read.
//  - staging software-pipelined: next chunk's 3 plane vectors prefetched
//    into registers during compute; Dtr is wave-local (rows 16wv..16wv+15
//    written AND read only by wave wv) so no barrier before selection.
// =====================================================================
__global__ __launch_bounds__(256) void k_knn(
    const short* __restrict__ P0, const short* __restrict__ P1,
    const short* __restrict__ P2, const int* __restrict__ sidx,
    const float* __restrict__ sqn, uint2* __restrict__ pw)
{
  // LDS: Bp [12 segs][64 lanes][8 shorts] = 12288 | Dtr [64r][36c] f32 = 9216
  //      | sqc [32] f32.  merge aliases all as uint2 mbuf[32][130] = 33280
  __shared__ __align__(16) char smraw[33280];
  short* Bp  = (short*)smraw;
  float* Dtr = (float*)(smraw + 12288);
  float* sqc = (float*)(smraw + 21504);

  const int t = threadIdx.x;
  const int b     = blockIdx.x & 7;          // XCD swizzle
  const int y     = blockIdx.x >> 3;
  const int tile  = y & 31;
  const int split = y >> 5;
  const int s0 = tile * 64;
  const float* Qb = sqn + (size_t)b * N_;

  const int lane = t & 63, wv = t >> 6;
  const int quad = lane >> 4, mcol = lane & 15;

  // ---- A fragments (wave wv owns sampled rows 16*wv..+15), from planes ----
  short8_ A0[2], A1[2], A2[2];
  {
    int srow = sidx[s0 + 16*wv + mcol];
    int cs = srow >> 6, cts = (srow >> 4) & 3, ms = srow & 15;
    size_t ab = (((size_t)(b*256 + cs))*4 + cts)*2*512 + ((size_t)quad*16 + ms)*8;
    #pragma unroll
    for (int kt = 0; kt < 2; ++kt) {
      A0[kt] = *(const short8_*)(P0 + ab + kt*512);
      A1[kt] = *(const short8_*)(P1 + ab + kt*512);
      A2[kt] = *(const short8_*)(P2 + ab + kt*512);
    }
  }

  float Lv[32]; int Li[32];
  #pragma unroll
  for (int i = 0; i < 32; ++i) { Lv[i] = 3.0e38f; Li[i] = 0; }

  const int r = t >> 2;        // selection row 0..63
  const int q = t & 3;         // stream within row
  const int n0base = split * NSPL_;
  const size_t bc8base = (size_t)b * 256;

  // ---- prefetch chunk 0 staging into registers ----
  short8_ pv0, pv1, pv2;
  {
    const int n0 = n0base;
    const size_t gsrc = (bc8base + (n0 >> 6)) * 8 + (size_t)(((n0 >> 5) & 1)*4 + wv);
    const size_t goff = gsrc*512 + (size_t)lane*8;
    pv0 = *(const short8_*)(P0 + goff);
    pv1 = *(const short8_*)(P1 + goff);
    pv2 = *(const short8_*)(P2 + goff);
  }

  for (int ch = 0; ch < CH32_; ++ch) {
    const int n0 = n0base + ch * 32;
    __syncthreads();                 // all waves done reading prev Bp
    *(short8_*)(Bp + (0*4 + wv)*512 + lane*8) = pv0;
    *(short8_*)(Bp + (1*4 + wv)*512 + lane*8) = pv1;
    *(short8_*)(Bp + (2*4 + wv)*512 + lane*8) = pv2;
    if (t < 8) *(float4*)(sqc + 4*t) = *(const float4*)(Qb + n0 + 4*t);
    __syncthreads();                 // Bp ready

    // ---- B-fragment reads (issued together) ----
    short8_ b0[2][2], b1[2][2], b2[2][2];   // [ct][kt]
    #pragma unroll
    for (int ct = 0; ct < 2; ++ct)
      #pragma unroll
      for (int kt = 0; kt < 2; ++kt) {
        int lo = lane*8;
        b0[ct][kt] = *(const short8_*)(Bp + (0*4 + ct*2 + kt)*512 + lo);
        b1[ct][kt] = *(const short8_*)(Bp + (1*4 + ct*2 + kt)*512 + lo);
        b2[ct][kt] = *(const short8_*)(Bp + (2*4 + ct*2 + kt)*512 + lo);
      }

    // ---- prefetch next chunk (hidden under MFMA + selection) ----
    if (ch + 1 < CH32_) {
      const int n1 = n0 + 32;
      const size_t gsrc = (bc8base + (n1 >> 6)) * 8 + (size_t)(((n1 >> 5) & 1)*4 + wv);
      const size_t goff = gsrc*512 + (size_t)lane*8;
      pv0 = *(const short8_*)(P0 + goff);
      pv1 = *(const short8_*)(P1 + goff);
      pv2 = *(const short8_*)(P2 + goff);
    }

    // ---- 16 MFMA per 16-cand tile (8 combos x 2 kt), 2 tiles ----
    #pragma unroll
    for (int ct = 0; ct < 2; ++ct) {
      f32x4_ a = {0.f, 0.f, 0.f, 0.f};
      #pragma unroll
      for (int kt = 0; kt < 2; ++kt) {
        a = __builtin_amdgcn_mfma_f32_16x16x32_bf16(A0[kt], b0[ct][kt], a, 0,0,0);
        a = __builtin_amdgcn_mfma_f32_16x16x32_bf16(A0[kt], b1[ct][kt], a, 0,0,0);
        a = __builtin_amdgcn_mfma_f32_16x16x32_bf16(A1[kt], b0[ct][kt], a, 0,0,0);
        a = __builtin_amdgcn_mfma_f32_16x16x32_bf16(A1[kt], b1[ct][kt], a, 0,0,0);
        a = __builtin_amdgcn_mfma_f32_16x16x32_bf16(A0[kt], b2[ct][kt], a, 0,0,0);
        a = __builtin_amdgcn_mfma_f32_16x16x32_bf16(A2[kt], b0[ct][kt], a, 0,0,0);
        a = __builtin_amdgcn_mfma_f32_16x16x32_bf16(A1[kt], b2[ct][kt], a, 0,0,0);
        a = __builtin_amdgcn_mfma_f32_16x16x32_bf16(A2[kt], b1[ct][kt], a, 0,0,0);
      }
      // keys -> Dtr (wave-local rows). C/D: col=lane&15, row=quad*4+reg
      int cc = 16*ct + mcol;
      float sq = sqc[cc];
      int rb = 16*wv + 4*quad;
      Dtr[(rb+0)*36 + cc] = sq - 2.f*a[0];
      Dtr[(rb+1)*36 + cc] = sq - 2.f*a[1];
      Dtr[(rb+2)*36 + cc] = sq - 2.f*a[2];
      Dtr[(rb+3)*36 + cc] = sq - 2.f*a[3];
    }
    // no barrier: Dtr rows 16wv..16wv+15 are read only by this wave
    // (thread t reads row t>>2 in [16wv,16wv+15]); lgkmcnt handles visibility

    // ---- selection: dual exact bounds, register-mux insert loop ----
    float ownL0 = Lv[0];
    float tmin = ownL0;                       // min of stream 32nds
    tmin = fminf(tmin, __shfl_xor(tmin, 1));
    tmin = fminf(tmin, __shfl_xor(tmin, 2));
    float t24 = Lv[24];                       // stream 8th-smallest
    t24 = fmaxf(t24, __shfl_xor(t24, 1));
    t24 = fmaxf(t24, __shfl_xor(t24, 2));     // max over streams: row-32nd <= t24
    const float thr = fminf(fminf(tmin, t24), ownL0);

    float4 ka = *(const float4*)(Dtr + r*36 + q*8);
    float4 kb = *(const float4*)(Dtr + r*36 + q*8 + 4);
    float x8[8] = {ka.x,ka.y,ka.z,ka.w, kb.x,kb.y,kb.z,kb.w};
    unsigned m = 0;
    #pragma unroll
    for (int i = 0; i < 8; ++i)
      m |= (x8[i] < thr) ? (1u << i) : 0u;
    while (__any(m != 0)) {
      if (m) {
        int i = __ffs(m) - 1;
        m &= m - 1;
        float xlo = (i & 1) ? ((i & 2) ? x8[3] : x8[1]) : ((i & 2) ? x8[2] : x8[0]);
        float xhi = (i & 1) ? ((i & 2) ? x8[7] : x8[5]) : ((i & 2) ? x8[6] : x8[4]);
        float x = (i & 4) ? xhi : xlo;
        if (x < Lv[0])
          insert32(Lv, Li, x, n0 + q*8 + i);
      }
    }
  }

  // ---- in-block 4-pointer merge (streams stored reversed -> ascending) ----
  uint2* mbuf = (uint2*)smraw;                 // [32][130]
  const int rowg = b * S_ + s0;
  for (int pass = 0; pass < 2; ++pass) {
    __syncthreads();
    const int rb = pass * 32;
    if (r >= rb && r < rb + 32) {
      #pragma unroll
      for (int i = 0; i < 32; ++i)
        mbuf[(r - rb)*130 + q*32 + (31 - i)] =
            make_uint2(__float_as_uint(Lv[i]), (unsigned)Li[i]);
    }
    __syncthreads();
    if (t < 32) {
      const uint2* Lrow = mbuf + t*130;
      uint2* dst = pw + ((size_t)(rowg + rb + t) * SPLIT_ + split) * 32;
      int p0 = 0, p1 = 0, p2 = 0, p3 = 0;
      for (int k = 0; k < 32; ++k) {
        float bv = 3.0e38f; unsigned bi = 0xFFFFFFFFu; int bq = 0;
        int pa[4] = {p0, p1, p2, p3};
        #pragma unroll
        for (int q4 = 0; q4 < 4; ++q4) {
          if (pa[q4] < 32) {
            uint2 e = Lrow[q4*32 + pa[q4]];
            float v = __uint_as_float(e.x);
            if (v < bv || (v == bv && e.y < bi)) { bv = v; bi = e.y; bq = q4; }
          }
        }
        dst[k] = make_uint2(__float_as_uint(bv), bi);
        if (bq == 0) p0++; else if (bq == 1) p1++; else if (bq == 2) p2++; else p3++;
      }
    }
  }
}

// =====================================================================
// FALLBACK path (ws too small): round-3 kernels, proven correct
// =====================================================================
__global__ __launch_bounds__(256) void k_prep_fb(
    const float* __restrict__ xyz, const float* __restrict__ points,
    const int* __restrict__ sidx, float* __restrict__ out, float* __restrict__ sqn)
{
  int tid = blockIdx.x * 256 + threadIdx.x;
  const float4* p = (const float4*)(points + (size_t)tid * 64);
  float s = 0.f;
  #pragma unroll
  for (int i = 0; i < 16; ++i) {
    float4 v = p[i];
    s += v.x*v.x + v.y*v.y + v.z*v.z + v.w*v.w;
  }
  sqn[tid] = s;
  if (tid < B_*S_) {
    int b = tid >> 11, ss = tid & (S_-1);
    int n = sidx[ss];
    const float* src = xyz + ((size_t)b * N_ + n) * 3;
    out[(size_t)tid*3+0] = src[0];
    out[(size_t)tid*3+1] = src[1];
    out[(size_t)tid*3+2] = src[2];
  }
}

__global__ __launch_bounds__(256) void k_knn_fb(
    const float* __restrict__ points, const int* __restrict__ sidx,
    const float* __restrict__ sqn, uint2* __restrict__ pw)
{
  __shared__ __align__(16) char smraw[45312];
  short* Bp0 = (short*)smraw;
  short* Bp1 = (short*)(smraw + 9216);
  short* Bp2 = (short*)(smraw + 18432);
  float* Dt  = (float*)(smraw + 27648);
  float* sqc = (float*)(smraw + 45056);

  const int t = threadIdx.x;
  const int b     = blockIdx.x & 7;
  const int y     = blockIdx.x >> 3;
  const int tile  = y & 31;
  const int split = y >> 5;
  const int s0 = tile * 64;
  const float* Pb = points + (size_t)b * N_ * 64;
  const float* Qb = sqn    + (size_t)b * N_;

  const int lane = t & 63, wv = t >> 6;
  const int quad = lane >> 4, mcol = lane & 15;

  short8_ A0[2], A1[2], A2[2];
  {
    int srow = sidx[s0 + 16*wv + mcol];
    const float* ar = Pb + (size_t)srow * 64;
    #pragma unroll
    for (int kt = 0; kt < 2; ++kt) {
      float4 v0 = *(const float4*)(ar + 32*kt + 8*quad);
      float4 v1 = *(const float4*)(ar + 32*kt + 8*quad + 4);
      float f[8] = {v0.x,v0.y,v0.z,v0.w,v1.x,v1.y,v1.z,v1.w};
      #pragma unroll
      for (int j = 0; j < 8; ++j) {
        short h0, h1, h2;
        bf3split(f[j], h0, h1, h2);
        A0[kt][j] = h0; A1[kt][j] = h1; A2[kt][j] = h2;
      }
    }
  }

  float Lv[32]; int Li[32];
  #pragma unroll
  for (int i = 0; i < 32; ++i) { Lv[i] = 3.0e38f; Li[i] = 0; }

  const int r = t >> 2;
  const int q = t & 3;
  const int n0base = split * NSPL_;

  for (int ch = 0; ch < NSPL_/64; ++ch) {
    const int n0 = n0base + ch * 64;
    {
      const int n = t & 63, jg = t >> 6;
      const float* src = Pb + (size_t)(n0 + n) * 64 + 16*jg;
      float4 u0 = *(const float4*)(src);
      float4 u1 = *(const float4*)(src + 4);
      float4 u2 = *(const float4*)(src + 8);
      float4 u3 = *(const float4*)(src + 12);
      float f[16] = {u0.x,u0.y,u0.z,u0.w, u1.x,u1.y,u1.z,u1.w,
                     u2.x,u2.y,u2.z,u2.w, u3.x,u3.y,u3.z,u3.w};
      short8_ p0[2], p1[2], p2[2];
      #pragma unroll
      for (int j = 0; j < 16; ++j) {
        short h0, h1, h2;
        bf3split(f[j], h0, h1, h2);
        p0[j>>3][j&7] = h0; p1[j>>3][j&7] = h1; p2[j>>3][j&7] = h2;
      }
      *(short8_*)(Bp0 + n*72 + 16*jg)     = p0[0];
      *(short8_*)(Bp0 + n*72 + 16*jg + 8) = p0[1];
      *(short8_*)(Bp1 + n*72 + 16*jg)     = p1[0];
      *(short8_*)(Bp1 + n*72 + 16*jg + 8) = p1[1];
      *(short8_*)(Bp2 + n*72 + 16*jg)     = p2[0];
      *(short8_*)(Bp2 + n*72 + 16*jg + 8) = p2[1];
      if (t < 16) *(float4*)(sqc + 4*t) = *(const float4*)(Qb + n0 + 4*t);
    }
    __syncthreads();

    f32x4_ acc[4];
    #pragma unroll
    for (int ct = 0; ct < 4; ++ct) {
      const int boff = (16*ct + mcol)*72 + 8*quad;
      short8_ b0[2], b1[2], b2[2];
      b0[0] = *(const short8_*)(Bp0 + boff); b0[1] = *(const short8_*)(Bp0 + boff + 32);
      b1[0] = *(const short8_*)(Bp1 + boff); b1[1] = *(const short8_*)(Bp1 + boff + 32);
      b2[0] = *(const short8_*)(Bp2 + boff); b2[1] = *(const short8_*)(Bp2 + boff + 32);
      f32x4_ a = {0.f, 0.f, 0.f, 0.f};
      #pragma unroll
      for (int kt = 0; kt < 2; ++kt) {
        a = __builtin_amdgcn_mfma_f32_16x16x32_bf16(A0[kt], b0[kt], a, 0,0,0);
        a = __builtin_amdgcn_mfma_f32_16x16x32_bf16(A0[kt], b1[kt], a, 0,0,0);
        a = __builtin_amdgcn_mfma_f32_16x16x32_bf16(A1[kt], b0[kt], a, 0,0,0);
        a = __builtin_amdgcn_mfma_f32_16x16x32_bf16(A1[kt], b1[kt], a, 0,0,0);
        a = __builtin_amdgcn_mfma_f32_16x16x32_bf16(A0[kt], b2[kt], a, 0,0,0);
        a = __builtin_amdgcn_mfma_f32_16x16x32_bf16(A2[kt], b0[kt], a, 0,0,0);
        a = __builtin_amdgcn_mfma_f32_16x16x32_bf16(A1[kt], b2[kt], a, 0,0,0);
        a = __builtin_amdgcn_mfma_f32_16x16x32_bf16(A2[kt], b1[kt], a, 0,0,0);
      }
      acc[ct] = a;
    }
    #pragma unroll
    for (int ct = 0; ct < 4; ++ct) {
      int c = 16*ct + mcol;
      float sq = sqc[c];
      float4 kv;
      kv.x = sq - 2.f*acc[ct][0];
      kv.y = sq - 2.f*acc[ct][1];
      kv.z = sq - 2.f*acc[ct][2];
      kv.w = sq - 2.f*acc[ct][3];
      *(float4*)(Dt + c*68 + 16*wv + 4*quad) = kv;
    }
    __syncthreads();

    float L0 = Lv[0];
    L0 = fminf(L0, __shfl_xor(L0, 1));
    L0 = fminf(L0, __shfl_xor(L0, 2));
    const float tau = L0;
    #pragma unroll
    for (int g = 0; g < 4; ++g) {
      #pragma unroll
      for (int u = 0; u < 4; ++u) {
        int c = q*16 + g*4 + u;
        float x = Dt[c*68 + r];
        if (x < fminf(tau, Lv[0]))
          insert32(Lv, Li, x, n0 + c);
      }
    }
  }

  uint2* mbuf = (uint2*)smraw;
  const int rowg = b * S_ + s0;
  for (int pass = 0; pass < 2; ++pass) {
    __syncthreads();
    const int rb = pass * 32;
    if (r >= rb && r < rb + 32) {
      #pragma unroll
      for (int i = 0; i < 32; ++i)
        mbuf[(r - rb)*130 + q*32 + (31 - i)] =
            make_uint2(__float_as_uint(Lv[i]), (unsigned)Li[i]);
    }
    __syncthreads();
    if (t < 32) {
      const uint2* Lrow = mbuf + t*130;
      uint2* dst = pw + ((size_t)(rowg + rb + t) * SPLIT_ + split) * 32;
      int p0 = 0, p1 = 0, p2 = 0, p3 = 0;
      for (int k = 0; k < 32; ++k) {
        float bv = 3.0e38f; unsigned bi = 0xFFFFFFFFu; int bq = 0;
        int pa[4] = {p0, p1, p2, p3};
        #pragma unroll
        for (int q4 = 0; q4 < 4; ++q4) {
          if (pa[q4] < 32) {
            uint2 e = Lrow[q4*32 + pa[q4]];
            float v = __uint_as_float(e.x);
            if (v < bv || (v == bv && e.y < bi)) { bv = v; bi = e.y; bq = q4; }
          }
        }
        dst[k] = make_uint2(__float_as_uint(bv), bi);
        if (bq == 0) p0++; else if (bq == 1) p1++; else if (bq == 2) p2++; else p3++;
      }
    }
  }
}

// =====================================================================
// K2b: merge the 4 split-partials (ascending) per row -> 32 indices
// =====================================================================
__global__ __launch_bounds__(256) void k_sel(const uint2* __restrict__ pw,
                                             int* __restrict__ nbr)
{
  int row = blockIdx.x * 256 + threadIdx.x;       // 0 .. B*S-1
  const uint2* L = pw + (size_t)row * (SPLIT_*32);
  int* dst = nbr + (size_t)row * K_;
  int p[4] = {0,0,0,0};
  for (int k = 0; k < K_; ++k) {
    float bv = 3.0e38f; unsigned bi = 0xFFFFFFFFu; int bq = 0;
    #pragma unroll
    for (int q4 = 0; q4 < 4; ++q4) {
      if (p[q4] < 32) {
        uint2 e = L[q4*32 + p[q4]];
        float v = __uint_as_float(e.x);
        if (v < bv || (v == bv && e.y < bi)) { bv = v; bi = e.y; bq = q4; }
      }
    }
    dst[k] = (int)bi;
    p[bq]++;
  }
}

// =====================================================================
// K3: MFMA MLP (bf16 2-split) + fused bias/relu/maxpool.
// =====================================================================
__device__ __forceinline__ void layer_mfma(
    int lane, int wv, const float* Xf, float* Hf,
    const float* __restrict__ wgt, const float* scl, const float* bia)
{
  const int quad = lane >> 4, mcol = lane & 15;
  const int o = wv*16 + mcol;                 // this wave's output column
  const float sc = scl[o];
  short8_ B0[2], B1[2];
  #pragma unroll
  for (int kt = 0; kt < 2; ++kt) {
    const float* wp = wgt + o*64 + kt*32 + quad*8;
    float4 u0 = *(const float4*)(wp);
    float4 u1 = *(const float4*)(wp + 4);
    float f[8] = {u0.x*sc,u0.y*sc,u0.z*sc,u0.w*sc,
                  u1.x*sc,u1.y*sc,u1.z*sc,u1.w*sc};
    bf2split8(f, B0[kt], B1[kt]);
  }
  const float bo = bia[o];
  const int kt2 = (o >> 5) & 1, qk2 = (o >> 3) & 3, h2 = (o >> 2) & 1, j2 = o & 3;
  #pragma unroll
  for (int mt = 0; mt < 2; ++mt) {
    short8_ A0[2], A1[2];
    #pragma unroll
    for (int kt = 0; kt < 2; ++kt) {
      float4 x0 = *(const float4*)(Xf + (((mt*2+kt)*2+0)*256) + lane*4);
      float4 x1 = *(const float4*)(Xf + (((mt*2+kt)*2+1)*256) + lane*4);
      float f[8] = {x0.x,x0.y,x0.z,x0.w, x1.x,x1.y,x1.z,x1.w};
      bf2split8(f, A0[kt], A1[kt]);
    }
    f32x4_ a = {0.f, 0.f, 0.f, 0.f};
    #pragma unroll
    for (int kt = 0; kt < 2; ++kt) {
      a = __builtin_amdgcn_mfma_f32_16x16x32_bf16(A0[kt], B0[kt], a, 0,0,0);
      a = __builtin_amdgcn_mfma_f32_16x16x32_bf16(A0[kt], B1[kt], a, 0,0,0);
      a = __builtin_amdgcn_mfma_f32_16x16x32_bf16(A1[kt], B0[kt], a, 0,0,0);
    }
    #pragma unroll
    for (int reg = 0; reg < 4; ++reg) {
      int ml = quad*4 + reg;                  // m within mtile
      float hval = fmaxf(a[reg] + bo, 0.f);
      Hf[((mt*2 + kt2)*2 + h2)*256 + (qk2*16 + ml)*4 + j2] = hval;
    }
  }
}

__global__ __launch_bounds__(256) void k_mlp(
    const float* __restrict__ points, const int* __restrict__ nbr,
    const float* __restrict__ w0, const float* __restrict__ b0,
    const float* __restrict__ g0, const float* __restrict__ be0,
    const float* __restrict__ m0, const float* __restrict__ v0,
    const float* __restrict__ w1, const float* __restrict__ b1,
    const float* __restrict__ g1, const float* __restrict__ be1,
    const float* __restrict__ m1, const float* __restrict__ v1,
    const float* __restrict__ w2, const float* __restrict__ b2,
    const float* __restrict__ g2, const float* __restrict__ be2,
    const float* __restrict__ m2, const float* __restrict__ v2,
    float* __restrict__ out)
{
  __shared__ __align__(16) float Xf[2048];   // 8 segs x 1KB
  __shared__ __align__(16) float Hf[2048];
  __shared__ float scl[128];
  __shared__ float bia[128];
  __shared__ int   nIx[32];

  const int t  = threadIdx.x;
  const int bs = blockIdx.x;
  const int b  = bs >> 11;
  const int lane = t & 63, wv = t >> 6;
  const int quad = lane >> 4, mcol = lane & 15;

  if (t < 32) nIx[t] = nbr[(size_t)bs * K_ + t];
  if (t >= 64 && t < 128) {                  // layer-0 BN fold in parallel
    int i = t - 64;
    float sc = g0[i] * rsqrtf(v0[i] + 1e-5f);
    scl[i] = sc;
    bia[i] = (b0[i] - m0[i]) * sc + be0[i];
  }
  __syncthreads();
  // stage X (32 rows x 64 ch fp32) into fragment-major segments
  #pragma unroll
  for (int rep = 0; rep < 2; ++rep) {
    int task = rep*256 + t;
    int row = task >> 4, j4 = task & 15;
    float4 v = *(const float4*)(points + ((size_t)b*N_ + nIx[row])*64 + j4*4);
    int kt = j4 >> 3, qk = (j4 >> 1) & 3, h = j4 & 1;
    *(float4*)(Xf + (((row>>4)*2 + kt)*2 + h)*256 + (qk*16 + (row&15))*4) = v;
  }
  __syncthreads();

  layer_mfma(lane, wv, Xf, Hf, w0, scl, bia);      // X -> H
  __syncthreads();
  if (t < 64) {
    float sc = g1[t] * rsqrtf(v1[t] + 1e-5f);
    scl[t] = sc;
    bia[t] = (b1[t] - m1[t]) * sc + be1[t];
  }
  __syncthreads();
  layer_mfma(lane, wv, Hf, Xf, w1, scl, bia);      // H -> X
  __syncthreads();
  if (t < 128) {
    float sc = g2[t] * rsqrtf(v2[t] + 1e-5f);
    scl[t] = sc;
    bia[t] = (b2[t] - m2[t]) * sc + be2[t];
  }
  __syncthreads();

  // ---- layer 2: 64 -> 128, fused maxpool.  A-frags hoisted ----
  short8_ A0[2][2], A1[2][2];
  #pragma unroll
  for (int mt = 0; mt < 2; ++mt)
    #pragma unroll
    for (int kt = 0; kt < 2; ++kt) {
      float4 x0 = *(const float4*)(Xf + (((mt*2+kt)*2+0)*256) + lane*4);
      float4 x1 = *(const float4*)(Xf + (((mt*2+kt)*2+1)*256) + lane*4);
      float f[8] = {x0.x,x0.y,x0.z,x0.w, x1.x,x1.y,x1.z,x1.w};
      bf2split8(f, A0[mt][kt], A1[mt][kt]);
    }
  float* outp = out + (size_t)(B_*S_)*3 + (size_t)bs*128;
  #pragma unroll
  for (int sub = 0; sub < 2; ++sub) {
    const int o = (wv*2 + sub)*16 + mcol;
    const float sc = scl[o];
    short8_ B0[2], B1[2];
    #pragma unroll
    for (int kt = 0; kt < 2; ++kt) {
      const float* wp = w2 + o*64 + kt*32 + quad*8;
      float4 u0 = *(const float4*)(wp);
      float4 u1 = *(const float4*)(wp + 4);
      float f[8] = {u0.x*sc,u0.y*sc,u0.z*sc,u0.w*sc,
                    u1.x*sc,u1.y*sc,u1.z*sc,u1.w*sc};
      bf2split8(f, B0[kt], B1[kt]);
    }
    float vmax = -3.0e38f;
    #pragma unroll
    for (int mt = 0; mt < 2; ++mt) {
      f32x4_ a = {0.f, 0.f, 0.f, 0.f};
      #pragma unroll
      for (int kt = 0; kt < 2; ++kt) {
        a = __builtin_amdgcn_mfma_f32_16x16x32_bf16(A0[mt][kt], B0[kt], a, 0,0,0);
        a = __builtin_amdgcn_mfma_f32_16x16x32_bf16(A0[mt][kt], B1[kt], a, 0,0,0);
        a = __builtin_amdgcn_mfma_f32_16x16x32_bf16(A1[mt][kt], B0[kt], a, 0,0,0);
      }
      vmax = fmaxf(vmax, fmaxf(fmaxf(a[0], a[1]), fmaxf(a[2], a[3])));
    }
    vmax = fmaxf(vmax, __shfl_xor(vmax, 16));
    vmax = fmaxf(vmax, __shfl_xor(vmax, 32));
    if (quad == 0) outp[o] = fmaxf(vmax + bia[o], 0.f);
  }
}

// =====================================================================
extern "C" void kernel_launch(void* const* d_in, const int* in_sizes, int n_in,
                              void* d_out, int out_size, void* d_ws, size_t ws_size,
                              hipStream_t stream)
{
  const float* xyz  = (const float*)d_in[0];
  const float* pts  = (const float*)d_in[1];
  const int*   sidx = (const int*)  d_in[2];
  const float* w0 = (const float*)d_in[3];
  const float* b0 = (const float*)d_in[4];
  const float* g0 = (const float*)d_in[5];
  const float* be0= (const float*)d_in[6];
  const float* m0 = (const float*)d_in[7];
  const float* v0 = (const float*)d_in[8];
  const float* w1 = (const float*)d_in[9];
  const float* b1 = (const float*)d_in[10];
  const float* g1 = (const float*)d_in[11];
  const float* be1= (const float*)d_in[12];
  const float* m1 = (const float*)d_in[13];
  const float* v1 = (const float*)d_in[14];
  const float* w2 = (const float*)d_in[15];
  const float* b2 = (const float*)d_in[16];
  const float* g2 = (const float*)d_in[17];
  const float* be2= (const float*)d_in[18];
  const float* m2 = (const float*)d_in[19];
  const float* v2 = (const float*)d_in[20];

  float* out = (float*)d_out;
  // ws: sqn (512KB) | nbr (2MB) | pw (16.8MB) | planes (3 x 16.78MB)
  float* sqn = (float*)d_ws;
  int*   nbr = (int*)  ((char*)d_ws + (size_t)B_*N_*4);
  uint2* pw  = (uint2*)((char*)d_ws + (size_t)B_*N_*4 + (size_t)B_*S_*K_*4);
  char*  pl  = (char*)d_ws + (size_t)B_*N_*4 + (size_t)B_*S_*K_*4
             + (size_t)B_*S_*SPLIT_*32*8;
  short* P0 = (short*)pl;
  short* P1 = P0 + PLANE_;
  short* P2 = P1 + PLANE_;
  const size_t need = (size_t)B_*N_*4 + (size_t)B_*S_*K_*4
                    + (size_t)B_*S_*SPLIT_*32*8 + 3*PLANE_*2;

  if (ws_size >= need) {
    k_prep<<<(B_*N_)/256, 256, 0, stream>>>(xyz, pts, sidx, out, sqn, P0, P1, P2);
    k_knn <<<B_*32*SPLIT_, 256, 0, stream>>>(P0, P1, P2, sidx, sqn, pw);
  } else {
    k_prep_fb<<<(B_*N_)/256, 256, 0, stream>>>(xyz, pts, sidx, out, sqn);
    k_knn_fb <<<B_*32*SPLIT_, 256, 0, stream>>>(pts, sidx, sqn, pw);
  }
  k_sel <<<(B_*S_)/256, 256, 0, stream>>>(pw, nbr);
  k_mlp <<<B_*S_, 256, 0, stream>>>(pts, nbr,
            w0,b0,g0,be0,m0,v0, w1,b1,g1,be1,m1,v1, w2,b2,g2,be2,m2,v2, out);
}

// Round 9
// 1319.634 us; speedup vs baseline: 48.7423x; 1.2956x over previous
//
#include <hip/hip_runtime.h>

#define B_  8
#define N_  16384
#define D_  64
#define S_  2048
#define K_  32
#define SPLIT_  4
#define NSPL_   (N_/SPLIT_)       // 4096 candidates per block
#define CH32_   (NSPL_/32)        // 128 chunks of 32
#define PLANE_  ((size_t)B_*N_*64) // shorts per plane (8.39M = 16.78 MB)

using short8_ = __attribute__((ext_vector_type(8))) short;
using f32x4_  = __attribute__((ext_vector_type(4))) float;

// =====================================================================
// exact bf16 triple-split of fp32 (truncation-based): f = h0 + h1 + h2
// =====================================================================
__device__ __forceinline__ void bf3split(float f, short& h0, short& h1, short& h2)
{
  unsigned u0 = __float_as_uint(f);
  float f0 = __uint_as_float(u0 & 0xFFFF0000u);
  h0 = (short)(u0 >> 16);
  float r1 = f - f0;
  unsigned u1 = __float_as_uint(r1);
  float f1 = __uint_as_float(u1 & 0xFFFF0000u);
  h1 = (short)(u1 >> 16);
  float r2 = r1 - f1;                 // <= 8 significant bits: bf16-exact
  h2 = (short)(__float_as_uint(r2) >> 16);
}

// bf16 2-split of 8 floats (for the MLP; residual ~2^-16 rel)
__device__ __forceinline__ void bf2split8(const float* f, short8_& h0, short8_& h1)
{
  #pragma unroll
  for (int j = 0; j < 8; ++j) {
    unsigned u = __float_as_uint(f[j]);
    h0[j] = (short)(u >> 16);
    float r = f[j] - __uint_as_float(u & 0xFFFF0000u);
    h1[j] = (short)(__float_as_uint(r) >> 16);
  }
}

// sorted-DESCENDING 32-entry list (Lv[0] = largest kept)
__device__ __forceinline__ void insert32(float (&Lv)[32], int (&Li)[32], float x, int n)
{
  bool ci = x < Lv[0];
  #pragma unroll
  for (int i = 0; i < 31; ++i) {
    bool c1 = x < Lv[i+1];
    float nv = c1 ? Lv[i+1] : (ci ? x : Lv[i]);
    int   ni = c1 ? Li[i+1] : (ci ? n : Li[i]);
    Lv[i] = nv; Li[i] = ni;
    ci = c1;
  }
  Lv[31] = ci ? x : Lv[31];
  Li[31] = ci ? n : Li[31];
}

// =====================================================================
// K1 (fast path): sqn + new_xyz gather + fragment-major bf16x3 planes
// sqn: EXACT round-3 expression (bit-identical keys -> selection).
// =====================================================================
__global__ __launch_bounds__(256) void k_prep(
    const float* __restrict__ xyz, const float* __restrict__ points,
    const int* __restrict__ sidx, float* __restrict__ out, float* __restrict__ sqn,
    short* __restrict__ P0, short* __restrict__ P1, short* __restrict__ P2)
{
  int tid = blockIdx.x * 256 + threadIdx.x;      // 0 .. B*N-1
  const float4* p = (const float4*)(points + (size_t)tid * 64);

  float s = 0.f;
  #pragma unroll
  for (int i = 0; i < 16; ++i) {
    float4 v = p[i];
    s += v.x*v.x + v.y*v.y + v.z*v.z + v.w*v.w;
  }
  sqn[tid] = s;

  int n = tid & (N_-1);
  int c = n >> 6, ct = (n >> 4) & 3, mc = n & 15;
  size_t segbase = (((size_t)(tid >> 14) * 256 + c) * 4 + ct) * 2;  // *512 shorts

  #pragma unroll
  for (int g = 0; g < 8; ++g) {                  // (kt=g>>2, qd=g&3), dims 8g..8g+7
    float4 a = p[2*g], b4 = p[2*g+1];
    float f[8] = {a.x,a.y,a.z,a.w, b4.x,b4.y,b4.z,b4.w};
    short8_ h0v, h1v, h2v;
    #pragma unroll
    for (int j = 0; j < 8; ++j) {
      short h0, h1, h2;
      bf3split(f[j], h0, h1, h2);
      h0v[j] = h0; h1v[j] = h1; h2v[j] = h2;
    }
    size_t off = ((segbase + (g>>2))*64 + (size_t)(g&3)*16 + mc)*8;
    *(short8_*)(P0 + off) = h0v;
    *(short8_*)(P1 + off) = h1v;
    *(short8_*)(P2 + off) = h2v;
  }
  if (tid < B_*S_) {
    int b = tid >> 11, ss = tid & (S_-1);
    int nn = sidx[ss];
    const float* src = xyz + ((size_t)b * N_ + nn) * 3;
    out[(size_t)tid*3+0] = src[0];
    out[(size_t)tid*3+1] = src[1];
    out[(size_t)tid*3+2] = src[2];
  }
}

// =====================================================================
// K2 (fast path): MFMA over pre-split planes + FIFO-decoupled top-32.
// Keys bit-identical to r3..r8.  New this round: admits go to a per-lane
// LDS FIFO (depth 8, [slot][lane] layout: 2-way bank aliasing = free);
// the wave runs exactly ONE insert-pass per chunk (all pending lanes
// progress together) + final drain.  Drain rate 1/chunk >= admit rate
// ~0.28/chunk so queues stay shallow.  Stale thresholds remain valid
// upper bounds (kept-set stats only shrink) -> admission superset, and
// FIFO preserves per-stream insert order -> pw/nbr bit-identical to r8.
// =====================================================================
__global__ __launch_bounds__(256) void k_knn(
    const short* __restrict__ P0, const short* __restrict__ P1,
    const short* __restrict__ P2, const int* __restrict__ sidx,
    const float* __restrict__ sqn, uint2* __restrict__ pw)
{
  // LDS: Bp 12288 | Dtr [64r][36c] 9216 | sqc 128 @21504 | qbuf 16384 @21760
  // merge phase aliases front as uint2 mbuf[32][130] = 33280 (queue dead then)
  __shared__ __align__(16) char smraw[38144];
  short* Bp  = (short*)smraw;
  float* Dtr = (float*)(smraw + 12288);
  float* sqc = (float*)(smraw + 21504);
  uint2* qb  = (uint2*)(smraw + 21760);   // [8 slots][256 lanes]

  const int t = threadIdx.x;
  const int b     = blockIdx.x & 7;          // XCD swizzle
  const int y     = blockIdx.x >> 3;
  const int tile  = y & 31;
  const int split = y >> 5;
  const int s0 = tile * 64;
  const float* Qb = sqn + (size_t)b * N_;

  const int lane = t & 63, wv = t >> 6;
  const int quad = lane >> 4, mcol = lane & 15;

  // ---- A fragments (wave wv owns sampled rows 16*wv..+15), from planes ----
  short8_ A0[2], A1[2], A2[2];
  {
    int srow = sidx[s0 + 16*wv + mcol];
    int cs = srow >> 6, cts = (srow >> 4) & 3, ms = srow & 15;
    size_t ab = (((size_t)(b*256 + cs))*4 + cts)*2*512 + ((size_t)quad*16 + ms)*8;
    #pragma unroll
    for (int kt = 0; kt < 2; ++kt) {
      A0[kt] = *(const short8_*)(P0 + ab + kt*512);
      A1[kt] = *(const short8_*)(P1 + ab + kt*512);
      A2[kt] = *(const short8_*)(P2 + ab + kt*512);
    }
  }

  float Lv[32]; int Li[32];
  #pragma unroll
  for (int i = 0; i < 32; ++i) { Lv[i] = 3.0e38f; Li[i] = 0; }

  const int r = t >> 2;        // selection row 0..63
  const int q = t & 3;         // stream within row
  const int n0base = split * NSPL_;
  const size_t bc8base = (size_t)b * 256;

  int qhead = 0, qtail = 0;    // per-lane FIFO state

  // ---- prefetch chunk 0 staging into registers ----
  short8_ pv0, pv1, pv2;
  {
    const int n0 = n0base;
    const size_t gsrc = (bc8base + (n0 >> 6)) * 8 + (size_t)(((n0 >> 5) & 1)*4 + wv);
    const size_t goff = gsrc*512 + (size_t)lane*8;
    pv0 = *(const short8_*)(P0 + goff);
    pv1 = *(const short8_*)(P1 + goff);
    pv2 = *(const short8_*)(P2 + goff);
  }

  for (int ch = 0; ch < CH32_; ++ch) {
    const int n0 = n0base + ch * 32;
    __syncthreads();                 // all waves done reading prev Bp
    *(short8_*)(Bp + (0*4 + wv)*512 + lane*8) = pv0;
    *(short8_*)(Bp + (1*4 + wv)*512 + lane*8) = pv1;
    *(short8_*)(Bp + (2*4 + wv)*512 + lane*8) = pv2;
    if (t < 8) *(float4*)(sqc + 4*t) = *(const float4*)(Qb + n0 + 4*t);
    __syncthreads();                 // Bp ready

    // ---- B-fragment reads (issued together) ----
    short8_ b0[2][2], b1[2][2], b2[2][2];   // [ct][kt]
    #pragma unroll
    for (int ct = 0; ct < 2; ++ct)
      #pragma unroll
      for (int kt = 0; kt < 2; ++kt) {
        int lo = lane*8;
        b0[ct][kt] = *(const short8_*)(Bp + (0*4 + ct*2 + kt)*512 + lo);
        b1[ct][kt] = *(const short8_*)(Bp + (1*4 + ct*2 + kt)*512 + lo);
        b2[ct][kt] = *(const short8_*)(Bp + (2*4 + ct*2 + kt)*512 + lo);
      }

    // ---- prefetch next chunk (hidden under MFMA + selection) ----
    if (ch + 1 < CH32_) {
      const int n1 = n0 + 32;
      const size_t gsrc = (bc8base + (n1 >> 6)) * 8 + (size_t)(((n1 >> 5) & 1)*4 + wv);
      const size_t goff = gsrc*512 + (size_t)lane*8;
      pv0 = *(const short8_*)(P0 + goff);
      pv1 = *(const short8_*)(P1 + goff);
      pv2 = *(const short8_*)(P2 + goff);
    }

    // ---- 16 MFMA per 16-cand tile (8 combos x 2 kt), 2 tiles ----
    #pragma unroll
    for (int ct = 0; ct < 2; ++ct) {
      f32x4_ a = {0.f, 0.f, 0.f, 0.f};
      #pragma unroll
      for (int kt = 0; kt < 2; ++kt) {
        a = __builtin_amdgcn_mfma_f32_16x16x32_bf16(A0[kt], b0[ct][kt], a, 0,0,0);
        a = __builtin_amdgcn_mfma_f32_16x16x32_bf16(A0[kt], b1[ct][kt], a, 0,0,0);
        a = __builtin_amdgcn_mfma_f32_16x16x32_bf16(A1[kt], b0[ct][kt], a, 0,0,0);
        a = __builtin_amdgcn_mfma_f32_16x16x32_bf16(A1[kt], b1[ct][kt], a, 0,0,0);
        a = __builtin_amdgcn_mfma_f32_16x16x32_bf16(A0[kt], b2[ct][kt], a, 0,0,0);
        a = __builtin_amdgcn_mfma_f32_16x16x32_bf16(A2[kt], b0[ct][kt], a, 0,0,0);
        a = __builtin_amdgcn_mfma_f32_16x16x32_bf16(A1[kt], b2[ct][kt], a, 0,0,0);
        a = __builtin_amdgcn_mfma_f32_16x16x32_bf16(A2[kt], b1[ct][kt], a, 0,0,0);
      }
      // keys -> Dtr (wave-local rows). C/D: col=lane&15, row=quad*4+reg
      int cc = 16*ct + mcol;
      float sq = sqc[cc];
      int rb = 16*wv + 4*quad;
      Dtr[(rb+0)*36 + cc] = sq - 2.f*a[0];
      Dtr[(rb+1)*36 + cc] = sq - 2.f*a[1];
      Dtr[(rb+2)*36 + cc] = sq - 2.f*a[2];
      Dtr[(rb+3)*36 + cc] = sq - 2.f*a[3];
    }
    // no barrier: Dtr rows 16wv..16wv+15 read only by this wave (lgkmcnt)

    // ---- steady drain: exactly one insert-pass per chunk (wave-wide) ----
    if (qhead < qtail) {
      uint2 e = qb[(qhead & 7)*256 + t];
      qhead++;
      float x = __uint_as_float(e.x);
      if (x < Lv[0])
        insert32(Lv, Li, x, (int)e.y);
    }

    // ---- admission: dual exact bounds, cheap FIFO pushes ----
    float ownL0 = Lv[0];
    float tmin = ownL0;                       // min of stream 32nds
    tmin = fminf(tmin, __shfl_xor(tmin, 1));
    tmin = fminf(tmin, __shfl_xor(tmin, 2));
    float t24 = Lv[24];                       // stream 8th-smallest
    t24 = fmaxf(t24, __shfl_xor(t24, 1));
    t24 = fmaxf(t24, __shfl_xor(t24, 2));     // max over streams: row-32nd <= t24
    const float thr = fminf(fminf(tmin, t24), ownL0);

    float4 ka = *(const float4*)(Dtr + r*36 + q*8);
    float4 kb = *(const float4*)(Dtr + r*36 + q*8 + 4);
    float x8[8] = {ka.x,ka.y,ka.z,ka.w, kb.x,kb.y,kb.z,kb.w};
    unsigned m = 0;
    #pragma unroll
    for (int i = 0; i < 8; ++i)
      m |= (x8[i] < thr) ? (1u << i) : 0u;
    while (m) {                               // per-lane, cheap body
      int i = __ffs(m) - 1;
      m &= m - 1;
      float xlo = (i & 1) ? ((i & 2) ? x8[3] : x8[1]) : ((i & 2) ? x8[2] : x8[0]);
      float xhi = (i & 1) ? ((i & 2) ? x8[7] : x8[5]) : ((i & 2) ? x8[6] : x8[4]);
      float x = (i & 4) ? xhi : xlo;
      if (qtail - qhead >= 8) {               // full: drain one in-place (rare)
        uint2 e = qb[(qhead & 7)*256 + t];
        qhead++;
        float xe = __uint_as_float(e.x);
        if (xe < Lv[0])
          insert32(Lv, Li, xe, (int)e.y);
      }
      qb[(qtail & 7)*256 + t] = make_uint2(__float_as_uint(x), (unsigned)(n0 + q*8 + i));
      qtail++;
    }
  }

  // ---- final drain ----
  while (__any(qhead < qtail)) {
    if (qhead < qtail) {
      uint2 e = qb[(qhead & 7)*256 + t];
      qhead++;
      float x = __uint_as_float(e.x);
      if (x < Lv[0])
        insert32(Lv, Li, x, (int)e.y);
    }
  }

  // ---- in-block 4-pointer merge (streams stored reversed -> ascending) ----
  uint2* mbuf = (uint2*)smraw;                 // [32][130]
  const int rowg = b * S_ + s0;
  for (int pass = 0; pass < 2; ++pass) {
    __syncthreads();
    const int rb = pass * 32;
    if (r >= rb && r < rb + 32) {
      #pragma unroll
      for (int i = 0; i < 32; ++i)
        mbuf[(r - rb)*130 + q*32 + (31 - i)] =
            make_uint2(__float_as_uint(Lv[i]), (unsigned)Li[i]);
    }
    __syncthreads();
    if (t < 32) {
      const uint2* Lrow = mbuf + t*130;
      uint2* dst = pw + ((size_t)(rowg + rb + t) * SPLIT_ + split) * 32;
      int p0 = 0, p1 = 0, p2 = 0, p3 = 0;
      for (int k = 0; k < 32; ++k) {
        float bv = 3.0e38f; unsigned bi = 0xFFFFFFFFu; int bq = 0;
        int pa[4] = {p0, p1, p2, p3};
        #pragma unroll
        for (int q4 = 0; q4 < 4; ++q4) {
          if (pa[q4] < 32) {
            uint2 e = Lrow[q4*32 + pa[q4]];
            float v = __uint_as_float(e.x);
            if (v < bv || (v == bv && e.y < bi)) { bv = v; bi = e.y; bq = q4; }
          }
        }
        dst[k] = make_uint2(__float_as_uint(bv), bi);
        if (bq == 0) p0++; else if (bq == 1) p1++; else if (bq == 2) p2++; else p3++;
      }
    }
  }
}

// =====================================================================
// FALLBACK path (ws too small): round-3 kernels, proven correct
// =====================================================================
__global__ __launch_bounds__(256) void k_prep_fb(
    const float* __restrict__ xyz, const float* __restrict__ points,
    const int* __restrict__ sidx, float* __restrict__ out, float* __restrict__ sqn)
{
  int tid = blockIdx.x * 256 + threadIdx.x;
  const float4* p = (const float4*)(points + (size_t)tid * 64);
  float s = 0.f;
  #pragma unroll
  for (int i = 0; i < 16; ++i) {
    float4 v = p[i];
    s += v.x*v.x + v.y*v.y + v.z*v.z + v.w*v.w;
  }
  sqn[tid] = s;
  if (tid < B_*S_) {
    int b = tid >> 11, ss = tid & (S_-1);
    int n = sidx[ss];
    const float* src = xyz + ((size_t)b * N_ + n) * 3;
    out[(size_t)tid*3+0] = src[0];
    out[(size_t)tid*3+1] = src[1];
    out[(size_t)tid*3+2] = src[2];
  }
}

__global__ __launch_bounds__(256) void k_knn_fb(
    const float* __restrict__ points, const int* __restrict__ sidx,
    const float* __restrict__ sqn, uint2* __restrict__ pw)
{
  __shared__ __align__(16) char smraw[45312];
  short* Bp0 = (short*)smraw;
  short* Bp1 = (short*)(smraw + 9216);
  short* Bp2 = (short*)(smraw + 18432);
  float* Dt  = (float*)(smraw + 27648);
  float* sqc = (float*)(smraw + 45056);

  const int t = threadIdx.x;
  const int b     = blockIdx.x & 7;
  const int y     = blockIdx.x >> 3;
  const int tile  = y & 31;
  const int split = y >> 5;
  const int s0 = tile * 64;
  const float* Pb = points + (size_t)b * N_ * 64;
  const float* Qb = sqn    + (size_t)b * N_;

  const int lane = t & 63, wv = t >> 6;
  const int quad = lane >> 4, mcol = lane & 15;

  short8_ A0[2], A1[2], A2[2];
  {
    int srow = sidx[s0 + 16*wv + mcol];
    const float* ar = Pb + (size_t)srow * 64;
    #pragma unroll
    for (int kt = 0; kt < 2; ++kt) {
      float4 v0 = *(const float4*)(ar + 32*kt + 8*quad);
      float4 v1 = *(const float4*)(ar + 32*kt + 8*quad + 4);
      float f[8] = {v0.x,v0.y,v0.z,v0.w,v1.x,v1.y,v1.z,v1.w};
      #pragma unroll
      for (int j = 0; j < 8; ++j) {
        short h0, h1, h2;
        bf3split(f[j], h0, h1, h2);
        A0[kt][j] = h0; A1[kt][j] = h1; A2[kt][j] = h2;
      }
    }
  }

  float Lv[32]; int Li[32];
  #pragma unroll
  for (int i = 0; i < 32; ++i) { Lv[i] = 3.0e38f; Li[i] = 0; }

  const int r = t >> 2;
  const int q = t & 3;
  const int n0base = split * NSPL_;

  for (int ch = 0; ch < NSPL_/64; ++ch) {
    const int n0 = n0base + ch * 64;
    {
      const int n = t & 63, jg = t >> 6;
      const float* src = Pb + (size_t)(n0 + n) * 64 + 16*jg;
      float4 u0 = *(const float4*)(src);
      float4 u1 = *(const float4*)(src + 4);
      float4 u2 = *(const float4*)(src + 8);
      float4 u3 = *(const float4*)(src + 12);
      float f[16] = {u0.x,u0.y,u0.z,u0.w, u1.x,u1.y,u1.z,u1.w,
                     u2.x,u2.y,u2.z,u2.w, u3.x,u3.y,u3.z,u3.w};
      short8_ p0[2], p1[2], p2[2];
      #pragma unroll
      for (int j = 0; j < 16; ++j) {
        short h0, h1, h2;
        bf3split(f[j], h0, h1, h2);
        p0[j>>3][j&7] = h0; p1[j>>3][j&7] = h1; p2[j>>3][j&7] = h2;
      }
      *(short8_*)(Bp0 + n*72 + 16*jg)     = p0[0];
      *(short8_*)(Bp0 + n*72 + 16*jg + 8) = p0[1];
      *(short8_*)(Bp1 + n*72 + 16*jg)     = p1[0];
      *(short8_*)(Bp1 + n*72 + 16*jg + 8) = p1[1];
      *(short8_*)(Bp2 + n*72 + 16*jg)     = p2[0];
      *(short8_*)(Bp2 + n*72 + 16*jg + 8) = p2[1];
      if (t < 16) *(float4*)(sqc + 4*t) = *(const float4*)(Qb + n0 + 4*t);
    }
    __syncthreads();

    f32x4_ acc[4];
    #pragma unroll
    for (int ct = 0; ct < 4; ++ct) {
      const int boff = (16*ct + mcol)*72 + 8*quad;
      short8_ b0[2], b1[2], b2[2];
      b0[0] = *(const short8_*)(Bp0 + boff); b0[1] = *(const short8_*)(Bp0 + boff + 32);
      b1[0] = *(const short8_*)(Bp1 + boff); b1[1] = *(const short8_*)(Bp1 + boff + 32);
      b2[0] = *(const short8_*)(Bp2 + boff); b2[1] = *(const short8_*)(Bp2 + boff + 32);
      f32x4_ a = {0.f, 0.f, 0.f, 0.f};
      #pragma unroll
      for (int kt = 0; kt < 2; ++kt) {
        a = __builtin_amdgcn_mfma_f32_16x16x32_bf16(A0[kt], b0[kt], a, 0,0,0);
        a = __builtin_amdgcn_mfma_f32_16x16x32_bf16(A0[kt], b1[kt], a, 0,0,0);
        a = __builtin_amdgcn_mfma_f32_16x16x32_bf16(A1[kt], b0[kt], a, 0,0,0);
        a = __builtin_amdgcn_mfma_f32_16x16x32_bf16(A1[kt], b1[kt], a, 0,0,0);
        a = __builtin_amdgcn_mfma_f32_16x16x32_bf16(A0[kt], b2[kt], a, 0,0,0);
        a = __builtin_amdgcn_mfma_f32_16x16x32_bf16(A2[kt], b0[kt], a, 0,0,0);
        a = __builtin_amdgcn_mfma_f32_16x16x32_bf16(A1[kt], b2[kt], a, 0,0,0);
        a = __builtin_amdgcn_mfma_f32_16x16x32_bf16(A2[kt], b1[kt], a, 0,0,0);
      }
      acc[ct] = a;
    }
    #pragma unroll
    for (int ct = 0; ct < 4; ++ct) {
      int c = 16*ct + mcol;
      float sq = sqc[c];
      float4 kv;
      kv.x = sq - 2.f*acc[ct][0];
      kv.y = sq - 2.f*acc[ct][1];
      kv.z = sq - 2.f*acc[ct][2];
      kv.w = sq - 2.f*acc[ct][3];
      *(float4*)(Dt + c*68 + 16*wv + 4*quad) = kv;
    }
    __syncthreads();

    float L0 = Lv[0];
    L0 = fminf(L0, __shfl_xor(L0, 1));
    L0 = fminf(L0, __shfl_xor(L0, 2));
    const float tau = L0;
    #pragma unroll
    for (int g = 0; g < 4; ++g) {
      #pragma unroll
      for (int u = 0; u < 4; ++u) {
        int c = q*16 + g*4 + u;
        float x = Dt[c*68 + r];
        if (x < fminf(tau, Lv[0]))
          insert32(Lv, Li, x, n0 + c);
      }
    }
  }

  uint2* mbuf = (uint2*)smraw;
  const int rowg = b * S_ + s0;
  for (int pass = 0; pass < 2; ++pass) {
    __syncthreads();
    const int rb = pass * 32;
    if (r >= rb && r < rb + 32) {
      #pragma unroll
      for (int i = 0; i < 32; ++i)
        mbuf[(r - rb)*130 + q*32 + (31 - i)] =
            make_uint2(__float_as_uint(Lv[i]), (unsigned)Li[i]);
    }
    __syncthreads();
    if (t < 32) {
      const uint2* Lrow = mbuf + t*130;
      uint2* dst = pw + ((size_t)(rowg + rb + t) * SPLIT_ + split) * 32;
      int p0 = 0, p1 = 0, p2 = 0, p3 = 0;
      for (int k = 0; k < 32; ++k) {
        float bv = 3.0e38f; unsigned bi = 0xFFFFFFFFu; int bq = 0;
        int pa[4] = {p0, p1, p2, p3};
        #pragma unroll
        for (int q4 = 0; q4 < 4; ++q4) {
          if (pa[q4] < 32) {
            uint2 e = Lrow[q4*32 + pa[q4]];
            float v = __uint_as_float(e.x);
            if (v < bv || (v == bv && e.y < bi)) { bv = v; bi = e.y; bq = q4; }
          }
        }
        dst[k] = make_uint2(__float_as_uint(bv), bi);
        if (bq == 0) p0++; else if (bq == 1) p1++; else if (bq == 2) p2++; else p3++;
      }
    }
  }
}

// =====================================================================
// K2b: merge the 4 split-partials (ascending) per row -> 32 indices
// =====================================================================
__global__ __launch_bounds__(256) void k_sel(const uint2* __restrict__ pw,
                                             int* __restrict__ nbr)
{
  int row = blockIdx.x * 256 + threadIdx.x;       // 0 .. B*S-1
  const uint2* L = pw + (size_t)row * (SPLIT_*32);
  int* dst = nbr + (size_t)row * K_;
  int p[4] = {0,0,0,0};
  for (int k = 0; k < K_; ++k) {
    float bv = 3.0e38f; unsigned bi = 0xFFFFFFFFu; int bq = 0;
    #pragma unroll
    for (int q4 = 0; q4 < 4; ++q4) {
      if (p[q4] < 32) {
        uint2 e = L[q4*32 + p[q4]];
        float v = __uint_as_float(e.x);
        if (v < bv || (v == bv && e.y < bi)) { bv = v; bi = e.y; bq = q4; }
      }
    }
    dst[k] = (int)bi;
    p[bq]++;
  }
}

// =====================================================================
// K3: MFMA MLP (bf16 2-split) + fused bias/relu/maxpool.
// =====================================================================
__device__ __forceinline__ void layer_mfma(
    int lane, int wv, const float* Xf, float* Hf,
    const float* __restrict__ wgt, const float* scl, const float* bia)
{
  const int quad = lane >> 4, mcol = lane & 15;
  const int o = wv*16 + mcol;                 // this wave's output column
  const float sc = scl[o];
  short8_ B0[2], B1[2];
  #pragma unroll
  for (int kt = 0; kt < 2; ++kt) {
    const float* wp = wgt + o*64 + kt*32 + quad*8;
    float4 u0 = *(const float4*)(wp);
    float4 u1 = *(const float4*)(wp + 4);
    float f[8] = {u0.x*sc,u0.y*sc,u0.z*sc,u0.w*sc,
                  u1.x*sc,u1.y*sc,u1.z*sc,u1.w*sc};
    bf2split8(f, B0[kt], B1[kt]);
  }
  const float bo = bia[o];
  const int kt2 = (o >> 5) & 1, qk2 = (o >> 3) & 3, h2 = (o >> 2) & 1, j2 = o & 3;
  #pragma unroll
  for (int mt = 0; mt < 2; ++mt) {
    short8_ A0[2], A1[2];
    #pragma unroll
    for (int kt = 0; kt < 2; ++kt) {
      float4 x0 = *(const float4*)(Xf + (((mt*2+kt)*2+0)*256) + lane*4);
      float4 x1 = *(const float4*)(Xf + (((mt*2+kt)*2+1)*256) + lane*4);
      float f[8] = {x0.x,x0.y,x0.z,x0.w, x1.x,x1.y,x1.z,x1.w};
      bf2split8(f, A0[kt], A1[kt]);
    }
    f32x4_ a = {0.f, 0.f, 0.f, 0.f};
    #pragma unroll
    for (int kt = 0; kt < 2; ++kt) {
      a = __builtin_amdgcn_mfma_f32_16x16x32_bf16(A0[kt], B0[kt], a, 0,0,0);
      a = __builtin_amdgcn_mfma_f32_16x16x32_bf16(A0[kt], B1[kt], a, 0,0,0);
      a = __builtin_amdgcn_mfma_f32_16x16x32_bf16(A1[kt], B0[kt], a, 0,0,0);
    }
    #pragma unroll
    for (int reg = 0; reg < 4; ++reg) {
      int ml = quad*4 + reg;                  // m within mtile
      float hval = fmaxf(a[reg] + bo, 0.f);
      Hf[((mt*2 + kt2)*2 + h2)*256 + (qk2*16 + ml)*4 + j2] = hval;
    }
  }
}

__global__ __launch_bounds__(256) void k_mlp(
    const float* __restrict__ points, const int* __restrict__ nbr,
    const float* __restrict__ w0, const float* __restrict__ b0,
    const float* __restrict__ g0, const float* __restrict__ be0,
    const float* __restrict__ m0, const float* __restrict__ v0,
    const float* __restrict__ w1, const float* __restrict__ b1,
    const float* __restrict__ g1, const float* __restrict__ be1,
    const float* __restrict__ m1, const float* __restrict__ v1,
    const float* __restrict__ w2, const float* __restrict__ b2,
    const float* __restrict__ g2, const float* __restrict__ be2,
    const float* __restrict__ m2, const float* __restrict__ v2,
    float* __restrict__ out)
{
  __shared__ __align__(16) float Xf[2048];   // 8 segs x 1KB
  __shared__ __align__(16) float Hf[2048];
  __shared__ float scl[128];
  __shared__ float bia[128];
  __shared__ int   nIx[32];

  const int t  = threadIdx.x;
  const int bs = blockIdx.x;
  const int b  = bs >> 11;
  const int lane = t & 63, wv = t >> 6;
  const int quad = lane >> 4, mcol = lane & 15;

  if (t < 32) nIx[t] = nbr[(size_t)bs * K_ + t];
  if (t >= 64 && t < 128) {                  // layer-0 BN fold in parallel
    int i = t - 64;
    float sc = g0[i] * rsqrtf(v0[i] + 1e-5f);
    scl[i] = sc;
    bia[i] = (b0[i] - m0[i]) * sc + be0[i];
  }
  __syncthreads();
  // stage X (32 rows x 64 ch fp32) into fragment-major segments
  #pragma unroll
  for (int rep = 0; rep < 2; ++rep) {
    int task = rep*256 + t;
    int row = task >> 4, j4 = task & 15;
    float4 v = *(const float4*)(points + ((size_t)b*N_ + nIx[row])*64 + j4*4);
    int kt = j4 >> 3, qk = (j4 >> 1) & 3, h = j4 & 1;
    *(float4*)(Xf + (((row>>4)*2 + kt)*2 + h)*256 + (qk*16 + (row&15))*4) = v;
  }
  __syncthreads();

  layer_mfma(lane, wv, Xf, Hf, w0, scl, bia);      // X -> H
  __syncthreads();
  if (t < 64) {
    float sc = g1[t] * rsqrtf(v1[t] + 1e-5f);
    scl[t] = sc;
    bia[t] = (b1[t] - m1[t]) * sc + be1[t];
  }
  __syncthreads();
  layer_mfma(lane, wv, Hf, Xf, w1, scl, bia);      // H -> X
  __syncthreads();
  if (t < 128) {
    float sc = g2[t] * rsqrtf(v2[t] + 1e-5f);
    scl[t] = sc;
    bia[t] = (b2[t] - m2[t]) * sc + be2[t];
  }
  __syncthreads();

  // ---- layer 2: 64 -> 128, fused maxpool.  A-frags hoisted ----
  short8_ A0[2][2], A1[2][2];
  #pragma unroll
  for (int mt = 0; mt < 2; ++mt)
    #pragma unroll
    for (int kt = 0; kt < 2; ++kt) {
      float4 x0 = *(const float4*)(Xf + (((mt*2+kt)*2+0)*256) + lane*4);
      float4 x1 = *(const float4*)(Xf + (((mt*2+kt)*2+1)*256) + lane*4);
      float f[8] = {x0.x,x0.y,x0.z,x0.w, x1.x,x1.y,x1.z,x1.w};
      bf2split8(f, A0[mt][kt], A1[mt][kt]);
    }
  float* outp = out + (size_t)(B_*S_)*3 + (size_t)bs*128;
  #pragma unroll
  for (int sub = 0; sub < 2; ++sub) {
    const int o = (wv*2 + sub)*16 + mcol;
    const float sc = scl[o];
    short8_ B0[2], B1[2];
    #pragma unroll
    for (int kt = 0; kt < 2; ++kt) {
      const float* wp = w2 + o*64 + kt*32 + quad*8;
      float4 u0 = *(const float4*)(wp);
      float4 u1 = *(const float4*)(wp + 4);
      float f[8] = {u0.x*sc,u0.y*sc,u0.z*sc,u0.w*sc,
                    u1.x*sc,u1.y*sc,u1.z*sc,u1.w*sc};
      bf2split8(f, B0[kt], B1[kt]);
    }
    float vmax = -3.0e38f;
    #pragma unroll
    for (int mt = 0; mt < 2; ++mt) {
      f32x4_ a = {0.f, 0.f, 0.f, 0.f};
      #pragma unroll
      for (int kt = 0; kt < 2; ++kt) {
        a = __builtin_amdgcn_mfma_f32_16x16x32_bf16(A0[mt][kt], B0[kt], a, 0,0,0);
        a = __builtin_amdgcn_mfma_f32_16x16x32_bf16(A0[mt][kt], B1[kt], a, 0,0,0);
        a = __builtin_amdgcn_mfma_f32_16x16x32_bf16(A1[mt][kt], B0[kt], a, 0,0,0);
      }
      vmax = fmaxf(vmax, fmaxf(fmaxf(a[0], a[1]), fmaxf(a[2], a[3])));
    }
    vmax = fmaxf(vmax, __shfl_xor(vmax, 16));
    vmax = fmaxf(vmax, __shfl_xor(vmax, 32));
    if (quad == 0) outp[o] = fmaxf(vmax + bia[o], 0.f);
  }
}

// =====================================================================
extern "C" void kernel_launch(void* const* d_in, const int* in_sizes, int n_in,
                              void* d_out, int out_size, void* d_ws, size_t ws_size,
                              hipStream_t stream)
{
  const float* xyz  = (const float*)d_in[0];
  const float* pts  = (const float*)d_in[1];
  const int*   sidx = (const int*)  d_in[2];
  const float* w0 = (const float*)d_in[3];
  const float* b0 = (const float*)d_in[4];
  const float* g0 = (const float*)d_in[5];
  const float* be0= (const float*)d_in[6];
  const float* m0 = (const float*)d_in[7];
  const float* v0 = (const float*)d_in[8];
  const float* w1 = (const float*)d_in[9];
  const float* b1 = (const float*)d_in[10];
  const float* g1 = (const float*)d_in[11];
  const float* be1= (const float*)d_in[12];
  const float* m1 = (const float*)d_in[13];
  const float* v1 = (const float*)d_in[14];
  const float* w2 = (const float*)d_in[15];
  const float* b2 = (const float*)d_in[16];
  const float* g2 = (const float*)d_in[17];
  const float* be2= (const float*)d_in[18];
  const float* m2 = (const float*)d_in[19];
  const float* v2 = (const float*)d_in[20];

  float* out = (float*)d_out;
  // ws: sqn (512KB) | nbr (2MB) | pw (16.8MB) | planes (3 x 16.78MB)
  float* sqn = (float*)d_ws;
  int*   nbr = (int*)  ((char*)d_ws + (size_t)B_*N_*4);
  uint2* pw  = (uint2*)((char*)d_ws + (size_t)B_*N_*4 + (size_t)B_*S_*K_*4);
  char*  pl  = (char*)d_ws + (size_t)B_*N_*4 + (size_t)B_*S_*K_*4
             + (size_t)B_*S_*SPLIT_*32*8;
  short* P0 = (short*)pl;
  short* P1 = P0 + PLANE_;
  short* P2 = P1 + PLANE_;
  const size_t need = (size_t)B_*N_*4 + (size_t)B_*S_*K_*4
                    + (size_t)B_*S_*SPLIT_*32*8 + 3*PLANE_*2;

  if (ws_size >= need) {
    k_prep<<<(B_*N_)/256, 256, 0, stream>>>(xyz, pts, sidx, out, sqn, P0, P1, P2);
    k_knn <<<B_*32*SPLIT_, 256, 0, stream>>>(P0, P1, P2, sidx, sqn, pw);
  } else {
    k_prep_fb<<<(B_*N_)/256, 256, 0, stream>>>(xyz, pts, sidx, out, sqn);
    k_knn_fb <<<B_*32*SPLIT_, 256, 0, stream>>>(pts, sidx, sqn, pw);
  }
  k_sel <<<(B_*S_)/256, 256, 0, stream>>>(pw, nbr);
  k_mlp <<<B_*S_, 256, 0, stream>>>(pts, nbr,
            w0,b0,g0,be0,m0,v0, w1,b1,g1,be1,m1,v1, w2,b2,g2,be2,m2,v2, out);
}

// Round 10
// 1303.619 us; speedup vs baseline: 49.3411x; 1.0123x over previous
//
#include <hip/hip_runtime.h>

#define B_  8
#define N_  16384
#define D_  64
#define S_  2048
#define K_  32
#define SPLIT_  4
#define NSPL_   (N_/SPLIT_)       // 4096 candidates per block
#define CH32_   (NSPL_/32)        // 128 chunks of 32
#define PLANE_  ((size_t)B_*N_*64) // shorts per plane (8.39M = 16.78 MB)

using short8_ = __attribute__((ext_vector_type(8))) short;
using f32x4_  = __attribute__((ext_vector_type(4))) float;

// =====================================================================
// exact bf16 triple-split of fp32 (truncation-based): f = h0 + h1 + h2
// =====================================================================
__device__ __forceinline__ void bf3split(float f, short& h0, short& h1, short& h2)
{
  unsigned u0 = __float_as_uint(f);
  float f0 = __uint_as_float(u0 & 0xFFFF0000u);
  h0 = (short)(u0 >> 16);
  float r1 = f - f0;
  unsigned u1 = __float_as_uint(r1);
  float f1 = __uint_as_float(u1 & 0xFFFF0000u);
  h1 = (short)(u1 >> 16);
  float r2 = r1 - f1;                 // <= 8 significant bits: bf16-exact
  h2 = (short)(__float_as_uint(r2) >> 16);
}

// bf16 2-split of 8 floats (for the MLP; residual ~2^-16 rel)
__device__ __forceinline__ void bf2split8(const float* f, short8_& h0, short8_& h1)
{
  #pragma unroll
  for (int j = 0; j < 8; ++j) {
    unsigned u = __float_as_uint(f[j]);
    h0[j] = (short)(u >> 16);
    float r = f[j] - __uint_as_float(u & 0xFFFF0000u);
    h1[j] = (short)(__float_as_uint(r) >> 16);
  }
}

// sorted-DESCENDING 32-entry list (Lv[0] = largest kept)
__device__ __forceinline__ void insert32(float (&Lv)[32], int (&Li)[32], float x, int n)
{
  bool ci = x < Lv[0];
  #pragma unroll
  for (int i = 0; i < 31; ++i) {
    bool c1 = x < Lv[i+1];
    float nv = c1 ? Lv[i+1] : (ci ? x : Lv[i]);
    int   ni = c1 ? Li[i+1] : (ci ? n : Li[i]);
    Lv[i] = nv; Li[i] = ni;
    ci = c1;
  }
  Lv[31] = ci ? x : Lv[31];
  Li[31] = ci ? n : Li[31];
}

// =====================================================================
// K1 (fast path): sqn + new_xyz gather + fragment-major bf16x3 planes
// sqn: EXACT round-3 expression (bit-identical keys -> selection).
// =====================================================================
__global__ __launch_bounds__(256) void k_prep(
    const float* __restrict__ xyz, const float* __restrict__ points,
    const int* __restrict__ sidx, float* __restrict__ out, float* __restrict__ sqn,
    short* __restrict__ P0, short* __restrict__ P1, short* __restrict__ P2)
{
  int tid = blockIdx.x * 256 + threadIdx.x;      // 0 .. B*N-1
  const float4* p = (const float4*)(points + (size_t)tid * 64);

  float s = 0.f;
  #pragma unroll
  for (int i = 0; i < 16; ++i) {
    float4 v = p[i];
    s += v.x*v.x + v.y*v.y + v.z*v.z + v.w*v.w;
  }
  sqn[tid] = s;

  int n = tid & (N_-1);
  int c = n >> 6, ct = (n >> 4) & 3, mc = n & 15;
  size_t segbase = (((size_t)(tid >> 14) * 256 + c) * 4 + ct) * 2;  // *512 shorts

  #pragma unroll
  for (int g = 0; g < 8; ++g) {                  // (kt=g>>2, qd=g&3), dims 8g..8g+7
    float4 a = p[2*g], b4 = p[2*g+1];
    float f[8] = {a.x,a.y,a.z,a.w, b4.x,b4.y,b4.z,b4.w};
    short8_ h0v, h1v, h2v;
    #pragma unroll
    for (int j = 0; j < 8; ++j) {
      short h0, h1, h2;
      bf3split(f[j], h0, h1, h2);
      h0v[j] = h0; h1v[j] = h1; h2v[j] = h2;
    }
    size_t off = ((segbase + (g>>2))*64 + (size_t)(g&3)*16 + mc)*8;
    *(short8_*)(P0 + off) = h0v;
    *(short8_*)(P1 + off) = h1v;
    *(short8_*)(P2 + off) = h2v;
  }
  if (tid < B_*S_) {
    int b = tid >> 11, ss = tid & (S_-1);
    int nn = sidx[ss];
    const float* src = xyz + ((size_t)b * N_ + nn) * 3;
    out[(size_t)tid*3+0] = src[0];
    out[(size_t)tid*3+1] = src[1];
    out[(size_t)tid*3+2] = src[2];
  }
}

// =====================================================================
// K2 (fast path): MFMA over pre-split planes + FIFO-decoupled top-32.
// r10 change: ADAPTIVE drain — the wave-wide insert-pass runs only when
// some lane has >=2 pending (passes drop ~128 -> ~max-lane-admits ~60).
// Thresholds computed from more-lagged lists are still valid upper
// bounds -> admitted set remains a superset of each stream's true
// top-32 -> final lists (= top-32 of inserted multiset), pw, nbr are
// IDENTICAL to r8/r9.  Keys bit-identical to r3..r9.
// =====================================================================
__global__ __launch_bounds__(256) void k_knn(
    const short* __restrict__ P0, const short* __restrict__ P1,
    const short* __restrict__ P2, const int* __restrict__ sidx,
    const float* __restrict__ sqn, uint2* __restrict__ pw)
{
  // LDS: Bp 12288 | Dtr [64r][36c] 9216 | sqc 128 @21504 | qbuf 16384 @21760
  // merge phase aliases front as uint2 mbuf[32][130] = 33280 (queue dead then)
  __shared__ __align__(16) char smraw[38144];
  short* Bp  = (short*)smraw;
  float* Dtr = (float*)(smraw + 12288);
  float* sqc = (float*)(smraw + 21504);
  uint2* qb  = (uint2*)(smraw + 21760);   // [8 slots][256 lanes]

  const int t = threadIdx.x;
  const int b     = blockIdx.x & 7;          // XCD swizzle
  const int y     = blockIdx.x >> 3;
  const int tile  = y & 31;
  const int split = y >> 5;
  const int s0 = tile * 64;
  const float* Qb = sqn + (size_t)b * N_;

  const int lane = t & 63, wv = t >> 6;
  const int quad = lane >> 4, mcol = lane & 15;

  // ---- A fragments (wave wv owns sampled rows 16*wv..+15), from planes ----
  short8_ A0[2], A1[2], A2[2];
  {
    int srow = sidx[s0 + 16*wv + mcol];
    int cs = srow >> 6, cts = (srow >> 4) & 3, ms = srow & 15;
    size_t ab = (((size_t)(b*256 + cs))*4 + cts)*2*512 + ((size_t)quad*16 + ms)*8;
    #pragma unroll
    for (int kt = 0; kt < 2; ++kt) {
      A0[kt] = *(const short8_*)(P0 + ab + kt*512);
      A1[kt] = *(const short8_*)(P1 + ab + kt*512);
      A2[kt] = *(const short8_*)(P2 + ab + kt*512);
    }
  }

  float Lv[32]; int Li[32];
  #pragma unroll
  for (int i = 0; i < 32; ++i) { Lv[i] = 3.0e38f; Li[i] = 0; }

  const int r = t >> 2;        // selection row 0..63
  const int q = t & 3;         // stream within row
  const int n0base = split * NSPL_;
  const size_t bc8base = (size_t)b * 256;

  int qhead = 0, qtail = 0;    // per-lane FIFO state

  // ---- prefetch chunk 0 staging into registers ----
  short8_ pv0, pv1, pv2;
  {
    const int n0 = n0base;
    const size_t gsrc = (bc8base + (n0 >> 6)) * 8 + (size_t)(((n0 >> 5) & 1)*4 + wv);
    const size_t goff = gsrc*512 + (size_t)lane*8;
    pv0 = *(const short8_*)(P0 + goff);
    pv1 = *(const short8_*)(P1 + goff);
    pv2 = *(const short8_*)(P2 + goff);
  }

  for (int ch = 0; ch < CH32_; ++ch) {
    const int n0 = n0base + ch * 32;
    __syncthreads();                 // all waves done reading prev Bp
    *(short8_*)(Bp + (0*4 + wv)*512 + lane*8) = pv0;
    *(short8_*)(Bp + (1*4 + wv)*512 + lane*8) = pv1;
    *(short8_*)(Bp + (2*4 + wv)*512 + lane*8) = pv2;
    if (t < 8) *(float4*)(sqc + 4*t) = *(const float4*)(Qb + n0 + 4*t);
    __syncthreads();                 // Bp ready

    // ---- B-fragment reads (issued together) ----
    short8_ b0[2][2], b1[2][2], b2[2][2];   // [ct][kt]
    #pragma unroll
    for (int ct = 0; ct < 2; ++ct)
      #pragma unroll
      for (int kt = 0; kt < 2; ++kt) {
        int lo = lane*8;
        b0[ct][kt] = *(const short8_*)(Bp + (0*4 + ct*2 + kt)*512 + lo);
        b1[ct][kt] = *(const short8_*)(Bp + (1*4 + ct*2 + kt)*512 + lo);
        b2[ct][kt] = *(const short8_*)(Bp + (2*4 + ct*2 + kt)*512 + lo);
      }

    // ---- prefetch next chunk (hidden under MFMA + selection) ----
    if (ch + 1 < CH32_) {
      const int n1 = n0 + 32;
      const size_t gsrc = (bc8base + (n1 >> 6)) * 8 + (size_t)(((n1 >> 5) & 1)*4 + wv);
      const size_t goff = gsrc*512 + (size_t)lane*8;
      pv0 = *(const short8_*)(P0 + goff);
      pv1 = *(const short8_*)(P1 + goff);
      pv2 = *(const short8_*)(P2 + goff);
    }

    // ---- 16 MFMA per 16-cand tile (8 combos x 2 kt), 2 tiles ----
    #pragma unroll
    for (int ct = 0; ct < 2; ++ct) {
      f32x4_ a = {0.f, 0.f, 0.f, 0.f};
      #pragma unroll
      for (int kt = 0; kt < 2; ++kt) {
        a = __builtin_amdgcn_mfma_f32_16x16x32_bf16(A0[kt], b0[ct][kt], a, 0,0,0);
        a = __builtin_amdgcn_mfma_f32_16x16x32_bf16(A0[kt], b1[ct][kt], a, 0,0,0);
        a = __builtin_amdgcn_mfma_f32_16x16x32_bf16(A1[kt], b0[ct][kt], a, 0,0,0);
        a = __builtin_amdgcn_mfma_f32_16x16x32_bf16(A1[kt], b1[ct][kt], a, 0,0,0);
        a = __builtin_amdgcn_mfma_f32_16x16x32_bf16(A0[kt], b2[ct][kt], a, 0,0,0);
        a = __builtin_amdgcn_mfma_f32_16x16x32_bf16(A2[kt], b0[ct][kt], a, 0,0,0);
        a = __builtin_amdgcn_mfma_f32_16x16x32_bf16(A1[kt], b2[ct][kt], a, 0,0,0);
        a = __builtin_amdgcn_mfma_f32_16x16x32_bf16(A2[kt], b1[ct][kt], a, 0,0,0);
      }
      // keys -> Dtr (wave-local rows). C/D: col=lane&15, row=quad*4+reg
      int cc = 16*ct + mcol;
      float sq = sqc[cc];
      int rb = 16*wv + 4*quad;
      Dtr[(rb+0)*36 + cc] = sq - 2.f*a[0];
      Dtr[(rb+1)*36 + cc] = sq - 2.f*a[1];
      Dtr[(rb+2)*36 + cc] = sq - 2.f*a[2];
      Dtr[(rb+3)*36 + cc] = sq - 2.f*a[3];
    }
    // no barrier: Dtr rows 16wv..16wv+15 read only by this wave (lgkmcnt)

    // ---- adaptive drain: pass only when some lane has >=2 pending ----
    if (__any((qtail - qhead) >= 2)) {
      if (qhead < qtail) {
        uint2 e = qb[(qhead & 7)*256 + t];
        qhead++;
        float x = __uint_as_float(e.x);
        if (x < Lv[0])
          insert32(Lv, Li, x, (int)e.y);
      }
    }

    // ---- admission: dual exact bounds, cheap FIFO pushes ----
    float ownL0 = Lv[0];
    float tmin = ownL0;                       // min of stream 32nds
    tmin = fminf(tmin, __shfl_xor(tmin, 1));
    tmin = fminf(tmin, __shfl_xor(tmin, 2));
    float t24 = Lv[24];                       // stream 8th-smallest
    t24 = fmaxf(t24, __shfl_xor(t24, 1));
    t24 = fmaxf(t24, __shfl_xor(t24, 2));     // max over streams: row-32nd <= t24
    const float thr = fminf(fminf(tmin, t24), ownL0);

    float4 ka = *(const float4*)(Dtr + r*36 + q*8);
    float4 kb = *(const float4*)(Dtr + r*36 + q*8 + 4);
    float x8[8] = {ka.x,ka.y,ka.z,ka.w, kb.x,kb.y,kb.z,kb.w};
    unsigned m = 0;
    #pragma unroll
    for (int i = 0; i < 8; ++i)
      m |= (x8[i] < thr) ? (1u << i) : 0u;
    while (m) {                               // per-lane, cheap body
      int i = __ffs(m) - 1;
      m &= m - 1;
      float xlo = (i & 1) ? ((i & 2) ? x8[3] : x8[1]) : ((i & 2) ? x8[2] : x8[0]);
      float xhi = (i & 1) ? ((i & 2) ? x8[7] : x8[5]) : ((i & 2) ? x8[6] : x8[4]);
      float x = (i & 4) ? xhi : xlo;
      if (qtail - qhead >= 8) {               // full: drain one in-place (rare)
        uint2 e = qb[(qhead & 7)*256 + t];
        qhead++;
        float xe = __uint_as_float(e.x);
        if (xe < Lv[0])
          insert32(Lv, Li, xe, (int)e.y);
      }
      qb[(qtail & 7)*256 + t] = make_uint2(__float_as_uint(x), (unsigned)(n0 + q*8 + i));
      qtail++;
    }
  }

  // ---- final drain ----
  while (__any(qhead < qtail)) {
    if (qhead < qtail) {
      uint2 e = qb[(qhead & 7)*256 + t];
      qhead++;
      float x = __uint_as_float(e.x);
      if (x < Lv[0])
        insert32(Lv, Li, x, (int)e.y);
    }
  }

  // ---- in-block 4-pointer merge (streams stored reversed -> ascending) ----
  uint2* mbuf = (uint2*)smraw;                 // [32][130]
  const int rowg = b * S_ + s0;
  for (int pass = 0; pass < 2; ++pass) {
    __syncthreads();
    const int rb = pass * 32;
    if (r >= rb && r < rb + 32) {
      #pragma unroll
      for (int i = 0; i < 32; ++i)
        mbuf[(r - rb)*130 + q*32 + (31 - i)] =
            make_uint2(__float_as_uint(Lv[i]), (unsigned)Li[i]);
    }
    __syncthreads();
    if (t < 32) {
      const uint2* Lrow = mbuf + t*130;
      uint2* dst = pw + ((size_t)(rowg + rb + t) * SPLIT_ + split) * 32;
      int p0 = 0, p1 = 0, p2 = 0, p3 = 0;
      for (int k = 0; k < 32; ++k) {
        float bv = 3.0e38f; unsigned bi = 0xFFFFFFFFu; int bq = 0;
        int pa[4] = {p0, p1, p2, p3};
        #pragma unroll
        for (int q4 = 0; q4 < 4; ++q4) {
          if (pa[q4] < 32) {
            uint2 e = Lrow[q4*32 + pa[q4]];
            float v = __uint_as_float(e.x);
            if (v < bv || (v == bv && e.y < bi)) { bv = v; bi = e.y; bq = q4; }
          }
        }
        dst[k] = make_uint2(__float_as_uint(bv), bi);
        if (bq == 0) p0++; else if (bq == 1) p1++; else if (bq == 2) p2++; else p3++;
      }
    }
  }
}

// =====================================================================
// FALLBACK path (ws too small): round-3 kernels, proven correct
// =====================================================================
__global__ __launch_bounds__(256) void k_prep_fb(
    const float* __restrict__ xyz, const float* __restrict__ points,
    const int* __restrict__ sidx, float* __restrict__ out, float* __restrict__ sqn)
{
  int tid = blockIdx.x * 256 + threadIdx.x;
  const float4* p = (const float4*)(points + (size_t)tid * 64);
  float s = 0.f;
  #pragma unroll
  for (int i = 0; i < 16; ++i) {
    float4 v = p[i];
    s += v.x*v.x + v.y*v.y + v.z*v.z + v.w*v.w;
  }
  sqn[tid] = s;
  if (tid < B_*S_) {
    int b = tid >> 11, ss = tid & (S_-1);
    int n = sidx[ss];
    const float* src = xyz + ((size_t)b * N_ + n) * 3;
    out[(size_t)tid*3+0] = src[0];
    out[(size_t)tid*3+1] = src[1];
    out[(size_t)tid*3+2] = src[2];
  }
}

__global__ __launch_bounds__(256) void k_knn_fb(
    const float* __restrict__ points, const int* __restrict__ sidx,
    const float* __restrict__ sqn, uint2* __restrict__ pw)
{
  __shared__ __align__(16) char smraw[45312];
  short* Bp0 = (short*)smraw;
  short* Bp1 = (short*)(smraw + 9216);
  short* Bp2 = (short*)(smraw + 18432);
  float* Dt  = (float*)(smraw + 27648);
  float* sqc = (float*)(smraw + 45056);

  const int t = threadIdx.x;
  const int b     = blockIdx.x & 7;
  const int y     = blockIdx.x >> 3;
  const int tile  = y & 31;
  const int split = y >> 5;
  const int s0 = tile * 64;
  const float* Pb = points + (size_t)b * N_ * 64;
  const float* Qb = sqn    + (size_t)b * N_;

  const int lane = t & 63, wv = t >> 6;
  const int quad = lane >> 4, mcol = lane & 15;

  short8_ A0[2], A1[2], A2[2];
  {
    int srow = sidx[s0 + 16*wv + mcol];
    const float* ar = Pb + (size_t)srow * 64;
    #pragma unroll
    for (int kt = 0; kt < 2; ++kt) {
      float4 v0 = *(const float4*)(ar + 32*kt + 8*quad);
      float4 v1 = *(const float4*)(ar + 32*kt + 8*quad + 4);
      float f[8] = {v0.x,v0.y,v0.z,v0.w,v1.x,v1.y,v1.z,v1.w};
      #pragma unroll
      for (int j = 0; j < 8; ++j) {
        short h0, h1, h2;
        bf3split(f[j], h0, h1, h2);
        A0[kt][j] = h0; A1[kt][j] = h1; A2[kt][j] = h2;
      }
    }
  }

  float Lv[32]; int Li[32];
  #pragma unroll
  for (int i = 0; i < 32; ++i) { Lv[i] = 3.0e38f; Li[i] = 0; }

  const int r = t >> 2;
  const int q = t & 3;
  const int n0base = split * NSPL_;

  for (int ch = 0; ch < NSPL_/64; ++ch) {
    const int n0 = n0base + ch * 64;
    {
      const int n = t & 63, jg = t >> 6;
      const float* src = Pb + (size_t)(n0 + n) * 64 + 16*jg;
      float4 u0 = *(const float4*)(src);
      float4 u1 = *(const float4*)(src + 4);
      float4 u2 = *(const float4*)(src + 8);
      float4 u3 = *(const float4*)(src + 12);
      float f[16] = {u0.x,u0.y,u0.z,u0.w, u1.x,u1.y,u1.z,u1.w,
                     u2.x,u2.y,u2.z,u2.w, u3.x,u3.y,u3.z,u3.w};
      short8_ p0[2], p1[2], p2[2];
      #pragma unroll
      for (int j = 0; j < 16; ++j) {
        short h0, h1, h2;
        bf3split(f[j], h0, h1, h2);
        p0[j>>3][j&7] = h0; p1[j>>3][j&7] = h1; p2[j>>3][j&7] = h2;
      }
      *(short8_*)(Bp0 + n*72 + 16*jg)     = p0[0];
      *(short8_*)(Bp0 + n*72 + 16*jg + 8) = p0[1];
      *(short8_*)(Bp1 + n*72 + 16*jg)     = p1[0];
      *(short8_*)(Bp1 + n*72 + 16*jg + 8) = p1[1];
      *(short8_*)(Bp2 + n*72 + 16*jg)     = p2[0];
      *(short8_*)(Bp2 + n*72 + 16*jg + 8) = p2[1];
      if (t < 16) *(float4*)(sqc + 4*t) = *(const float4*)(Qb + n0 + 4*t);
    }
    __syncthreads();

    f32x4_ acc[4];
    #pragma unroll
    for (int ct = 0; ct < 4; ++ct) {
      const int boff = (16*ct + mcol)*72 + 8*quad;
      short8_ b0[2], b1[2], b2[2];
      b0[0] = *(const short8_*)(Bp0 + boff); b0[1] = *(const short8_*)(Bp0 + boff + 32);
      b1[0] = *(const short8_*)(Bp1 + boff); b1[1] = *(const short8_*)(Bp1 + boff + 32);
      b2[0] = *(const short8_*)(Bp2 + boff); b2[1] = *(const short8_*)(Bp2 + boff + 32);
      f32x4_ a = {0.f, 0.f, 0.f, 0.f};
      #pragma unroll
      for (int kt = 0; kt < 2; ++kt) {
        a = __builtin_amdgcn_mfma_f32_16x16x32_bf16(A0[kt], b0[kt], a, 0,0,0);
        a = __builtin_amdgcn_mfma_f32_16x16x32_bf16(A0[kt], b1[kt], a, 0,0,0);
        a = __builtin_amdgcn_mfma_f32_16x16x32_bf16(A1[kt], b0[kt], a, 0,0,0);
        a = __builtin_amdgcn_mfma_f32_16x16x32_bf16(A1[kt], b1[kt], a, 0,0,0);
        a = __builtin_amdgcn_mfma_f32_16x16x32_bf16(A0[kt], b2[kt], a, 0,0,0);
        a = __builtin_amdgcn_mfma_f32_16x16x32_bf16(A2[kt], b0[kt], a, 0,0,0);
        a = __builtin_amdgcn_mfma_f32_16x16x32_bf16(A1[kt], b2[kt], a, 0,0,0);
        a = __builtin_amdgcn_mfma_f32_16x16x32_bf16(A2[kt], b1[kt], a, 0,0,0);
      }
      acc[ct] = a;
    }
    #pragma unroll
    for (int ct = 0; ct < 4; ++ct) {
      int c = 16*ct + mcol;
      float sq = sqc[c];
      float4 kv;
      kv.x = sq - 2.f*acc[ct][0];
      kv.y = sq - 2.f*acc[ct][1];
      kv.z = sq - 2.f*acc[ct][2];
      kv.w = sq - 2.f*acc[ct][3];
      *(float4*)(Dt + c*68 + 16*wv + 4*quad) = kv;
    }
    __syncthreads();

    float L0 = Lv[0];
    L0 = fminf(L0, __shfl_xor(L0, 1));
    L0 = fminf(L0, __shfl_xor(L0, 2));
    const float tau = L0;
    #pragma unroll
    for (int g = 0; g < 4; ++g) {
      #pragma unroll
      for (int u = 0; u < 4; ++u) {
        int c = q*16 + g*4 + u;
        float x = Dt[c*68 + r];
        if (x < fminf(tau, Lv[0]))
          insert32(Lv, Li, x, n0 + c);
      }
    }
  }

  uint2* mbuf = (uint2*)smraw;
  const int rowg = b * S_ + s0;
  for (int pass = 0; pass < 2; ++pass) {
    __syncthreads();
    const int rb = pass * 32;
    if (r >= rb && r < rb + 32) {
      #pragma unroll
      for (int i = 0; i < 32; ++i)
        mbuf[(r - rb)*130 + q*32 + (31 - i)] =
            make_uint2(__float_as_uint(Lv[i]), (unsigned)Li[i]);
    }
    __syncthreads();
    if (t < 32) {
      const uint2* Lrow = mbuf + t*130;
      uint2* dst = pw + ((size_t)(rowg + rb + t) * SPLIT_ + split) * 32;
      int p0 = 0, p1 = 0, p2 = 0, p3 = 0;
      for (int k = 0; k < 32; ++k) {
        float bv = 3.0e38f; unsigned bi = 0xFFFFFFFFu; int bq = 0;
        int pa[4] = {p0, p1, p2, p3};
        #pragma unroll
        for (int q4 = 0; q4 < 4; ++q4) {
          if (pa[q4] < 32) {
            uint2 e = Lrow[q4*32 + pa[q4]];
            float v = __uint_as_float(e.x);
            if (v < bv || (v == bv && e.y < bi)) { bv = v; bi = e.y; bq = q4; }
          }
        }
        dst[k] = make_uint2(__float_as_uint(bv), bi);
        if (bq == 0) p0++; else if (bq == 1) p1++; else if (bq == 2) p2++; else p3++;
      }
    }
  }
}

// =====================================================================
// K2b: merge the 4 split-partials (ascending) per row -> 32 indices
// =====================================================================
__global__ __launch_bounds__(256) void k_sel(const uint2* __restrict__ pw,
                                             int* __restrict__ nbr)
{
  int row = blockIdx.x * 256 + threadIdx.x;       // 0 .. B*S-1
  const uint2* L = pw + (size_t)row * (SPLIT_*32);
  int* dst = nbr + (size_t)row * K_;
  int p[4] = {0,0,0,0};
  for (int k = 0; k < K_; ++k) {
    float bv = 3.0e38f; unsigned bi = 0xFFFFFFFFu; int bq = 0;
    #pragma unroll
    for (int q4 = 0; q4 < 4; ++q4) {
      if (p[q4] < 32) {
        uint2 e = L[q4*32 + p[q4]];
        float v = __uint_as_float(e.x);
        if (v < bv || (v == bv && e.y < bi)) { bv = v; bi = e.y; bq = q4; }
      }
    }
    dst[k] = (int)bi;
    p[bq]++;
  }
}

// =====================================================================
// K3: MFMA MLP (bf16 2-split) + fused bias/relu/maxpool.
// =====================================================================
__device__ __forceinline__ void layer_mfma(
    int lane, int wv, const float* Xf, float* Hf,
    const float* __restrict__ wgt, const float* scl, const float* bia)
{
  const int quad = lane >> 4, mcol = lane & 15;
  const int o = wv*16 + mcol;                 // this wave's output column
  const float sc = scl[o];
  short8_ B0[2], B1[2];
  #pragma unroll
  for (int kt = 0; kt < 2; ++kt) {
    const float* wp = wgt + o*64 + kt*32 + quad*8;
    float4 u0 = *(const float4*)(wp);
    float4 u1 = *(const float4*)(wp + 4);
    float f[8] = {u0.x*sc,u0.y*sc,u0.z*sc,u0.w*sc,
                  u1.x*sc,u1.y*sc,u1.z*sc,u1.w*sc};
    bf2split8(f, B0[kt], B1[kt]);
  }
  const float bo = bia[o];
  const int kt2 = (o >> 5) & 1, qk2 = (o >> 3) & 3, h2 = (o >> 2) & 1, j2 = o & 3;
  #pragma unroll
  for (int mt = 0; mt < 2; ++mt) {
    short8_ A0[2], A1[2];
    #pragma unroll
    for (int kt = 0; kt < 2; ++kt) {
      float4 x0 = *(const float4*)(Xf + (((mt*2+kt)*2+0)*256) + lane*4);
      float4 x1 = *(const float4*)(Xf + (((mt*2+kt)*2+1)*256) + lane*4);
      float f[8] = {x0.x,x0.y,x0.z,x0.w, x1.x,x1.y,x1.z,x1.w};
      bf2split8(f, A0[kt], A1[kt]);
    }
    f32x4_ a = {0.f, 0.f, 0.f, 0.f};
    #pragma unroll
    for (int kt = 0; kt < 2; ++kt) {
      a = __builtin_amdgcn_mfma_f32_16x16x32_bf16(A0[kt], B0[kt], a, 0,0,0);
      a = __builtin_amdgcn_mfma_f32_16x16x32_bf16(A0[kt], B1[kt], a, 0,0,0);
      a = __builtin_amdgcn_mfma_f32_16x16x32_bf16(A1[kt], B0[kt], a, 0,0,0);
    }
    #pragma unroll
    for (int reg = 0; reg < 4; ++reg) {
      int ml = quad*4 + reg;                  // m within mtile
      float hval = fmaxf(a[reg] + bo, 0.f);
      Hf[((mt*2 + kt2)*2 + h2)*256 + (qk2*16 + ml)*4 + j2] = hval;
    }
  }
}

__global__ __launch_bounds__(256) void k_mlp(
    const float* __restrict__ points, const int* __restrict__ nbr,
    const float* __restrict__ w0, const float* __restrict__ b0,
    const float* __restrict__ g0, const float* __restrict__ be0,
    const float* __restrict__ m0, const float* __restrict__ v0,
    const float* __restrict__ w1, const float* __restrict__ b1,
    const float* __restrict__ g1, const float* __restrict__ be1,
    const float* __restrict__ m1, const float* __restrict__ v1,
    const float* __restrict__ w2, const float* __restrict__ b2,
    const float* __restrict__ g2, const float* __restrict__ be2,
    const float* __restrict__ m2, const float* __restrict__ v2,
    float* __restrict__ out)
{
  __shared__ __align__(16) float Xf[2048];   // 8 segs x 1KB
  __shared__ __align__(16) float Hf[2048];
  __shared__ float scl[128];
  __shared__ float bia[128];
  __shared__ int   nIx[32];

  const int t  = threadIdx.x;
  const int bs = blockIdx.x;
  const int b  = bs >> 11;
  const int lane = t & 63, wv = t >> 6;
  const int quad = lane >> 4, mcol = lane & 15;

  if (t < 32) nIx[t] = nbr[(size_t)bs * K_ + t];
  if (t >= 64 && t < 128) {                  // layer-0 BN fold in parallel
    int i = t - 64;
    float sc = g0[i] * rsqrtf(v0[i] + 1e-5f);
    scl[i] = sc;
    bia[i] = (b0[i] - m0[i]) * sc + be0[i];
  }
  __syncthreads();
  // stage X (32 rows x 64 ch fp32) into fragment-major segments
  #pragma unroll
  for (int rep = 0; rep < 2; ++rep) {
    int task = rep*256 + t;
    int row = task >> 4, j4 = task & 15;
    float4 v = *(const float4*)(points + ((size_t)b*N_ + nIx[row])*64 + j4*4);
    int kt = j4 >> 3, qk = (j4 >> 1) & 3, h = j4 & 1;
    *(float4*)(Xf + (((row>>4)*2 + kt)*2 + h)*256 + (qk*16 + (row&15))*4) = v;
  }
  __syncthreads();

  layer_mfma(lane, wv, Xf, Hf, w0, scl, bia);      // X -> H
  __syncthreads();
  if (t < 64) {
    float sc = g1[t] * rsqrtf(v1[t] + 1e-5f);
    scl[t] = sc;
    bia[t] = (b1[t] - m1[t]) * sc + be1[t];
  }
  __syncthreads();
  layer_mfma(lane, wv, Hf, Xf, w1, scl, bia);      // H -> X
  __syncthreads();
  if (t < 128) {
    float sc = g2[t] * rsqrtf(v2[t] + 1e-5f);
    scl[t] = sc;
    bia[t] = (b2[t] - m2[t]) * sc + be2[t];
  }
  __syncthreads();

  // ---- layer 2: 64 -> 128, fused maxpool.  A-frags hoisted ----
  short8_ A0[2][2], A1[2][2];
  #pragma unroll
  for (int mt = 0; mt < 2; ++mt)
    #pragma unroll
    for (int kt = 0; kt < 2; ++kt) {
      float4 x0 = *(const float4*)(Xf + (((mt*2+kt)*2+0)*256) + lane*4);
      float4 x1 = *(const float4*)(Xf + (((mt*2+kt)*2+1)*256) + lane*4);
      float f[8] = {x0.x,x0.y,x0.z,x0.w, x1.x,x1.y,x1.z,x1.w};
      bf2split8(f, A0[mt][kt], A1[mt][kt]);
    }
  float* outp = out + (size_t)(B_*S_)*3 + (size_t)bs*128;
  #pragma unroll
  for (int sub = 0; sub < 2; ++sub) {
    const int o = (wv*2 + sub)*16 + mcol;
    const float sc = scl[o];
    short8_ B0[2], B1[2];
    #pragma unroll
    for (int kt = 0; kt < 2; ++kt) {
      const float* wp = w2 + o*64 + kt*32 + quad*8;
      float4 u0 = *(const float4*)(wp);
      float4 u1 = *(const float4*)(wp + 4);
      float f[8] = {u0.x*sc,u0.y*sc,u0.z*sc,u0.w*sc,
                    u1.x*sc,u1.y*sc,u1.z*sc,u1.w*sc};
      bf2split8(f, B0[kt], B1[kt]);
    }
    float vmax = -3.0e38f;
    #pragma unroll
    for (int mt = 0; mt < 2; ++mt) {
      f32x4_ a = {0.f, 0.f, 0.f, 0.f};
      #pragma unroll
      for (int kt = 0; kt < 2; ++kt) {
        a = __builtin_amdgcn_mfma_f32_16x16x32_bf16(A0[mt][kt], B0[kt], a, 0,0,0);
        a = __builtin_amdgcn_mfma_f32_16x16x32_bf16(A0[mt][kt], B1[kt], a, 0,0,0);
        a = __builtin_amdgcn_mfma_f32_16x16x32_bf16(A1[mt][kt], B0[kt], a, 0,0,0);
      }
      vmax = fmaxf(vmax, fmaxf(fmaxf(a[0], a[1]), fmaxf(a[2], a[3])));
    }
    vmax = fmaxf(vmax, __shfl_xor(vmax, 16));
    vmax = fmaxf(vmax, __shfl_xor(vmax, 32));
    if (quad == 0) outp[o] = fmaxf(vmax + bia[o], 0.f);
  }
}

// =====================================================================
extern "C" void kernel_launch(void* const* d_in, const int* in_sizes, int n_in,
                              void* d_out, int out_size, void* d_ws, size_t ws_size,
                              hipStream_t stream)
{
  const float* xyz  = (const float*)d_in[0];
  const float* pts  = (const float*)d_in[1];
  const int*   sidx = (const int*)  d_in[2];
  const float* w0 = (const float*)d_in[3];
  const float* b0 = (const float*)d_in[4];
  const float* g0 = (const float*)d_in[5];
  const float* be0= (const float*)d_in[6];
  const float* m0 = (const float*)d_in[7];
  const float* v0 = (const float*)d_in[8];
  const float* w1 = (const float*)d_in[9];
  const float* b1 = (const float*)d_in[10];
  const float* g1 = (const float*)d_in[11];
  const float* be1= (const float*)d_in[12];
  const float* m1 = (const float*)d_in[13];
  const float* v1 = (const float*)d_in[14];
  const float* w2 = (const float*)d_in[15];
  const float* b2 = (const float*)d_in[16];
  const float* g2 = (const float*)d_in[17];
  const float* be2= (const float*)d_in[18];
  const float* m2 = (const float*)d_in[19];
  const float* v2 = (const float*)d_in[20];

  float* out = (float*)d_out;
  // ws: sqn (512KB) | nbr (2MB) | pw (16.8MB) | planes (3 x 16.78MB)
  float* sqn = (float*)d_ws;
  int*   nbr = (int*)  ((char*)d_ws + (size_t)B_*N_*4);
  uint2* pw  = (uint2*)((char*)d_ws + (size_t)B_*N_*4 + (size_t)B_*S_*K_*4);
  char*  pl  = (char*)d_ws + (size_t)B_*N_*4 + (size_t)B_*S_*K_*4
             + (size_t)B_*S_*SPLIT_*32*8;
  short* P0 = (short*)pl;
  short* P1 = P0 + PLANE_;
  short* P2 = P1 + PLANE_;
  const size_t need = (size_t)B_*N_*4 + (size_t)B_*S_*K_*4
                    + (size_t)B_*S_*SPLIT_*32*8 + 3*PLANE_*2;

  if (ws_size >= need) {
    k_prep<<<(B_*N_)/256, 256, 0, stream>>>(xyz, pts, sidx, out, sqn, P0, P1, P2);
    k_knn <<<B_*32*SPLIT_, 256, 0, stream>>>(P0, P1, P2, sidx, sqn, pw);
  } else {
    k_prep_fb<<<(B_*N_)/256, 256, 0, stream>>>(xyz, pts, sidx, out, sqn);
    k_knn_fb <<<B_*32*SPLIT_, 256, 0, stream>>>(pts, sidx, sqn, pw);
  }
  k_sel <<<(B_*S_)/256, 256, 0, stream>>>(pw, nbr);
  k_mlp <<<B_*S_, 256, 0, stream>>>(pts, nbr,
            w0,b0,g0,be0,m0,v0, w1,b1,g1,be1,m1,v1, w2,b2,g2,be2,m2,v2, out);
}